// Round 5
// baseline (537.631 us; speedup 1.0000x reference)
//
#include <hip/hip_runtime.h>

#define N_IN 64
#define HID 128
#define OUT_F 64

typedef unsigned short ushort_t;
typedef ushort_t us8 __attribute__((ext_vector_type(8)));
typedef short    s16x8 __attribute__((ext_vector_type(8)));
typedef float    f32x4 __attribute__((ext_vector_type(4)));

__device__ inline ushort_t f2bf(float f) {          // round-to-nearest-even
    unsigned u = __float_as_uint(f);
    u = u + 0x7fffu + ((u >> 16) & 1u);
    return (ushort_t)(u >> 16);
}
__device__ inline float bf2f(ushort_t b) {
    return __uint_as_float((unsigned)b << 16);
}

// ---------------------------------------------------------------------------
// feat (fp32 row-major [n][64]) -> bf16 column-sliced [slice8][n][8]
// thread = (n, slice): reads 32B contiguous, 8 lanes cover one row.
// ---------------------------------------------------------------------------
__global__ __launch_bounds__(256)
void cvt_feat_sliced(const float* __restrict__ in, ushort_t* __restrict__ out, int nn) {
    int gid = blockIdx.x * 256 + threadIdx.x;
    int n = gid / 8, s = gid % 8;
    if (n >= nn) return;
    f32x4 a = *(const f32x4*)(in + (size_t)n * N_IN + s * 8);
    f32x4 b = *(const f32x4*)(in + (size_t)n * N_IN + s * 8 + 4);
    us8 v;
#pragma unroll
    for (int t = 0; t < 4; ++t) { v[t] = f2bf(a[t]); v[4 + t] = f2bf(b[t]); }
    *(us8*)(out + (size_t)s * nn * 8 + (size_t)n * 8) = v;
}

// ---------------------------------------------------------------------------
// weight convert + transpose: WT[h][k] = bf16(W[k][h])
// ---------------------------------------------------------------------------
__global__ __launch_bounds__(256)
void cvtT(const float* __restrict__ W, ushort_t* __restrict__ WT, int K, int H) {
    int i = blockIdx.x * 256 + threadIdx.x;
    if (i >= H * K) return;
    int h = i / K, k = i % K;
    WT[i] = f2bf(W[(size_t)k * H + h]);
}

// ---------------------------------------------------------------------------
// degree + rank: rank[e] = old count (coalesced write); degi counts
// ---------------------------------------------------------------------------
__global__ __launch_bounds__(256)
void deg_rank(const int* __restrict__ dst, int* __restrict__ degi,
              int* __restrict__ rank, int E) {
    int e = blockIdx.x * 256 + threadIdx.x;
    if (e < E) {
        int r = atomicAdd(&degi[dst[e]], 1);
        __builtin_nontemporal_store(r, &rank[e]);
    }
}

// ---------------------------------------------------------------------------
// prefix scan (3 kernels)
// ---------------------------------------------------------------------------
__global__ __launch_bounds__(256)
void scan_block(const int* __restrict__ degi, int* __restrict__ offs,
                int* __restrict__ partials, int nn) {
    __shared__ int sm[256];
    int i = blockIdx.x * 256 + threadIdx.x;
    int v = (i < nn) ? degi[i] : 0;
    sm[threadIdx.x] = v;
    __syncthreads();
    for (int d = 1; d < 256; d <<= 1) {
        int t = (threadIdx.x >= d) ? sm[threadIdx.x - d] : 0;
        __syncthreads();
        sm[threadIdx.x] += t;
        __syncthreads();
    }
    if (i < nn) offs[i] = sm[threadIdx.x] - v;
    if (threadIdx.x == 255) partials[blockIdx.x] = sm[255];
}

__global__ __launch_bounds__(1024)
void scan_partials(int* __restrict__ partials, int nparts) {
    __shared__ int sm[1024];
    int i = threadIdx.x;
    int v = (i < nparts) ? partials[i] : 0;
    sm[i] = v;
    __syncthreads();
    for (int d = 1; d < 1024; d <<= 1) {
        int t = (i >= d) ? sm[i - d] : 0;
        __syncthreads();
        sm[i] += t;
        __syncthreads();
    }
    if (i < nparts) partials[i] = sm[i] - v;
}

__global__ __launch_bounds__(256)
void finalize_offs(int* __restrict__ offs, float* __restrict__ invd,
                   const int* __restrict__ partials, const int* __restrict__ degi,
                   int nn, int E) {
    int i = blockIdx.x * 256 + threadIdx.x;
    if (i < nn) {
        offs[i] = offs[i] + partials[i >> 8];
        invd[i] = 1.0f / fmaxf((float)degi[i], 1.0f);
    } else if (i == nn) {
        offs[nn] = E;
    }
}

// ---------------------------------------------------------------------------
// CSR edge placement: atomic-free, nontemporal scatter store
// ---------------------------------------------------------------------------
__global__ __launch_bounds__(256)
void place2(const int* __restrict__ src, const int* __restrict__ dst,
            const int* __restrict__ rank, const int* __restrict__ offs,
            int* __restrict__ csr_src, int E) {
    int e = blockIdx.x * 256 + threadIdx.x;
    if (e < E) {
        int pos = offs[dst[e]] + rank[e];
        __builtin_nontemporal_store(src[e], &csr_src[pos]);
    }
}

// ---------------------------------------------------------------------------
// XCD-local sliced gather:
//   slice = blockIdx.x & 7  (round-robin blockIdx->XCD keeps each 3.2MB/1.6MB
//   slice table L2-resident on ONE XCD)
//   aggb[slice][n][:] = bf16( invd[n] * sum_j xb[slice][csr_src[j]][:] )
// ---------------------------------------------------------------------------
template<int SC>   // slice columns (8 for D=64, 16 for D=128)
__global__ __launch_bounds__(256)
void gather_sliced(const ushort_t* __restrict__ xb, const int* __restrict__ csr_src,
                   const int* __restrict__ offs, const float* __restrict__ invd,
                   ushort_t* __restrict__ aggb, int nn) {
    constexpr int CPS = SC / 8;            // us8 chunks per slice
    const int slice = blockIdx.x & 7;
    int gid = (blockIdx.x >> 3) * 256 + threadIdx.x;
    int n = gid / CPS;
    if (n >= nn) return;
    int c = (gid % CPS) * 8;
    const ushort_t* tab = xb + (size_t)slice * nn * SC + c;
    int beg = offs[n], end = offs[n + 1];
    float acc[8] = {0.f, 0.f, 0.f, 0.f, 0.f, 0.f, 0.f, 0.f};
    int j = beg;
    for (; j + 1 < end; j += 2) {
        int s0 = csr_src[j], s1 = csr_src[j + 1];
        us8 v0 = *(const us8*)(tab + (size_t)s0 * SC);
        us8 v1 = *(const us8*)(tab + (size_t)s1 * SC);
#pragma unroll
        for (int t = 0; t < 8; ++t) acc[t] += bf2f(v0[t]) + bf2f(v1[t]);
    }
    if (j < end) {
        int s = csr_src[j];
        us8 v = *(const us8*)(tab + (size_t)s * SC);
#pragma unroll
        for (int t = 0; t < 8; ++t) acc[t] += bf2f(v[t]);
    }
    float iv = invd[n];
    us8 ov;
#pragma unroll
    for (int t = 0; t < 8; ++t) ov[t] = f2bf(acc[t] * iv);
    *(us8*)(aggb + (size_t)slice * nn * SC + (size_t)n * SC + c) = ov;
}

// ---------------------------------------------------------------------------
// MFMA SAGE layer on sliced bf16 inputs:
//   out[n][0..127] = relu( x[n]@Ws + g[n]@Wn + b )
// x,g stored [slice8][n][SC]; staged to LDS row-major (XOR-swizzled).
// OBF output: bf16 sliced [slice8][n][16]; else fp32 row-major.
// ---------------------------------------------------------------------------
template<int K, int SCX, int SCG, bool OBF>
__global__ __launch_bounds__(256)
void mfma_layer(const ushort_t* __restrict__ xb, const ushort_t* __restrict__ gb,
                const ushort_t* __restrict__ wsT, const ushort_t* __restrict__ wnT,
                const float* __restrict__ bias, void* __restrict__ out, int nn) {
    constexpr int CH   = K / 8;               // 16B chunks per row
    constexpr int CPSX = SCX / 8;
    constexpr int CPSG = SCG / 8;
    __shared__ us8 xs[64][CH];
    __shared__ us8 gs[64][CH];

    const int tid  = threadIdx.x;
    const int row0 = blockIdx.x * 64;

    for (int i = tid; i < 64 * CH; i += 256) {
        int r = i / CH, c = i % CH;
        int n = row0 + r;
        us8 vx = {0, 0, 0, 0, 0, 0, 0, 0};
        us8 vg = {0, 0, 0, 0, 0, 0, 0, 0};
        if (n < nn) {
            int sx = c / CPSX, cx = c % CPSX;
            int sg = c / CPSG, cg = c % CPSG;
            vx = *(const us8*)(xb + (size_t)sx * nn * SCX + (size_t)n * SCX + cx * 8);
            vg = *(const us8*)(gb + (size_t)sg * nn * SCG + (size_t)n * SCG + cg * 8);
        }
        int cs = c ^ (r & 7);
        xs[r][cs] = vx;
        gs[r][cs] = vg;
    }
    __syncthreads();

    const int lane = tid & 63;
    const int w    = tid >> 6;
    const int lr   = lane & 15;               // A-row / B-col / D-col index
    const int lk   = lane >> 4;               // k-group
    const int R    = w * 16 + lr;

    f32x4 acc[8];
#pragma unroll
    for (int t = 0; t < 8; ++t) acc[t] = {0.f, 0.f, 0.f, 0.f};

#pragma unroll
    for (int ks = 0; ks < K / 32; ++ks) {
        int c = ks * 4 + lk;
        int cs = c ^ (R & 7);
        s16x8 ax = (s16x8)xs[R][cs];
        s16x8 ag = (s16x8)gs[R][cs];
        const size_t wko = (size_t)(ks * 32 + lk * 8);
#pragma unroll
        for (int t = 0; t < 8; ++t) {
            const size_t hrow = (size_t)(t * 16 + lr) * K;
            s16x8 bs = *(const s16x8*)(wsT + hrow + wko);
            s16x8 bn = *(const s16x8*)(wnT + hrow + wko);
            acc[t] = __builtin_amdgcn_mfma_f32_16x16x32_bf16(ax, bs, acc[t], 0, 0, 0);
            acc[t] = __builtin_amdgcn_mfma_f32_16x16x32_bf16(ag, bn, acc[t], 0, 0, 0);
        }
    }

    // epilogue: bias + relu; D layout col(h)=lane&15 (within t*16), row(n)=lk*4+reg
#pragma unroll
    for (int t = 0; t < 8; ++t) {
        float bv = bias[t * 16 + lr];
#pragma unroll
        for (int j = 0; j < 4; ++j) {
            int n = row0 + w * 16 + lk * 4 + j;
            if (n < nn) {
                float v = fmaxf(acc[t][j] + bv, 0.f);
                if constexpr (OBF)   // sliced [t][n][16], col lr
                    ((ushort_t*)out)[(size_t)t * nn * 16 + (size_t)n * 16 + lr] = f2bf(v);
                else
                    ((float*)out)[(size_t)n * HID + t * 16 + lr] = v;
            }
        }
    }
}

// ---------------------------------------------------------------------------
// fp32 vector MLP layer: out[n][h] = act( x[n]@W + b )  (in-place safe)
// ---------------------------------------------------------------------------
template<int K, int H, bool RELU>
__global__ __launch_bounds__(256)
void mlp_gemm(const float* __restrict__ x, const float* __restrict__ W,
              const float* __restrict__ bias, float* __restrict__ out, int nn) {
    constexpr int HG   = H / 4;
    constexpr int RGS  = 256 / HG;
    constexpr int ROWS = RGS * 4;

    __shared__ float xs[ROWS][K];

    const int tid  = threadIdx.x;
    const int row0 = blockIdx.x * ROWS;

    constexpr int CHN = K / 4;
    for (int i = tid; i < ROWS * CHN; i += 256) {
        int r = i / CHN, c = i % CHN, n = row0 + r;
        f32x4 v = {0.f, 0.f, 0.f, 0.f};
        if (n < nn) v = *(const f32x4*)(x + (size_t)n * K + c * 4);
        *(f32x4*)&xs[r][c * 4] = v;
    }
    __syncthreads();

    const int rg = tid / HG;
    const int h0 = (tid % HG) * 4;
    const int r0 = rg * 4;

    float acc[4][4];
#pragma unroll
    for (int r = 0; r < 4; ++r)
#pragma unroll
        for (int j = 0; j < 4; ++j) acc[r][j] = 0.f;

#pragma unroll 2
    for (int k0 = 0; k0 < K; k0 += 4) {
        f32x4 xr[4];
#pragma unroll
        for (int r = 0; r < 4; ++r) xr[r] = *(const f32x4*)&xs[r0 + r][k0];
#pragma unroll
        for (int kk = 0; kk < 4; ++kk) {
            const f32x4 wv = *(const f32x4*)(W + (size_t)(k0 + kk) * H + h0);
#pragma unroll
            for (int r = 0; r < 4; ++r) {
                const float xv = xr[r][kk];
#pragma unroll
                for (int j = 0; j < 4; ++j) acc[r][j] += xv * wv[j];
            }
        }
    }

    const f32x4 bv = *(const f32x4*)(bias + h0);
#pragma unroll
    for (int r = 0; r < 4; ++r) {
        int n = row0 + r0 + r;
        if (n < nn) {
            f32x4 o;
#pragma unroll
            for (int j = 0; j < 4; ++j) {
                float v = acc[r][j] + bv[j];
                if constexpr (RELU) v = fmaxf(v, 0.f);
                o[j] = v;
            }
            *(f32x4*)(out + (size_t)n * H + h0) = o;
        }
    }
}

// ---------------------------------------------------------------------------
extern "C" void kernel_launch(void* const* d_in, const int* in_sizes, int n_in,
                              void* d_out, int out_size, void* d_ws, size_t ws_size,
                              hipStream_t stream) {
    const float* feat = (const float*)d_in[0];
    const float* Wn1  = (const float*)d_in[1];
    const float* Ws1  = (const float*)d_in[2];
    const float* b1   = (const float*)d_in[3];
    const float* Wn2  = (const float*)d_in[4];
    const float* Ws2  = (const float*)d_in[5];
    const float* b2   = (const float*)d_in[6];
    const float* Wm1  = (const float*)d_in[7];
    const float* bm1  = (const float*)d_in[8];
    const float* Wm2  = (const float*)d_in[9];
    const float* bm2  = (const float*)d_in[10];
    const int*   src  = (const int*)d_in[11];
    const int*   dst  = (const int*)d_in[12];

    const int nn = in_sizes[0] / N_IN;    // 100000
    const int E  = in_sizes[11];          // 1600000

    // ---- workspace carve-up (64B-aligned segments) ----
    char* p = (char*)d_ws;
    auto alloc = [&](size_t bytes) { void* q = p; p += (bytes + 63) & ~(size_t)63; return q; };
    int*      degi     = (int*)alloc((size_t)nn * 4);
    int*      offs     = (int*)alloc((size_t)(nn + 1) * 4);
    int*      partials = (int*)alloc(1024 * 4);
    float*    invd     = (float*)alloc((size_t)nn * 4);
    int*      rank     = (int*)alloc((size_t)E * 4);
    int*      csr_src  = (int*)alloc((size_t)E * 4);
    ushort_t* wsT1     = (ushort_t*)alloc((size_t)N_IN * HID * 2);
    ushort_t* wnT1     = (ushort_t*)alloc((size_t)N_IN * HID * 2);
    ushort_t* wsT2     = (ushort_t*)alloc((size_t)HID * HID * 2);
    ushort_t* wnT2     = (ushort_t*)alloc((size_t)HID * HID * 2);
    ushort_t* x1b      = (ushort_t*)alloc((size_t)nn * HID * 2);   // sliced [8][nn][16]
    ushort_t* agg2b    = (ushort_t*)alloc((size_t)nn * HID * 2);   // sliced [8][nn][16]
    float*    buf3     = (float*)alloc((size_t)nn * HID * 4);
    ushort_t* featb    = (ushort_t*)buf3;            // sliced [8][nn][8]; dead before buf3
    ushort_t* agg1b    = (ushort_t*)d_out;           // sliced [8][nn][8]; dead before final GEMM

    const int nparts = (nn + 255) / 256;

    hipMemsetAsync(degi, 0, (size_t)nn * sizeof(int), stream);

    // ---- bf16 conversions ----
    cvt_feat_sliced<<<((size_t)nn * 8 + 255) / 256, 256, 0, stream>>>(feat, featb, nn);
    cvtT<<<(N_IN * HID + 255) / 256, 256, 0, stream>>>(Ws1, wsT1, N_IN, HID);
    cvtT<<<(N_IN * HID + 255) / 256, 256, 0, stream>>>(Wn1, wnT1, N_IN, HID);
    cvtT<<<(HID * HID + 255) / 256, 256, 0, stream>>>(Ws2, wsT2, HID, HID);
    cvtT<<<(HID * HID + 255) / 256, 256, 0, stream>>>(Wn2, wnT2, HID, HID);

    // ---- CSR build ----
    deg_rank<<<(E + 255) / 256, 256, 0, stream>>>(dst, degi, rank, E);
    scan_block<<<nparts, 256, 0, stream>>>(degi, offs, partials, nn);
    scan_partials<<<1, 1024, 0, stream>>>(partials, nparts);
    finalize_offs<<<(nn + 256) / 256, 256, 0, stream>>>(offs, invd, partials, degi, nn, E);
    place2<<<(E + 255) / 256, 256, 0, stream>>>(src, dst, rank, offs, csr_src, E);

    // ---- layer 1 (SC=8 tables: 1.6MB/slice) ----
    {
        int bps = (nn + 255) / 256;            // CPS=1
        gather_sliced<8><<<8 * bps, 256, 0, stream>>>(featb, csr_src, offs, invd, agg1b, nn);
    }
    mfma_layer<N_IN, 8, 8, true><<<(nn + 63) / 64, 256, 0, stream>>>(
        featb, agg1b, wsT1, wnT1, b1, x1b, nn);

    // ---- layer 2 (SC=16 tables: 3.2MB/slice) ----
    {
        int bps = (nn * 2 + 255) / 256;        // CPS=2
        gather_sliced<16><<<8 * bps, 256, 0, stream>>>(x1b, csr_src, offs, invd, agg2b, nn);
    }
    mfma_layer<HID, 16, 16, false><<<(nn + 63) / 64, 256, 0, stream>>>(
        x1b, agg2b, wsT2, wnT2, b2, buf3, nn);

    // ---- MLP (fp32 vector) ----
    mlp_gemm<HID, HID, true><<<(nn + 31) / 32, 256, 0, stream>>>(
        buf3, Wm1, bm1, buf3, nn);
    mlp_gemm<HID, OUT_F, false><<<(nn + 63) / 64, 256, 0, stream>>>(
        buf3, Wm2, bm2, (float*)d_out, nn);
}

// Round 6
// 454.116 us; speedup vs baseline: 1.1839x; 1.1839x over previous
//
#include <hip/hip_runtime.h>

#define N_IN 64
#define HID 128
#define OUT_F 64

typedef unsigned short ushort_t;
typedef ushort_t us8 __attribute__((ext_vector_type(8)));
typedef short    s16x8 __attribute__((ext_vector_type(8)));
typedef float    f32x4 __attribute__((ext_vector_type(4)));

__device__ inline ushort_t f2bf(float f) {          // round-to-nearest-even
    unsigned u = __float_as_uint(f);
    u = u + 0x7fffu + ((u >> 16) & 1u);
    return (ushort_t)(u >> 16);
}
__device__ inline float bf2f(ushort_t b) {
    return __uint_as_float((unsigned)b << 16);
}

// ---------------------------------------------------------------------------
// fp32 -> bf16 row conversion (row-major, 16B out per thread)
// ---------------------------------------------------------------------------
__global__ __launch_bounds__(256)
void cvt_bf16(const float* __restrict__ in, ushort_t* __restrict__ out, int n8) {
    int i = blockIdx.x * 256 + threadIdx.x;
    if (i >= n8) return;
    f32x4 a = ((const f32x4*)in)[2 * i];
    f32x4 b = ((const f32x4*)in)[2 * i + 1];
    us8 v;
#pragma unroll
    for (int t = 0; t < 4; ++t) { v[t] = f2bf(a[t]); v[4 + t] = f2bf(b[t]); }
    ((us8*)out)[i] = v;
}

// ---------------------------------------------------------------------------
// weight convert + transpose: WT[h][k] = bf16(W[k][h])
// ---------------------------------------------------------------------------
__global__ __launch_bounds__(256)
void cvtT(const float* __restrict__ W, ushort_t* __restrict__ WT, int K, int H) {
    int i = blockIdx.x * 256 + threadIdx.x;
    if (i >= H * K) return;
    int h = i / K, k = i % K;
    WT[i] = f2bf(W[(size_t)k * H + h]);
}

// ---------------------------------------------------------------------------
// degree + rank: rank[e] = old count (coalesced write); degi counts
// ---------------------------------------------------------------------------
__global__ __launch_bounds__(256)
void deg_rank(const int* __restrict__ dst, int* __restrict__ degi,
              int* __restrict__ rank, int E) {
    int e = blockIdx.x * 256 + threadIdx.x;
    if (e < E) {
        int r = atomicAdd(&degi[dst[e]], 1);
        __builtin_nontemporal_store(r, &rank[e]);
    }
}

// ---------------------------------------------------------------------------
// prefix scan (3 kernels)
// ---------------------------------------------------------------------------
__global__ __launch_bounds__(256)
void scan_block(const int* __restrict__ degi, int* __restrict__ offs,
                int* __restrict__ partials, int nn) {
    __shared__ int sm[256];
    int i = blockIdx.x * 256 + threadIdx.x;
    int v = (i < nn) ? degi[i] : 0;
    sm[threadIdx.x] = v;
    __syncthreads();
    for (int d = 1; d < 256; d <<= 1) {
        int t = (threadIdx.x >= d) ? sm[threadIdx.x - d] : 0;
        __syncthreads();
        sm[threadIdx.x] += t;
        __syncthreads();
    }
    if (i < nn) offs[i] = sm[threadIdx.x] - v;
    if (threadIdx.x == 255) partials[blockIdx.x] = sm[255];
}

__global__ __launch_bounds__(1024)
void scan_partials(int* __restrict__ partials, int nparts) {
    __shared__ int sm[1024];
    int i = threadIdx.x;
    int v = (i < nparts) ? partials[i] : 0;
    sm[i] = v;
    __syncthreads();
    for (int d = 1; d < 1024; d <<= 1) {
        int t = (i >= d) ? sm[i - d] : 0;
        __syncthreads();
        sm[i] += t;
        __syncthreads();
    }
    if (i < nparts) partials[i] = sm[i] - v;
}

__global__ __launch_bounds__(256)
void finalize_offs(int* __restrict__ offs, float* __restrict__ invd,
                   const int* __restrict__ partials, const int* __restrict__ degi,
                   int nn, int E) {
    int i = blockIdx.x * 256 + threadIdx.x;
    if (i < nn) {
        offs[i] = offs[i] + partials[i >> 8];
        invd[i] = 1.0f / fmaxf((float)degi[i], 1.0f);
    } else if (i == nn) {
        offs[nn] = E;
    }
}

// ---------------------------------------------------------------------------
// CSR edge placement: atomic-free, nontemporal scatter store
// ---------------------------------------------------------------------------
__global__ __launch_bounds__(256)
void place2(const int* __restrict__ src, const int* __restrict__ dst,
            const int* __restrict__ rank, const int* __restrict__ offs,
            int* __restrict__ csr_src, int E) {
    int e = blockIdx.x * 256 + threadIdx.x;
    if (e < E) {
        int pos = offs[dst[e]] + rank[e];
        __builtin_nontemporal_store(src[e], &csr_src[pos]);
    }
}

// ---------------------------------------------------------------------------
// edge-parallel gather, wave = node:
//   lane = eg*C + c ; NE edges in flight x C us8-chunks (full-row coalesced)
//   aggb[n][:] = bf16( invd[n] * sum_j xb[csr_src[j]][:] )
// cross-lane shfl_xor reduce over edge groups at the end.
// ---------------------------------------------------------------------------
template<int D>
__global__ __launch_bounds__(256)
void gather_edges(const ushort_t* __restrict__ xb, const int* __restrict__ csr_src,
                  const int* __restrict__ offs, const float* __restrict__ invd,
                  ushort_t* __restrict__ aggb, int nn) {
    constexpr int C  = D / 8;          // us8 chunks per row (8 or 16)
    constexpr int NE = 64 / C;         // edge groups (8 or 4)
    const int n = (blockIdx.x * 256 + threadIdx.x) >> 6;   // wave id = node
    if (n >= nn) return;
    const int lane = threadIdx.x & 63;
    const int c  = lane % C;
    const int eg = lane / C;
    const ushort_t* tab = xb + (size_t)c * 8;

    const int beg = offs[n], end = offs[n + 1];
    float acc[8] = {0.f, 0.f, 0.f, 0.f, 0.f, 0.f, 0.f, 0.f};

    int j = beg + eg;
    for (; j + NE < end; j += 2 * NE) {
        int s0 = csr_src[j];
        int s1 = csr_src[j + NE];
        us8 v0 = *(const us8*)(tab + (size_t)s0 * D);
        us8 v1 = *(const us8*)(tab + (size_t)s1 * D);
#pragma unroll
        for (int t = 0; t < 8; ++t) acc[t] += bf2f(v0[t]) + bf2f(v1[t]);
    }
    if (j < end) {
        int s = csr_src[j];
        us8 v = *(const us8*)(tab + (size_t)s * D);
#pragma unroll
        for (int t = 0; t < 8; ++t) acc[t] += bf2f(v[t]);
    }

    // reduce across edge groups (lanes c, c+C, c+2C, ...)
#pragma unroll
    for (int m = C; m < 64; m <<= 1) {
#pragma unroll
        for (int t = 0; t < 8; ++t) acc[t] += __shfl_xor(acc[t], m, 64);
    }

    if (eg == 0) {
        float iv = invd[n];
        us8 ov;
#pragma unroll
        for (int t = 0; t < 8; ++t) ov[t] = f2bf(acc[t] * iv);
        *(us8*)(aggb + (size_t)n * D + c * 8) = ov;
    }
}

// ---------------------------------------------------------------------------
// MFMA layer: out[n][0..H-1] = act( x[n]@Ws (+ g[n]@Wn) + b )
// bf16 in, fp32 accum (v_mfma_f32_16x16x32_bf16), bf16 or fp32 out.
// Block = 4 waves, 64 nodes; wave w: nodes w*16..w*16+15, all H cols.
// A-frag row=lane&15, k=8*(lane>>4)+e (b128 from XOR-swizzled LDS);
// B-frag col=lane&15 from WT[h][k]; D col=lane&15, row=(lane>>4)*4+reg.
// ---------------------------------------------------------------------------
template<int K, int H, bool NEIGH, bool RELU, bool OBF>
__global__ __launch_bounds__(256)
void mfma_layer(const ushort_t* __restrict__ xb, const ushort_t* __restrict__ gb,
                const ushort_t* __restrict__ wsT, const ushort_t* __restrict__ wnT,
                const float* __restrict__ bias, void* __restrict__ out, int nn) {
    constexpr int CH = K / 8;                 // 16B chunks per row
    constexpr int HT = H / 16;                // 16-col tiles
    __shared__ us8 xs[64][CH];
    __shared__ us8 gs[NEIGH ? 64 : 1][NEIGH ? CH : 1];

    const int tid  = threadIdx.x;
    const int row0 = blockIdx.x * 64;

    for (int i = tid; i < 64 * CH; i += 256) {
        int r = i / CH, c = i % CH;
        int n = row0 + r;
        us8 vx = {0, 0, 0, 0, 0, 0, 0, 0};
        us8 vg = {0, 0, 0, 0, 0, 0, 0, 0};
        if (n < nn) {
            vx = *(const us8*)(xb + (size_t)n * K + c * 8);
            if constexpr (NEIGH)
                vg = *(const us8*)(gb + (size_t)n * K + c * 8);
        }
        int cs = c ^ (r & 7);
        xs[r][cs] = vx;
        if constexpr (NEIGH) gs[r][cs] = vg;
    }
    __syncthreads();

    const int lane = tid & 63;
    const int w    = tid >> 6;
    const int lr   = lane & 15;
    const int lk   = lane >> 4;
    const int R    = w * 16 + lr;

    f32x4 acc[HT];
#pragma unroll
    for (int t = 0; t < HT; ++t) acc[t] = {0.f, 0.f, 0.f, 0.f};

#pragma unroll
    for (int ks = 0; ks < K / 32; ++ks) {
        int c = ks * 4 + lk;
        int cs = c ^ (R & 7);
        s16x8 ax = (s16x8)xs[R][cs];
        s16x8 ag;
        if constexpr (NEIGH) ag = (s16x8)gs[R][cs];
        const size_t wko = (size_t)(ks * 32 + lk * 8);
#pragma unroll
        for (int t = 0; t < HT; ++t) {
            const size_t hrow = (size_t)(t * 16 + lr) * K;
            s16x8 bs = *(const s16x8*)(wsT + hrow + wko);
            acc[t] = __builtin_amdgcn_mfma_f32_16x16x32_bf16(ax, bs, acc[t], 0, 0, 0);
            if constexpr (NEIGH) {
                s16x8 bn = *(const s16x8*)(wnT + hrow + wko);
                acc[t] = __builtin_amdgcn_mfma_f32_16x16x32_bf16(ag, bn, acc[t], 0, 0, 0);
            }
        }
    }

#pragma unroll
    for (int t = 0; t < HT; ++t) {
        float bv = bias[t * 16 + lr];
        int h = t * 16 + lr;
#pragma unroll
        for (int j = 0; j < 4; ++j) {
            int n = row0 + w * 16 + lk * 4 + j;
            if (n < nn) {
                float v = acc[t][j] + bv;
                if constexpr (RELU) v = fmaxf(v, 0.f);
                if constexpr (OBF)
                    ((ushort_t*)out)[(size_t)n * H + h] = f2bf(v);
                else
                    ((float*)out)[(size_t)n * H + h] = v;
            }
        }
    }
}

// ---------------------------------------------------------------------------
extern "C" void kernel_launch(void* const* d_in, const int* in_sizes, int n_in,
                              void* d_out, int out_size, void* d_ws, size_t ws_size,
                              hipStream_t stream) {
    const float* feat = (const float*)d_in[0];
    const float* Wn1  = (const float*)d_in[1];
    const float* Ws1  = (const float*)d_in[2];
    const float* b1   = (const float*)d_in[3];
    const float* Wn2  = (const float*)d_in[4];
    const float* Ws2  = (const float*)d_in[5];
    const float* b2   = (const float*)d_in[6];
    const float* Wm1  = (const float*)d_in[7];
    const float* bm1  = (const float*)d_in[8];
    const float* Wm2  = (const float*)d_in[9];
    const float* bm2  = (const float*)d_in[10];
    const int*   src  = (const int*)d_in[11];
    const int*   dst  = (const int*)d_in[12];

    const int nn = in_sizes[0] / N_IN;    // 100000
    const int E  = in_sizes[11];          // 1600000

    // ---- workspace carve-up (64B-aligned) ----
    char* p = (char*)d_ws;
    auto alloc = [&](size_t bytes) { void* q = p; p += (bytes + 63) & ~(size_t)63; return q; };
    int*      degi     = (int*)alloc((size_t)nn * 4);
    int*      offs     = (int*)alloc((size_t)(nn + 1) * 4);
    int*      partials = (int*)alloc(1024 * 4);
    float*    invd     = (float*)alloc((size_t)nn * 4);
    int*      rank     = (int*)alloc((size_t)E * 4);
    int*      csr_src  = (int*)alloc((size_t)E * 4);
    ushort_t* wsT1     = (ushort_t*)alloc((size_t)N_IN * HID * 2);
    ushort_t* wnT1     = (ushort_t*)alloc((size_t)N_IN * HID * 2);
    ushort_t* wsT2     = (ushort_t*)alloc((size_t)HID * HID * 2);
    ushort_t* wnT2     = (ushort_t*)alloc((size_t)HID * HID * 2);
    ushort_t* wmT1     = (ushort_t*)alloc((size_t)HID * HID * 2);
    ushort_t* wmT2     = (ushort_t*)alloc((size_t)HID * OUT_F * 2);
    // region A (25.6MB): featb [nn*64] + agg1b [nn*64] early; x3b [nn*128] late.
    // featb/agg1b are dead after mfma layer-1; x3b written by MLP-1 (after layer-2).
    ushort_t* regionA  = (ushort_t*)alloc((size_t)nn * HID * 2);
    ushort_t* featb    = regionA;
    ushort_t* agg1b    = regionA + (size_t)nn * N_IN;
    ushort_t* x3b      = regionA;
    ushort_t* x1b      = (ushort_t*)alloc((size_t)nn * HID * 2);
    ushort_t* agg2b    = (ushort_t*)alloc((size_t)nn * HID * 2);
    ushort_t* x2b      = (ushort_t*)alloc((size_t)nn * HID * 2);

    const int nparts = (nn + 255) / 256;

    hipMemsetAsync(degi, 0, (size_t)nn * sizeof(int), stream);

    // ---- bf16 conversions ----
    cvt_bf16<<<((size_t)nn * (N_IN / 8) + 255) / 256, 256, 0, stream>>>(
        feat, featb, nn * (N_IN / 8));
    cvtT<<<(N_IN * HID + 255) / 256, 256, 0, stream>>>(Ws1, wsT1, N_IN, HID);
    cvtT<<<(N_IN * HID + 255) / 256, 256, 0, stream>>>(Wn1, wnT1, N_IN, HID);
    cvtT<<<(HID * HID + 255) / 256, 256, 0, stream>>>(Ws2, wsT2, HID, HID);
    cvtT<<<(HID * HID + 255) / 256, 256, 0, stream>>>(Wn2, wnT2, HID, HID);
    cvtT<<<(HID * HID + 255) / 256, 256, 0, stream>>>(Wm1, wmT1, HID, HID);
    cvtT<<<(HID * OUT_F + 255) / 256, 256, 0, stream>>>(Wm2, wmT2, HID, OUT_F);

    // ---- CSR build ----
    deg_rank<<<(E + 255) / 256, 256, 0, stream>>>(dst, degi, rank, E);
    scan_block<<<nparts, 256, 0, stream>>>(degi, offs, partials, nn);
    scan_partials<<<1, 1024, 0, stream>>>(partials, nparts);
    finalize_offs<<<(nn + 256) / 256, 256, 0, stream>>>(offs, invd, partials, degi, nn, E);
    place2<<<(E + 255) / 256, 256, 0, stream>>>(src, dst, rank, offs, csr_src, E);

    // ---- layer 1 ----
    gather_edges<N_IN><<<(nn + 3) / 4, 256, 0, stream>>>(
        featb, csr_src, offs, invd, agg1b, nn);
    mfma_layer<N_IN, HID, true, true, true><<<(nn + 63) / 64, 256, 0, stream>>>(
        featb, agg1b, wsT1, wnT1, b1, x1b, nn);

    // ---- layer 2 ----
    gather_edges<HID><<<(nn + 3) / 4, 256, 0, stream>>>(
        x1b, csr_src, offs, invd, agg2b, nn);
    mfma_layer<HID, HID, true, true, true><<<(nn + 63) / 64, 256, 0, stream>>>(
        x1b, agg2b, wsT2, wnT2, b2, x2b, nn);

    // ---- MLP (bf16 MFMA) ----
    mfma_layer<HID, HID, false, true, true><<<(nn + 63) / 64, 256, 0, stream>>>(
        x2b, nullptr, wmT1, nullptr, bm1, x3b, nn);
    mfma_layer<HID, OUT_F, false, false, false><<<(nn + 63) / 64, 256, 0, stream>>>(
        x3b, nullptr, wmT2, nullptr, bm2, (float*)d_out, nn);
}

// Round 7
// 448.557 us; speedup vs baseline: 1.1986x; 1.0124x over previous
//
#include <hip/hip_runtime.h>
#include <hip/hip_fp8.h>

#define N_IN 64
#define HID 128
#define OUT_F 64

typedef unsigned short ushort_t;
typedef unsigned char  uchar_t;
typedef ushort_t us8  __attribute__((ext_vector_type(8)));
typedef uchar_t  uc8  __attribute__((ext_vector_type(8)));
typedef short    s16x8 __attribute__((ext_vector_type(8)));
typedef float    f32x4 __attribute__((ext_vector_type(4)));
typedef unsigned int uint4v __attribute__((ext_vector_type(4)));

__device__ inline ushort_t f2bf(float f) {          // round-to-nearest-even
    unsigned u = __float_as_uint(f);
    u = u + 0x7fffu + ((u >> 16) & 1u);
    return (ushort_t)(u >> 16);
}
__device__ inline float bf2f(ushort_t b) {
    return __uint_as_float((unsigned)b << 16);
}
__device__ inline uchar_t f2fp8(float v) {          // OCP e4m3, HW-consistent
    __hip_fp8_e4m3 q(v);
    return (uchar_t)q.__x;
}
// decode 4 fp8 (one dword) -> 4 floats
__device__ inline void fp8x4_to_f32(unsigned int dw, float* o) {
#if __has_builtin(__builtin_amdgcn_cvt_pk_f32_fp8)
    auto lo = __builtin_amdgcn_cvt_pk_f32_fp8(dw, false);
    auto hi = __builtin_amdgcn_cvt_pk_f32_fp8(dw, true);
    o[0] = lo[0]; o[1] = lo[1]; o[2] = hi[0]; o[3] = hi[1];
#else
#pragma unroll
    for (int i = 0; i < 4; ++i) {
        __hip_fp8_e4m3 h; h.__x = (dw >> (8 * i)) & 0xff;
        o[i] = (float)h;
    }
#endif
}

// ---------------------------------------------------------------------------
// feat fp32 -> bf16 row-major + fp8 row-major (8 elems/thread)
// ---------------------------------------------------------------------------
__global__ __launch_bounds__(256)
void cvt_feat(const float* __restrict__ in, ushort_t* __restrict__ outb,
              uchar_t* __restrict__ outq, int n8) {
    int i = blockIdx.x * 256 + threadIdx.x;
    if (i >= n8) return;
    f32x4 a = ((const f32x4*)in)[2 * i];
    f32x4 b = ((const f32x4*)in)[2 * i + 1];
    us8 v; uc8 q;
#pragma unroll
    for (int t = 0; t < 4; ++t) {
        v[t] = f2bf(a[t]); v[4 + t] = f2bf(b[t]);
        q[t] = f2fp8(a[t]); q[4 + t] = f2fp8(b[t]);
    }
    ((us8*)outb)[i] = v;
    ((uc8*)outq)[i] = q;
}

// ---------------------------------------------------------------------------
// all 6 weight matrices: WT[h][k] = bf16(W[k][h]), one fused kernel
// segments (elems): ws1 8192 | wn1 8192 | ws2 16384 | wn2 16384 | wm1 16384 | wm2 8192
// ---------------------------------------------------------------------------
__global__ __launch_bounds__(256)
void cvt_weights(const float* __restrict__ Ws1, const float* __restrict__ Wn1,
                 const float* __restrict__ Ws2, const float* __restrict__ Wn2,
                 const float* __restrict__ Wm1, const float* __restrict__ Wm2,
                 ushort_t* __restrict__ wsT1, ushort_t* __restrict__ wnT1,
                 ushort_t* __restrict__ wsT2, ushort_t* __restrict__ wnT2,
                 ushort_t* __restrict__ wmT1, ushort_t* __restrict__ wmT2) {
    int i = blockIdx.x * 256 + threadIdx.x;
    const float* W; ushort_t* WT; int K, H, l;
    if      (i < 8192)  { W = Ws1; WT = wsT1; K = 64;  H = 128; l = i; }
    else if (i < 16384) { W = Wn1; WT = wnT1; K = 64;  H = 128; l = i - 8192; }
    else if (i < 32768) { W = Ws2; WT = wsT2; K = 128; H = 128; l = i - 16384; }
    else if (i < 49152) { W = Wn2; WT = wnT2; K = 128; H = 128; l = i - 32768; }
    else if (i < 65536) { W = Wm1; WT = wmT1; K = 128; H = 128; l = i - 49152; }
    else if (i < 73728) { W = Wm2; WT = wmT2; K = 128; H = 64;  l = i - 65536; }
    else return;
    int h = l / K, k = l % K;
    WT[l] = f2bf(W[(size_t)k * H + h]);
}

// ---------------------------------------------------------------------------
// degree + rank
// ---------------------------------------------------------------------------
__global__ __launch_bounds__(256)
void deg_rank(const int* __restrict__ dst, int* __restrict__ degi,
              int* __restrict__ rank, int E) {
    int e = blockIdx.x * 256 + threadIdx.x;
    if (e < E) {
        int r = atomicAdd(&degi[dst[e]], 1);
        __builtin_nontemporal_store(r, &rank[e]);
    }
}

// ---------------------------------------------------------------------------
// prefix scan (3 kernels)
// ---------------------------------------------------------------------------
__global__ __launch_bounds__(256)
void scan_block(const int* __restrict__ degi, int* __restrict__ offs,
                int* __restrict__ partials, int nn) {
    __shared__ int sm[256];
    int i = blockIdx.x * 256 + threadIdx.x;
    int v = (i < nn) ? degi[i] : 0;
    sm[threadIdx.x] = v;
    __syncthreads();
    for (int d = 1; d < 256; d <<= 1) {
        int t = (threadIdx.x >= d) ? sm[threadIdx.x - d] : 0;
        __syncthreads();
        sm[threadIdx.x] += t;
        __syncthreads();
    }
    if (i < nn) offs[i] = sm[threadIdx.x] - v;
    if (threadIdx.x == 255) partials[blockIdx.x] = sm[255];
}

__global__ __launch_bounds__(1024)
void scan_partials(int* __restrict__ partials, int nparts) {
    __shared__ int sm[1024];
    int i = threadIdx.x;
    int v = (i < nparts) ? partials[i] : 0;
    sm[i] = v;
    __syncthreads();
    for (int d = 1; d < 1024; d <<= 1) {
        int t = (i >= d) ? sm[i - d] : 0;
        __syncthreads();
        sm[i] += t;
        __syncthreads();
    }
    if (i < nparts) partials[i] = sm[i] - v;
}

__global__ __launch_bounds__(256)
void finalize_offs(int* __restrict__ offs, float* __restrict__ invd,
                   const int* __restrict__ partials, const int* __restrict__ degi,
                   int nn, int E) {
    int i = blockIdx.x * 256 + threadIdx.x;
    if (i < nn) {
        offs[i] = offs[i] + partials[i >> 8];
        invd[i] = 1.0f / fmaxf((float)degi[i], 1.0f);
    } else if (i == nn) {
        offs[nn] = E;
    }
}

// ---------------------------------------------------------------------------
// CSR edge placement: atomic-free, nontemporal scatter store
// ---------------------------------------------------------------------------
__global__ __launch_bounds__(256)
void place2(const int* __restrict__ src, const int* __restrict__ dst,
            const int* __restrict__ rank, const int* __restrict__ offs,
            int* __restrict__ csr_src, int E) {
    int e = blockIdx.x * 256 + threadIdx.x;
    if (e < E) {
        int pos = offs[dst[e]] + rank[e];
        __builtin_nontemporal_store(src[e], &csr_src[pos]);
    }
}

// ---------------------------------------------------------------------------
// fp8 edge-parallel gather, wave = node:
//   row = D fp8 bytes; lane = eg*C + c over C 16B-chunks x NE edge groups
//   aggb[n][:] = bf16( invd[n] * sum_j fp8dec(xq[csr_src[j]][:]) )
// ---------------------------------------------------------------------------
template<int D>
__global__ __launch_bounds__(256)
void gather_fp8(const uchar_t* __restrict__ xq, const int* __restrict__ csr_src,
                const int* __restrict__ offs, const float* __restrict__ invd,
                ushort_t* __restrict__ aggb, int nn) {
    constexpr int C  = D / 16;         // 16B chunks per row (4 for D=64, 8 for D=128)
    constexpr int NE = 64 / C;         // edge groups (16 or 8)
    const int n = (blockIdx.x * 256 + threadIdx.x) >> 6;
    if (n >= nn) return;
    const int lane = threadIdx.x & 63;
    const int c  = lane % C;
    const int eg = lane / C;
    const uchar_t* tab = xq + (size_t)c * 16;

    const int beg = offs[n], end = offs[n + 1];
    float acc[16];
#pragma unroll
    for (int t = 0; t < 16; ++t) acc[t] = 0.f;

    int j = beg + eg;
    for (; j + NE < end; j += 2 * NE) {
        int s0 = csr_src[j], s1 = csr_src[j + NE];
        uint4v q0 = *(const uint4v*)(tab + (size_t)s0 * D);
        uint4v q1 = *(const uint4v*)(tab + (size_t)s1 * D);
        float f0[16], f1[16];
#pragma unroll
        for (int d = 0; d < 4; ++d) { fp8x4_to_f32(q0[d], f0 + 4 * d); fp8x4_to_f32(q1[d], f1 + 4 * d); }
#pragma unroll
        for (int t = 0; t < 16; ++t) acc[t] += f0[t] + f1[t];
    }
    if (j < end) {
        int s = csr_src[j];
        uint4v q = *(const uint4v*)(tab + (size_t)s * D);
        float f[16];
#pragma unroll
        for (int d = 0; d < 4; ++d) fp8x4_to_f32(q[d], f + 4 * d);
#pragma unroll
        for (int t = 0; t < 16; ++t) acc[t] += f[t];
    }

    // reduce across edge groups
#pragma unroll
    for (int m = C; m < 64; m <<= 1) {
#pragma unroll
        for (int t = 0; t < 16; ++t) acc[t] += __shfl_xor(acc[t], m, 64);
    }

    if (eg == 0) {
        float iv = invd[n];
        us8 o0, o1;
#pragma unroll
        for (int t = 0; t < 8; ++t) { o0[t] = f2bf(acc[t] * iv); o1[t] = f2bf(acc[8 + t] * iv); }
        *(us8*)(aggb + (size_t)n * D + c * 16) = o0;
        *(us8*)(aggb + (size_t)n * D + c * 16 + 8) = o1;
    }
}

// ---------------------------------------------------------------------------
// MFMA layer: out[n][0..H-1] = act( x[n]@Ws (+ g[n]@Wn) + b )
// bf16 in, fp32 accum, bf16/fp32 out (+ optional fp8 shadow copy for gather)
// ---------------------------------------------------------------------------
template<int K, int H, bool NEIGH, bool RELU, bool OBF, bool OFP8>
__global__ __launch_bounds__(256)
void mfma_layer(const ushort_t* __restrict__ xb, const ushort_t* __restrict__ gb,
                const ushort_t* __restrict__ wsT, const ushort_t* __restrict__ wnT,
                const float* __restrict__ bias, void* __restrict__ out,
                uchar_t* __restrict__ outq, int nn) {
    constexpr int CH = K / 8;                 // 16B chunks per row
    constexpr int HT = H / 16;                // 16-col tiles
    __shared__ us8 xs[64][CH];
    __shared__ us8 gs[NEIGH ? 64 : 1][NEIGH ? CH : 1];

    const int tid  = threadIdx.x;
    const int row0 = blockIdx.x * 64;

    for (int i = tid; i < 64 * CH; i += 256) {
        int r = i / CH, c = i % CH;
        int n = row0 + r;
        us8 vx = {0, 0, 0, 0, 0, 0, 0, 0};
        us8 vg = {0, 0, 0, 0, 0, 0, 0, 0};
        if (n < nn) {
            vx = *(const us8*)(xb + (size_t)n * K + c * 8);
            if constexpr (NEIGH)
                vg = *(const us8*)(gb + (size_t)n * K + c * 8);
        }
        int cs = c ^ (r & 7);
        xs[r][cs] = vx;
        if constexpr (NEIGH) gs[r][cs] = vg;
    }
    __syncthreads();

    const int lane = tid & 63;
    const int w    = tid >> 6;
    const int lr   = lane & 15;
    const int lk   = lane >> 4;
    const int R    = w * 16 + lr;

    f32x4 acc[HT];
#pragma unroll
    for (int t = 0; t < HT; ++t) acc[t] = {0.f, 0.f, 0.f, 0.f};

#pragma unroll
    for (int ks = 0; ks < K / 32; ++ks) {
        int c = ks * 4 + lk;
        int cs = c ^ (R & 7);
        s16x8 ax = (s16x8)xs[R][cs];
        s16x8 ag;
        if constexpr (NEIGH) ag = (s16x8)gs[R][cs];
        const size_t wko = (size_t)(ks * 32 + lk * 8);
#pragma unroll
        for (int t = 0; t < HT; ++t) {
            const size_t hrow = (size_t)(t * 16 + lr) * K;
            s16x8 bs = *(const s16x8*)(wsT + hrow + wko);
            acc[t] = __builtin_amdgcn_mfma_f32_16x16x32_bf16(ax, bs, acc[t], 0, 0, 0);
            if constexpr (NEIGH) {
                s16x8 bn = *(const s16x8*)(wnT + hrow + wko);
                acc[t] = __builtin_amdgcn_mfma_f32_16x16x32_bf16(ag, bn, acc[t], 0, 0, 0);
            }
        }
    }

#pragma unroll
    for (int t = 0; t < HT; ++t) {
        float bv = bias[t * 16 + lr];
        int h = t * 16 + lr;
#pragma unroll
        for (int j = 0; j < 4; ++j) {
            int n = row0 + w * 16 + lk * 4 + j;
            if (n < nn) {
                float v = acc[t][j] + bv;
                if constexpr (RELU) v = fmaxf(v, 0.f);
                if constexpr (OBF)
                    ((ushort_t*)out)[(size_t)n * H + h] = f2bf(v);
                else
                    ((float*)out)[(size_t)n * H + h] = v;
                if constexpr (OFP8)
                    outq[(size_t)n * H + h] = f2fp8(v);
            }
        }
    }
}

// ---------------------------------------------------------------------------
extern "C" void kernel_launch(void* const* d_in, const int* in_sizes, int n_in,
                              void* d_out, int out_size, void* d_ws, size_t ws_size,
                              hipStream_t stream) {
    const float* feat = (const float*)d_in[0];
    const float* Wn1  = (const float*)d_in[1];
    const float* Ws1  = (const float*)d_in[2];
    const float* b1   = (const float*)d_in[3];
    const float* Wn2  = (const float*)d_in[4];
    const float* Ws2  = (const float*)d_in[5];
    const float* b2   = (const float*)d_in[6];
    const float* Wm1  = (const float*)d_in[7];
    const float* bm1  = (const float*)d_in[8];
    const float* Wm2  = (const float*)d_in[9];
    const float* bm2  = (const float*)d_in[10];
    const int*   src  = (const int*)d_in[11];
    const int*   dst  = (const int*)d_in[12];

    const int nn = in_sizes[0] / N_IN;    // 100000
    const int E  = in_sizes[11];          // 1600000

    // ---- workspace carve-up (64B-aligned) ----
    char* p = (char*)d_ws;
    auto alloc = [&](size_t bytes) { void* q = p; p += (bytes + 63) & ~(size_t)63; return q; };
    int*      degi     = (int*)alloc((size_t)nn * 4);
    int*      offs     = (int*)alloc((size_t)(nn + 1) * 4);
    int*      partials = (int*)alloc(1024 * 4);
    float*    invd     = (float*)alloc((size_t)nn * 4);
    int*      rank     = (int*)alloc((size_t)E * 4);
    int*      csr_src  = (int*)alloc((size_t)E * 4);
    ushort_t* wsT1     = (ushort_t*)alloc((size_t)N_IN * HID * 2);
    ushort_t* wnT1     = (ushort_t*)alloc((size_t)N_IN * HID * 2);
    ushort_t* wsT2     = (ushort_t*)alloc((size_t)HID * HID * 2);
    ushort_t* wnT2     = (ushort_t*)alloc((size_t)HID * HID * 2);
    ushort_t* wmT1     = (ushort_t*)alloc((size_t)HID * HID * 2);
    ushort_t* wmT2     = (ushort_t*)alloc((size_t)HID * OUT_F * 2);
    // featb (12.8MB) + x1q (12.8MB) are contiguous; reused as x2b (25.6MB) after both die.
    ushort_t* featb    = (ushort_t*)alloc((size_t)nn * N_IN * 2);
    uchar_t*  x1q      = (uchar_t*)alloc((size_t)nn * HID);
    ushort_t* x2b      = featb;                       // alias: featb dead after mfma1, x1q dead after gather2
    ushort_t* x1b      = (ushort_t*)alloc((size_t)nn * HID * 2);
    ushort_t* x3b      = x1b;                         // alias: x1b dead after mfma2
    ushort_t* agg2b    = (ushort_t*)alloc((size_t)nn * HID * 2);
    // d_out (25.6MB) as early scratch: agg1b (12.8MB) + featq (6.4MB); both dead before final GEMM.
    ushort_t* agg1b    = (ushort_t*)d_out;
    uchar_t*  featq    = (uchar_t*)d_out + (size_t)nn * N_IN * 2;

    const int nparts = (nn + 255) / 256;

    hipMemsetAsync(degi, 0, (size_t)nn * sizeof(int), stream);

    // ---- conversions (fused) ----
    cvt_feat<<<((size_t)nn * (N_IN / 8) + 255) / 256, 256, 0, stream>>>(
        feat, featb, featq, nn * (N_IN / 8));
    cvt_weights<<<(73728 + 255) / 256, 256, 0, stream>>>(
        Ws1, Wn1, Ws2, Wn2, Wm1, Wm2, wsT1, wnT1, wsT2, wnT2, wmT1, wmT2);

    // ---- CSR build ----
    deg_rank<<<(E + 255) / 256, 256, 0, stream>>>(dst, degi, rank, E);
    scan_block<<<nparts, 256, 0, stream>>>(degi, offs, partials, nn);
    scan_partials<<<1, 1024, 0, stream>>>(partials, nparts);
    finalize_offs<<<(nn + 256) / 256, 256, 0, stream>>>(offs, invd, partials, degi, nn, E);
    place2<<<(E + 255) / 256, 256, 0, stream>>>(src, dst, rank, offs, csr_src, E);

    // ---- layer 1: agg1 = mean-gather(fp8 feat); x1 = relu(feat@Ws1 + agg1@Wn1 + b1) ----
    gather_fp8<N_IN><<<(nn + 3) / 4, 256, 0, stream>>>(
        featq, csr_src, offs, invd, agg1b, nn);
    mfma_layer<N_IN, HID, true, true, true, true><<<(nn + 63) / 64, 256, 0, stream>>>(
        featb, agg1b, wsT1, wnT1, b1, x1b, x1q, nn);

    // ---- layer 2: agg2 = mean-gather(fp8 x1); x2 = relu(x1@Ws2 + agg2@Wn2 + b2) ----
    gather_fp8<HID><<<(nn + 3) / 4, 256, 0, stream>>>(
        x1q, csr_src, offs, invd, agg2b, nn);
    mfma_layer<HID, HID, true, true, true, false><<<(nn + 63) / 64, 256, 0, stream>>>(
        x1b, agg2b, wsT2, wnT2, b2, x2b, nullptr, nn);

    // ---- MLP (bf16 MFMA) ----
    mfma_layer<HID, HID, false, true, true, false><<<(nn + 63) / 64, 256, 0, stream>>>(
        x2b, nullptr, wmT1, nullptr, bm1, x3b, nullptr, nn);
    mfma_layer<HID, OUT_F, false, false, false, false><<<(nn + 63) / 64, 256, 0, stream>>>(
        x3b, nullptr, wmT2, nullptr, bm2, (float*)d_out, nullptr, nn);
}

// Round 8
// 324.765 us; speedup vs baseline: 1.6554x; 1.3812x over previous
//
#include <hip/hip_runtime.h>
#include <hip/hip_fp8.h>

#define N_IN 64
#define HID 128
#define OUT_F 64

typedef unsigned short ushort_t;
typedef unsigned char  uchar_t;
typedef ushort_t us8  __attribute__((ext_vector_type(8)));
typedef uchar_t  uc8  __attribute__((ext_vector_type(8)));
typedef short    s16x8 __attribute__((ext_vector_type(8)));
typedef float    f32x4 __attribute__((ext_vector_type(4)));
typedef unsigned int uint4v __attribute__((ext_vector_type(4)));

__device__ inline ushort_t f2bf(float f) {          // round-to-nearest-even
    unsigned u = __float_as_uint(f);
    u = u + 0x7fffu + ((u >> 16) & 1u);
    return (ushort_t)(u >> 16);
}
__device__ inline float bf2f(ushort_t b) {
    return __uint_as_float((unsigned)b << 16);
}
__device__ inline uchar_t f2fp8(float v) {          // OCP e4m3
    __hip_fp8_e4m3 q(v);
    return (uchar_t)q.__x;
}
__device__ inline void fp8x4_to_f32(unsigned int dw, float* o) {
#if __has_builtin(__builtin_amdgcn_cvt_pk_f32_fp8)
    auto lo = __builtin_amdgcn_cvt_pk_f32_fp8(dw, false);
    auto hi = __builtin_amdgcn_cvt_pk_f32_fp8(dw, true);
    o[0] = lo[0]; o[1] = lo[1]; o[2] = hi[0]; o[3] = hi[1];
#else
#pragma unroll
    for (int i = 0; i < 4; ++i) {
        __hip_fp8_e4m3 h; h.__x = (dw >> (8 * i)) & 0xff;
        o[i] = (float)h;
    }
#endif
}

// ---------------------------------------------------------------------------
// feat fp32 -> bf16 row-major + fp8 row-major
// ---------------------------------------------------------------------------
__global__ __launch_bounds__(256)
void cvt_feat(const float* __restrict__ in, ushort_t* __restrict__ outb,
              uchar_t* __restrict__ outq, int n8) {
    int i = blockIdx.x * 256 + threadIdx.x;
    if (i >= n8) return;
    f32x4 a = ((const f32x4*)in)[2 * i];
    f32x4 b = ((const f32x4*)in)[2 * i + 1];
    us8 v; uc8 q;
#pragma unroll
    for (int t = 0; t < 4; ++t) {
        v[t] = f2bf(a[t]); v[4 + t] = f2bf(b[t]);
        q[t] = f2fp8(a[t]); q[4 + t] = f2fp8(b[t]);
    }
    ((us8*)outb)[i] = v;
    ((uc8*)outq)[i] = q;
}

// ---------------------------------------------------------------------------
// all 6 weight matrices: WT[h][k] = bf16(W[k][h]), one fused kernel
// ---------------------------------------------------------------------------
__global__ __launch_bounds__(256)
void cvt_weights(const float* __restrict__ Ws1, const float* __restrict__ Wn1,
                 const float* __restrict__ Ws2, const float* __restrict__ Wn2,
                 const float* __restrict__ Wm1, const float* __restrict__ Wm2,
                 ushort_t* __restrict__ wsT1, ushort_t* __restrict__ wnT1,
                 ushort_t* __restrict__ wsT2, ushort_t* __restrict__ wnT2,
                 ushort_t* __restrict__ wmT1, ushort_t* __restrict__ wmT2) {
    int i = blockIdx.x * 256 + threadIdx.x;
    const float* W; ushort_t* WT; int K, H, l;
    if      (i < 8192)  { W = Ws1; WT = wsT1; K = 64;  H = 128; l = i; }
    else if (i < 16384) { W = Wn1; WT = wnT1; K = 64;  H = 128; l = i - 8192; }
    else if (i < 32768) { W = Ws2; WT = wsT2; K = 128; H = 128; l = i - 16384; }
    else if (i < 49152) { W = Wn2; WT = wnT2; K = 128; H = 128; l = i - 32768; }
    else if (i < 65536) { W = Wm1; WT = wmT1; K = 128; H = 128; l = i - 49152; }
    else if (i < 73728) { W = Wm2; WT = wmT2; K = 128; H = 64;  l = i - 65536; }
    else return;
    int h = l / K, k = l % K;
    WT[l] = f2bf(W[(size_t)k * H + h]);
}

// ---------------------------------------------------------------------------
// degree + rank
// ---------------------------------------------------------------------------
__global__ __launch_bounds__(256)
void deg_rank(const int* __restrict__ dst, int* __restrict__ degi,
              int* __restrict__ rank, int E) {
    int e = blockIdx.x * 256 + threadIdx.x;
    if (e < E) {
        int r = atomicAdd(&degi[dst[e]], 1);
        __builtin_nontemporal_store(r, &rank[e]);
    }
}

// ---------------------------------------------------------------------------
// prefix scan (3 kernels)
// ---------------------------------------------------------------------------
__global__ __launch_bounds__(256)
void scan_block(const int* __restrict__ degi, int* __restrict__ offs,
                int* __restrict__ partials, int nn) {
    __shared__ int sm[256];
    int i = blockIdx.x * 256 + threadIdx.x;
    int v = (i < nn) ? degi[i] : 0;
    sm[threadIdx.x] = v;
    __syncthreads();
    for (int d = 1; d < 256; d <<= 1) {
        int t = (threadIdx.x >= d) ? sm[threadIdx.x - d] : 0;
        __syncthreads();
        sm[threadIdx.x] += t;
        __syncthreads();
    }
    if (i < nn) offs[i] = sm[threadIdx.x] - v;
    if (threadIdx.x == 255) partials[blockIdx.x] = sm[255];
}

__global__ __launch_bounds__(1024)
void scan_partials(int* __restrict__ partials, int nparts) {
    __shared__ int sm[1024];
    int i = threadIdx.x;
    int v = (i < nparts) ? partials[i] : 0;
    sm[i] = v;
    __syncthreads();
    for (int d = 1; d < 1024; d <<= 1) {
        int t = (i >= d) ? sm[i - d] : 0;
        __syncthreads();
        sm[i] += t;
        __syncthreads();
    }
    if (i < nparts) partials[i] = sm[i] - v;
}

__global__ __launch_bounds__(256)
void finalize_offs(int* __restrict__ offs, float* __restrict__ invd,
                   const int* __restrict__ partials, const int* __restrict__ degi,
                   int nn, int E) {
    int i = blockIdx.x * 256 + threadIdx.x;
    if (i < nn) {
        offs[i] = offs[i] + partials[i >> 8];
        invd[i] = 1.0f / fmaxf((float)degi[i], 1.0f);
    } else if (i == nn) {
        offs[nn] = E;
    }
}

// ---------------------------------------------------------------------------
// CSR edge placement
// ---------------------------------------------------------------------------
__global__ __launch_bounds__(256)
void place2(const int* __restrict__ src, const int* __restrict__ dst,
            const int* __restrict__ rank, const int* __restrict__ offs,
            int* __restrict__ csr_src, int E) {
    int e = blockIdx.x * 256 + threadIdx.x;
    if (e < E) {
        int pos = offs[dst[e]] + rank[e];
        __builtin_nontemporal_store(src[e], &csr_src[pos]);
    }
}

// ---------------------------------------------------------------------------
// fp8 edge-parallel gather, wave = node
// ---------------------------------------------------------------------------
template<int D>
__global__ __launch_bounds__(256)
void gather_fp8(const uchar_t* __restrict__ xq, const int* __restrict__ csr_src,
                const int* __restrict__ offs, const float* __restrict__ invd,
                ushort_t* __restrict__ aggb, int nn) {
    constexpr int C  = D / 16;
    constexpr int NE = 64 / C;
    const int n = (blockIdx.x * 256 + threadIdx.x) >> 6;
    if (n >= nn) return;
    const int lane = threadIdx.x & 63;
    const int c  = lane % C;
    const int eg = lane / C;
    const uchar_t* tab = xq + (size_t)c * 16;

    const int beg = offs[n], end = offs[n + 1];
    float acc[16];
#pragma unroll
    for (int t = 0; t < 16; ++t) acc[t] = 0.f;

    int j = beg + eg;
    for (; j + NE < end; j += 2 * NE) {
        int s0 = csr_src[j], s1 = csr_src[j + NE];
        uint4v q0 = *(const uint4v*)(tab + (size_t)s0 * D);
        uint4v q1 = *(const uint4v*)(tab + (size_t)s1 * D);
        float f0[16], f1[16];
#pragma unroll
        for (int d = 0; d < 4; ++d) { fp8x4_to_f32(q0[d], f0 + 4 * d); fp8x4_to_f32(q1[d], f1 + 4 * d); }
#pragma unroll
        for (int t = 0; t < 16; ++t) acc[t] += f0[t] + f1[t];
    }
    if (j < end) {
        int s = csr_src[j];
        uint4v q = *(const uint4v*)(tab + (size_t)s * D);
        float f[16];
#pragma unroll
        for (int d = 0; d < 4; ++d) fp8x4_to_f32(q[d], f + 4 * d);
#pragma unroll
        for (int t = 0; t < 16; ++t) acc[t] += f[t];
    }

#pragma unroll
    for (int m = C; m < 64; m <<= 1) {
#pragma unroll
        for (int t = 0; t < 16; ++t) acc[t] += __shfl_xor(acc[t], m, 64);
    }

    if (eg == 0) {
        float iv = invd[n];
        us8 o0, o1;
#pragma unroll
        for (int t = 0; t < 8; ++t) { o0[t] = f2bf(acc[t] * iv); o1[t] = f2bf(acc[8 + t] * iv); }
        *(us8*)(aggb + (size_t)n * D + c * 16) = o0;
        *(us8*)(aggb + (size_t)n * D + c * 16 + 8) = o1;
    }
}

// ---------------------------------------------------------------------------
// Weight-stationary MFMA layer (grid-stride over 64-node tiles):
//   out[n][0..H-1] = act( x[n]@Ws (+ g[n]@Wn) + b )
// Wave w holds B-frags for cols [w*H/4,(w+1)*H/4) in REGISTERS (loaded once);
// per tile: prefetch A-rows to regs -> LDS (XOR swizzle) -> MFMA.
// A-frag row=lane&15, k=8*(lane>>4)+e; D col=lane&15, row=(lane>>4)*4+reg.
// ---------------------------------------------------------------------------
template<int K, int H, bool NEIGH, bool RELU, bool OBF, bool OFP8>
__global__ __launch_bounds__(256)
void mfma_layer(const ushort_t* __restrict__ xb, const ushort_t* __restrict__ gb,
                const ushort_t* __restrict__ wsT, const ushort_t* __restrict__ wnT,
                const float* __restrict__ bias, void* __restrict__ out,
                uchar_t* __restrict__ outq, int nn) {
    constexpr int CH   = K / 8;       // us8 chunks per row
    constexpr int KS   = K / 32;      // k-steps
    constexpr int WTPW = H / 64;      // 16-col tiles per wave (2 for H=128, 1 for H=64)
    constexpr int PF   = CH / 4;      // per-thread us8 prefetch regs per table

    __shared__ us8 xs[64][CH];
    __shared__ us8 gs[NEIGH ? 64 : 1][NEIGH ? CH : 1];

    const int tid  = threadIdx.x;
    const int lane = tid & 63;
    const int w    = tid >> 6;
    const int lr   = lane & 15;
    const int lk   = lane >> 4;

    // ---- weights: loaded ONCE into registers ----
    s16x8 bws[WTPW][KS];
    s16x8 bwn[NEIGH ? WTPW : 1][NEIGH ? KS : 1];
#pragma unroll
    for (int t = 0; t < WTPW; ++t) {
        const size_t hrow = (size_t)((w * WTPW + t) * 16 + lr) * K;
#pragma unroll
        for (int ks = 0; ks < KS; ++ks) {
            bws[t][ks] = *(const s16x8*)(wsT + hrow + ks * 32 + lk * 8);
            if constexpr (NEIGH)
                bwn[t][ks] = *(const s16x8*)(wnT + hrow + ks * 32 + lk * 8);
        }
    }
    float bv[WTPW];
#pragma unroll
    for (int t = 0; t < WTPW; ++t) bv[t] = bias[(w * WTPW + t) * 16 + lr];

    const int ntiles = (nn + 63) >> 6;
    us8 pfx[PF], pfg[NEIGH ? PF : 1];
    const us8 z8 = {0, 0, 0, 0, 0, 0, 0, 0};

    auto loadpf = [&](int T) {
        const int base = T * 64;
#pragma unroll
        for (int q = 0; q < PF; ++q) {
            int idx = tid + q * 256, r = idx / CH, c = idx % CH, n = base + r;
            pfx[q] = (n < nn) ? *(const us8*)(xb + (size_t)n * K + c * 8) : z8;
            if constexpr (NEIGH)
                pfg[q] = (n < nn) ? *(const us8*)(gb + (size_t)n * K + c * 8) : z8;
        }
    };

    int tile = blockIdx.x;
    if (tile >= ntiles) return;
    loadpf(tile);

    while (true) {
        __syncthreads();                      // previous compute done; LDS free
#pragma unroll
        for (int q = 0; q < PF; ++q) {
            int idx = tid + q * 256, r = idx / CH, c = idx % CH;
            int cs = c ^ (r & 7);
            xs[r][cs] = pfx[q];
            if constexpr (NEIGH) gs[r][cs] = pfg[q];
        }
        __syncthreads();                      // LDS ready

        const int cur  = tile;
        const int row0 = cur * 64;
        tile += gridDim.x;
        if (tile < ntiles) loadpf(tile);      // overlap next loads with compute

        f32x4 acc[4][WTPW];
#pragma unroll
        for (int rg = 0; rg < 4; ++rg)
#pragma unroll
            for (int t = 0; t < WTPW; ++t) acc[rg][t] = {0.f, 0.f, 0.f, 0.f};

#pragma unroll
        for (int rg = 0; rg < 4; ++rg) {
            const int R = rg * 16 + lr;
#pragma unroll
            for (int ks = 0; ks < KS; ++ks) {
                const int cs = (ks * 4 + lk) ^ (R & 7);
                s16x8 ax = (s16x8)xs[R][cs];
                s16x8 ag;
                if constexpr (NEIGH) ag = (s16x8)gs[R][cs];
#pragma unroll
                for (int t = 0; t < WTPW; ++t) {
                    acc[rg][t] = __builtin_amdgcn_mfma_f32_16x16x32_bf16(ax, bws[t][ks], acc[rg][t], 0, 0, 0);
                    if constexpr (NEIGH)
                        acc[rg][t] = __builtin_amdgcn_mfma_f32_16x16x32_bf16(ag, bwn[t][ks], acc[rg][t], 0, 0, 0);
                }
            }
        }

        // ---- epilogue ----
#pragma unroll
        for (int rg = 0; rg < 4; ++rg) {
#pragma unroll
            for (int t = 0; t < WTPW; ++t) {
                const int h = (w * WTPW + t) * 16 + lr;
#pragma unroll
                for (int j = 0; j < 4; ++j) {
                    int n = row0 + rg * 16 + lk * 4 + j;
                    if (n < nn) {
                        float v = acc[rg][t][j] + bv[t];
                        if constexpr (RELU) v = fmaxf(v, 0.f);
                        if constexpr (OBF)
                            ((ushort_t*)out)[(size_t)n * H + h] = f2bf(v);
                        else
                            ((float*)out)[(size_t)n * H + h] = v;
                        if constexpr (OFP8)
                            outq[(size_t)n * H + h] = f2fp8(v);
                    }
                }
            }
        }

        if (tile >= ntiles) break;
    }
}

// ---------------------------------------------------------------------------
extern "C" void kernel_launch(void* const* d_in, const int* in_sizes, int n_in,
                              void* d_out, int out_size, void* d_ws, size_t ws_size,
                              hipStream_t stream) {
    const float* feat = (const float*)d_in[0];
    const float* Wn1  = (const float*)d_in[1];
    const float* Ws1  = (const float*)d_in[2];
    const float* b1   = (const float*)d_in[3];
    const float* Wn2  = (const float*)d_in[4];
    const float* Ws2  = (const float*)d_in[5];
    const float* b2   = (const float*)d_in[6];
    const float* Wm1  = (const float*)d_in[7];
    const float* bm1  = (const float*)d_in[8];
    const float* Wm2  = (const float*)d_in[9];
    const float* bm2  = (const float*)d_in[10];
    const int*   src  = (const int*)d_in[11];
    const int*   dst  = (const int*)d_in[12];

    const int nn = in_sizes[0] / N_IN;    // 100000
    const int E  = in_sizes[11];          // 1600000

    // ---- workspace carve-up (64B-aligned) ----
    char* p = (char*)d_ws;
    auto alloc = [&](size_t bytes) { void* q = p; p += (bytes + 63) & ~(size_t)63; return q; };
    int*      degi     = (int*)alloc((size_t)nn * 4);
    int*      offs     = (int*)alloc((size_t)(nn + 1) * 4);
    int*      partials = (int*)alloc(1024 * 4);
    float*    invd     = (float*)alloc((size_t)nn * 4);
    int*      rank     = (int*)alloc((size_t)E * 4);
    int*      csr_src  = (int*)alloc((size_t)E * 4);
    ushort_t* wsT1     = (ushort_t*)alloc((size_t)N_IN * HID * 2);
    ushort_t* wnT1     = (ushort_t*)alloc((size_t)N_IN * HID * 2);
    ushort_t* wsT2     = (ushort_t*)alloc((size_t)HID * HID * 2);
    ushort_t* wnT2     = (ushort_t*)alloc((size_t)HID * HID * 2);
    ushort_t* wmT1     = (ushort_t*)alloc((size_t)HID * HID * 2);
    ushort_t* wmT2     = (ushort_t*)alloc((size_t)HID * OUT_F * 2);
    ushort_t* featb    = (ushort_t*)alloc((size_t)nn * N_IN * 2);
    uchar_t*  x1q      = (uchar_t*)alloc((size_t)nn * HID);
    ushort_t* x2b      = featb;                       // featb+x1q dead by then
    ushort_t* x1b      = (ushort_t*)alloc((size_t)nn * HID * 2);
    ushort_t* x3b      = x1b;                         // x1b dead after mfma2
    ushort_t* agg2b    = (ushort_t*)alloc((size_t)nn * HID * 2);
    ushort_t* agg1b    = (ushort_t*)d_out;            // dead before final GEMM
    uchar_t*  featq    = (uchar_t*)d_out + (size_t)nn * N_IN * 2;

    const int nparts = (nn + 255) / 256;
    const int ntiles = (nn + 63) / 64;
    const int NB     = ntiles < 768 ? ntiles : 768;

    hipMemsetAsync(degi, 0, (size_t)nn * sizeof(int), stream);

    // ---- conversions ----
    cvt_feat<<<((size_t)nn * (N_IN / 8) + 255) / 256, 256, 0, stream>>>(
        feat, featb, featq, nn * (N_IN / 8));
    cvt_weights<<<(73728 + 255) / 256, 256, 0, stream>>>(
        Ws1, Wn1, Ws2, Wn2, Wm1, Wm2, wsT1, wnT1, wsT2, wnT2, wmT1, wmT2);

    // ---- CSR build ----
    deg_rank<<<(E + 255) / 256, 256, 0, stream>>>(dst, degi, rank, E);
    scan_block<<<nparts, 256, 0, stream>>>(degi, offs, partials, nn);
    scan_partials<<<1, 1024, 0, stream>>>(partials, nparts);
    finalize_offs<<<(nn + 256) / 256, 256, 0, stream>>>(offs, invd, partials, degi, nn, E);
    place2<<<(E + 255) / 256, 256, 0, stream>>>(src, dst, rank, offs, csr_src, E);

    // ---- layer 1 ----
    gather_fp8<N_IN><<<(nn + 3) / 4, 256, 0, stream>>>(
        featq, csr_src, offs, invd, agg1b, nn);
    mfma_layer<N_IN, HID, true, true, true, true><<<NB, 256, 0, stream>>>(
        featb, agg1b, wsT1, wnT1, b1, x1b, x1q, nn);

    // ---- layer 2 ----
    gather_fp8<HID><<<(nn + 3) / 4, 256, 0, stream>>>(
        x1q, csr_src, offs, invd, agg2b, nn);
    mfma_layer<HID, HID, true, true, true, false><<<NB, 256, 0, stream>>>(
        x1b, agg2b, wsT2, wnT2, b2, x2b, nullptr, nn);

    // ---- MLP ----
    mfma_layer<HID, HID, false, true, true, false><<<NB, 256, 0, stream>>>(
        x2b, nullptr, wmT1, nullptr, bm1, x3b, nullptr, nn);
    mfma_layer<HID, OUT_F, false, false, false, false><<<NB, 256, 0, stream>>>(
        x3b, nullptr, wmT2, nullptr, bm2, (float*)d_out, nullptr, nn);
}

// Round 9
// 296.569 us; speedup vs baseline: 1.8128x; 1.0951x over previous
//
#include <hip/hip_runtime.h>
#include <hip/hip_fp8.h>

#define N_IN 64
#define HID 128
#define OUT_F 64

typedef unsigned short ushort_t;
typedef unsigned char  uchar_t;
typedef ushort_t us8  __attribute__((ext_vector_type(8)));
typedef uchar_t  uc8  __attribute__((ext_vector_type(8)));
typedef short    s16x8 __attribute__((ext_vector_type(8)));
typedef float    f32x4 __attribute__((ext_vector_type(4)));
typedef unsigned int uint2v __attribute__((ext_vector_type(2)));

__device__ inline ushort_t f2bf(float f) {          // round-to-nearest-even
    unsigned u = __float_as_uint(f);
    u = u + 0x7fffu + ((u >> 16) & 1u);
    return (ushort_t)(u >> 16);
}
__device__ inline float bf2f(ushort_t b) {
    return __uint_as_float((unsigned)b << 16);
}
__device__ inline uchar_t f2fp8(float v) {          // OCP e4m3
    __hip_fp8_e4m3 q(v);
    return (uchar_t)q.__x;
}
__device__ inline void fp8x4_to_f32(unsigned int dw, float* o) {
#if __has_builtin(__builtin_amdgcn_cvt_pk_f32_fp8)
    auto lo = __builtin_amdgcn_cvt_pk_f32_fp8(dw, false);
    auto hi = __builtin_amdgcn_cvt_pk_f32_fp8(dw, true);
    o[0] = lo[0]; o[1] = lo[1]; o[2] = hi[0]; o[3] = hi[1];
#else
#pragma unroll
    for (int i = 0; i < 4; ++i) {
        __hip_fp8_e4m3 h; h.__x = (dw >> (8 * i)) & 0xff;
        o[i] = (float)h;
    }
#endif
}

// ---------------------------------------------------------------------------
// fused prep: [0,BA) feat->bf16+fp8 | [BA,BB) weights->bf16^T | [BB,..) deg+rank
// ---------------------------------------------------------------------------
__global__ __launch_bounds__(256)
void prep_kernel(const float* __restrict__ feat, ushort_t* __restrict__ featb,
                 uchar_t* __restrict__ featq, int n8,
                 const float* __restrict__ Ws1, const float* __restrict__ Wn1,
                 const float* __restrict__ Ws2, const float* __restrict__ Wn2,
                 const float* __restrict__ Wm1, const float* __restrict__ Wm2,
                 ushort_t* __restrict__ wsT1, ushort_t* __restrict__ wnT1,
                 ushort_t* __restrict__ wsT2, ushort_t* __restrict__ wnT2,
                 ushort_t* __restrict__ wmT1, ushort_t* __restrict__ wmT2,
                 const int* __restrict__ dst, int* __restrict__ degi,
                 int* __restrict__ rank, int E, int BA, int BB) {
    int b = blockIdx.x;
    if (b < BA) {
        int i = b * 256 + threadIdx.x;
        if (i >= n8) return;
        f32x4 a = ((const f32x4*)feat)[2 * i];
        f32x4 c = ((const f32x4*)feat)[2 * i + 1];
        us8 v; uc8 q;
#pragma unroll
        for (int t = 0; t < 4; ++t) {
            v[t] = f2bf(a[t]); v[4 + t] = f2bf(c[t]);
            q[t] = f2fp8(a[t]); q[4 + t] = f2fp8(c[t]);
        }
        ((us8*)featb)[i] = v;
        ((uc8*)featq)[i] = q;
    } else if (b < BB) {
        int i = (b - BA) * 256 + threadIdx.x;
        const float* W; ushort_t* WT; int K, H, l;
        if      (i < 8192)  { W = Ws1; WT = wsT1; K = 64;  H = 128; l = i; }
        else if (i < 16384) { W = Wn1; WT = wnT1; K = 64;  H = 128; l = i - 8192; }
        else if (i < 32768) { W = Ws2; WT = wsT2; K = 128; H = 128; l = i - 16384; }
        else if (i < 49152) { W = Wn2; WT = wnT2; K = 128; H = 128; l = i - 32768; }
        else if (i < 65536) { W = Wm1; WT = wmT1; K = 128; H = 128; l = i - 49152; }
        else if (i < 73728) { W = Wm2; WT = wmT2; K = 128; H = 64;  l = i - 65536; }
        else return;
        int h = l / K, k = l % K;
        WT[l] = f2bf(W[(size_t)k * H + h]);
    } else {
        int e = (b - BB) * 256 + threadIdx.x;
        if (e < E) {
            int r = atomicAdd(&degi[dst[e]], 1);
            __builtin_nontemporal_store(r, &rank[e]);
        }
    }
}

// ---------------------------------------------------------------------------
// prefix scan (3 kernels)
// ---------------------------------------------------------------------------
__global__ __launch_bounds__(256)
void scan_block(const int* __restrict__ degi, int* __restrict__ offs,
                int* __restrict__ partials, int nn) {
    __shared__ int sm[256];
    int i = blockIdx.x * 256 + threadIdx.x;
    int v = (i < nn) ? degi[i] : 0;
    sm[threadIdx.x] = v;
    __syncthreads();
    for (int d = 1; d < 256; d <<= 1) {
        int t = (threadIdx.x >= d) ? sm[threadIdx.x - d] : 0;
        __syncthreads();
        sm[threadIdx.x] += t;
        __syncthreads();
    }
    if (i < nn) offs[i] = sm[threadIdx.x] - v;
    if (threadIdx.x == 255) partials[blockIdx.x] = sm[255];
}

__global__ __launch_bounds__(1024)
void scan_partials(int* __restrict__ partials, int nparts) {
    __shared__ int sm[1024];
    int i = threadIdx.x;
    int v = (i < nparts) ? partials[i] : 0;
    sm[i] = v;
    __syncthreads();
    for (int d = 1; d < 1024; d <<= 1) {
        int t = (i >= d) ? sm[i - d] : 0;
        __syncthreads();
        sm[i] += t;
        __syncthreads();
    }
    if (i < nparts) partials[i] = sm[i] - v;
}

__global__ __launch_bounds__(256)
void finalize_offs(int* __restrict__ offs, float* __restrict__ invd,
                   const int* __restrict__ partials, const int* __restrict__ degi,
                   int nn, int E) {
    int i = blockIdx.x * 256 + threadIdx.x;
    if (i < nn) {
        offs[i] = offs[i] + partials[i >> 8];
        invd[i] = 1.0f / fmaxf((float)degi[i], 1.0f);
    } else if (i == nn) {
        offs[nn] = E;
    }
}

// ---------------------------------------------------------------------------
// CSR edge placement
// ---------------------------------------------------------------------------
__global__ __launch_bounds__(256)
void place2(const int* __restrict__ src, const int* __restrict__ dst,
            const int* __restrict__ rank, const int* __restrict__ offs,
            int* __restrict__ csr_src, int E) {
    int e = blockIdx.x * 256 + threadIdx.x;
    if (e < E) {
        int pos = offs[dst[e]] + rank[e];
        __builtin_nontemporal_store(src[e], &csr_src[pos]);
    }
}

// ---------------------------------------------------------------------------
// fp8 edge-parallel gather, wave = node, 8B per lane:
//   D=64:  C=8 lanes/row, NE=8 edge groups, acc[8], 3 shfl rounds
//   D=128: C=16 lanes/row, NE=4 edge groups, acc[8], 2 shfl rounds
// ---------------------------------------------------------------------------
template<int D>
__global__ __launch_bounds__(256)
void gather_fp8(const uchar_t* __restrict__ xq, const int* __restrict__ csr_src,
                const int* __restrict__ offs, const float* __restrict__ invd,
                ushort_t* __restrict__ aggb, int nn) {
    constexpr int C  = D / 8;          // 8B chunks per row
    constexpr int NE = 64 / C;         // edge groups
    const int n = (blockIdx.x * 256 + threadIdx.x) >> 6;
    if (n >= nn) return;
    const int lane = threadIdx.x & 63;
    const int c  = lane % C;
    const int eg = lane / C;
    const uchar_t* tab = xq + (size_t)c * 8;

    const int beg = offs[n], end = offs[n + 1];
    float acc[8] = {0.f, 0.f, 0.f, 0.f, 0.f, 0.f, 0.f, 0.f};

    int j = beg + eg;
    for (; j + NE < end; j += 2 * NE) {
        int s0 = csr_src[j], s1 = csr_src[j + NE];
        uint2v q0 = *(const uint2v*)(tab + (size_t)s0 * D);
        uint2v q1 = *(const uint2v*)(tab + (size_t)s1 * D);
        float f0[8], f1[8];
        fp8x4_to_f32(q0[0], f0); fp8x4_to_f32(q0[1], f0 + 4);
        fp8x4_to_f32(q1[0], f1); fp8x4_to_f32(q1[1], f1 + 4);
#pragma unroll
        for (int t = 0; t < 8; ++t) acc[t] += f0[t] + f1[t];
    }
    if (j < end) {
        int s = csr_src[j];
        uint2v q = *(const uint2v*)(tab + (size_t)s * D);
        float f[8];
        fp8x4_to_f32(q[0], f); fp8x4_to_f32(q[1], f + 4);
#pragma unroll
        for (int t = 0; t < 8; ++t) acc[t] += f[t];
    }

    // reduce across edge groups (stride C within the wave)
#pragma unroll
    for (int m = C; m < 64; m <<= 1) {
#pragma unroll
        for (int t = 0; t < 8; ++t) acc[t] += __shfl_xor(acc[t], m, 64);
    }

    if (eg == 0) {
        float iv = invd[n];
        us8 ov;
#pragma unroll
        for (int t = 0; t < 8; ++t) ov[t] = f2bf(acc[t] * iv);
        *(us8*)(aggb + (size_t)n * D + c * 8) = ov;
    }
}

// ---------------------------------------------------------------------------
// Weight-stationary MFMA layer (grid-stride over 64-node tiles)
// ---------------------------------------------------------------------------
template<int K, int H, bool NEIGH, bool RELU, bool OBF, bool OFP8>
__global__ __launch_bounds__(256)
void mfma_layer(const ushort_t* __restrict__ xb, const ushort_t* __restrict__ gb,
                const ushort_t* __restrict__ wsT, const ushort_t* __restrict__ wnT,
                const float* __restrict__ bias, void* __restrict__ out,
                uchar_t* __restrict__ outq, int nn) {
    constexpr int CH   = K / 8;
    constexpr int KS   = K / 32;
    constexpr int WTPW = H / 64;
    constexpr int PF   = CH / 4;

    __shared__ us8 xs[64][CH];
    __shared__ us8 gs[NEIGH ? 64 : 1][NEIGH ? CH : 1];

    const int tid  = threadIdx.x;
    const int lane = tid & 63;
    const int w    = tid >> 6;
    const int lr   = lane & 15;
    const int lk   = lane >> 4;

    s16x8 bws[WTPW][KS];
    s16x8 bwn[NEIGH ? WTPW : 1][NEIGH ? KS : 1];
#pragma unroll
    for (int t = 0; t < WTPW; ++t) {
        const size_t hrow = (size_t)((w * WTPW + t) * 16 + lr) * K;
#pragma unroll
        for (int ks = 0; ks < KS; ++ks) {
            bws[t][ks] = *(const s16x8*)(wsT + hrow + ks * 32 + lk * 8);
            if constexpr (NEIGH)
                bwn[t][ks] = *(const s16x8*)(wnT + hrow + ks * 32 + lk * 8);
        }
    }
    float bv[WTPW];
#pragma unroll
    for (int t = 0; t < WTPW; ++t) bv[t] = bias[(w * WTPW + t) * 16 + lr];

    const int ntiles = (nn + 63) >> 6;
    us8 pfx[PF], pfg[NEIGH ? PF : 1];
    const us8 z8 = {0, 0, 0, 0, 0, 0, 0, 0};

    auto loadpf = [&](int T) {
        const int base = T * 64;
#pragma unroll
        for (int q = 0; q < PF; ++q) {
            int idx = tid + q * 256, r = idx / CH, c = idx % CH, n = base + r;
            pfx[q] = (n < nn) ? *(const us8*)(xb + (size_t)n * K + c * 8) : z8;
            if constexpr (NEIGH)
                pfg[q] = (n < nn) ? *(const us8*)(gb + (size_t)n * K + c * 8) : z8;
        }
    };

    int tile = blockIdx.x;
    if (tile >= ntiles) return;
    loadpf(tile);

    while (true) {
        __syncthreads();
#pragma unroll
        for (int q = 0; q < PF; ++q) {
            int idx = tid + q * 256, r = idx / CH, c = idx % CH;
            int cs = c ^ (r & 7);
            xs[r][cs] = pfx[q];
            if constexpr (NEIGH) gs[r][cs] = pfg[q];
        }
        __syncthreads();

        const int row0 = tile * 64;
        tile += gridDim.x;
        if (tile < ntiles) loadpf(tile);

        f32x4 acc[4][WTPW];
#pragma unroll
        for (int rg = 0; rg < 4; ++rg)
#pragma unroll
            for (int t = 0; t < WTPW; ++t) acc[rg][t] = {0.f, 0.f, 0.f, 0.f};

#pragma unroll
        for (int rg = 0; rg < 4; ++rg) {
            const int R = rg * 16 + lr;
#pragma unroll
            for (int ks = 0; ks < KS; ++ks) {
                const int cs = (ks * 4 + lk) ^ (R & 7);
                s16x8 ax = (s16x8)xs[R][cs];
                s16x8 ag;
                if constexpr (NEIGH) ag = (s16x8)gs[R][cs];
#pragma unroll
                for (int t = 0; t < WTPW; ++t) {
                    acc[rg][t] = __builtin_amdgcn_mfma_f32_16x16x32_bf16(ax, bws[t][ks], acc[rg][t], 0, 0, 0);
                    if constexpr (NEIGH)
                        acc[rg][t] = __builtin_amdgcn_mfma_f32_16x16x32_bf16(ag, bwn[t][ks], acc[rg][t], 0, 0, 0);
                }
            }
        }

#pragma unroll
        for (int rg = 0; rg < 4; ++rg) {
#pragma unroll
            for (int t = 0; t < WTPW; ++t) {
                const int h = (w * WTPW + t) * 16 + lr;
#pragma unroll
                for (int j = 0; j < 4; ++j) {
                    int n = row0 + rg * 16 + lk * 4 + j;
                    if (n < nn) {
                        float v = acc[rg][t][j] + bv[t];
                        if constexpr (RELU) v = fmaxf(v, 0.f);
                        if constexpr (OBF)
                            ((ushort_t*)out)[(size_t)n * H + h] = f2bf(v);
                        else
                            ((float*)out)[(size_t)n * H + h] = v;
                        if constexpr (OFP8)
                            outq[(size_t)n * H + h] = f2fp8(v);
                    }
                }
            }
        }

        if (tile >= ntiles) break;
    }
}

// ---------------------------------------------------------------------------
extern "C" void kernel_launch(void* const* d_in, const int* in_sizes, int n_in,
                              void* d_out, int out_size, void* d_ws, size_t ws_size,
                              hipStream_t stream) {
    const float* feat = (const float*)d_in[0];
    const float* Wn1  = (const float*)d_in[1];
    const float* Ws1  = (const float*)d_in[2];
    const float* b1   = (const float*)d_in[3];
    const float* Wn2  = (const float*)d_in[4];
    const float* Ws2  = (const float*)d_in[5];
    const float* b2   = (const float*)d_in[6];
    const float* Wm1  = (const float*)d_in[7];
    const float* bm1  = (const float*)d_in[8];
    const float* Wm2  = (const float*)d_in[9];
    const float* bm2  = (const float*)d_in[10];
    const int*   src  = (const int*)d_in[11];
    const int*   dst  = (const int*)d_in[12];

    const int nn = in_sizes[0] / N_IN;    // 100000
    const int E  = in_sizes[11];          // 1600000

    // ---- workspace carve-up (64B-aligned) ----
    char* p = (char*)d_ws;
    auto alloc = [&](size_t bytes) { void* q = p; p += (bytes + 63) & ~(size_t)63; return q; };
    int*      degi     = (int*)alloc((size_t)nn * 4);
    int*      offs     = (int*)alloc((size_t)(nn + 1) * 4);
    int*      partials = (int*)alloc(1024 * 4);
    float*    invd     = (float*)alloc((size_t)nn * 4);
    int*      rank     = (int*)alloc((size_t)E * 4);
    int*      csr_src  = (int*)alloc((size_t)E * 4);
    ushort_t* wsT1     = (ushort_t*)alloc((size_t)N_IN * HID * 2);
    ushort_t* wnT1     = (ushort_t*)alloc((size_t)N_IN * HID * 2);
    ushort_t* wsT2     = (ushort_t*)alloc((size_t)HID * HID * 2);
    ushort_t* wnT2     = (ushort_t*)alloc((size_t)HID * HID * 2);
    ushort_t* wmT1     = (ushort_t*)alloc((size_t)HID * HID * 2);
    ushort_t* wmT2     = (ushort_t*)alloc((size_t)HID * OUT_F * 2);
    ushort_t* featb    = (ushort_t*)alloc((size_t)nn * N_IN * 2);
    uchar_t*  x1q      = (uchar_t*)alloc((size_t)nn * HID);
    ushort_t* x2b      = featb;                       // featb+x1q dead by then
    ushort_t* x1b      = (ushort_t*)alloc((size_t)nn * HID * 2);
    ushort_t* x3b      = x1b;                         // x1b dead after mfma2
    ushort_t* agg2b    = (ushort_t*)alloc((size_t)nn * HID * 2);
    ushort_t* agg1b    = (ushort_t*)d_out;            // dead before final GEMM
    uchar_t*  featq    = (uchar_t*)d_out + (size_t)nn * N_IN * 2;

    const int nparts = (nn + 255) / 256;
    const int ntiles = (nn + 63) / 64;
    const int NB     = ntiles < 768 ? ntiles : 768;
    const int n8     = nn * (N_IN / 8);
    const int BA     = (n8 + 255) / 256;              // feat-cvt blocks
    const int BB     = BA + (73728 + 255) / 256;      // + weight-cvt blocks
    const int BC     = BB + (E + 255) / 256;          // + deg_rank blocks

    hipMemsetAsync(degi, 0, (size_t)nn * sizeof(int), stream);

    // ---- fused prep: conversions + degree/rank ----
    prep_kernel<<<BC, 256, 0, stream>>>(
        feat, featb, featq, n8,
        Ws1, Wn1, Ws2, Wn2, Wm1, Wm2,
        wsT1, wnT1, wsT2, wnT2, wmT1, wmT2,
        dst, degi, rank, E, BA, BB);

    // ---- CSR build ----
    scan_block<<<nparts, 256, 0, stream>>>(degi, offs, partials, nn);
    scan_partials<<<1, 1024, 0, stream>>>(partials, nparts);
    finalize_offs<<<(nn + 256) / 256, 256, 0, stream>>>(offs, invd, partials, degi, nn, E);
    place2<<<(E + 255) / 256, 256, 0, stream>>>(src, dst, rank, offs, csr_src, E);

    // ---- layer 1 ----
    gather_fp8<N_IN><<<(nn + 3) / 4, 256, 0, stream>>>(
        featq, csr_src, offs, invd, agg1b, nn);
    mfma_layer<N_IN, HID, true, true, true, true><<<NB, 256, 0, stream>>>(
        featb, agg1b, wsT1, wnT1, b1, x1b, x1q, nn);

    // ---- layer 2 ----
    gather_fp8<HID><<<(nn + 3) / 4, 256, 0, stream>>>(
        x1q, csr_src, offs, invd, agg2b, nn);
    mfma_layer<HID, HID, true, true, true, false><<<NB, 256, 0, stream>>>(
        x1b, agg2b, wsT2, wnT2, b2, x2b, nullptr, nn);

    // ---- MLP ----
    mfma_layer<HID, HID, false, true, true, false><<<NB, 256, 0, stream>>>(
        x2b, nullptr, wmT1, nullptr, bm1, x3b, nullptr, nn);
    mfma_layer<HID, OUT_F, false, false, false, false><<<NB, 256, 0, stream>>>(
        x3b, nullptr, wmT2, nullptr, bm2, (float*)d_out, nullptr, nn);
}

// Round 10
// 281.770 us; speedup vs baseline: 1.9081x; 1.0525x over previous
//
#include <hip/hip_runtime.h>
#include <hip/hip_fp8.h>

#define N_IN 64
#define HID 128
#define OUT_F 64
#define EPB 2048          // edges per partition block (8 iters x 256)

typedef unsigned short ushort_t;
typedef unsigned char  uchar_t;
typedef unsigned long long ull_t;
typedef ushort_t us8  __attribute__((ext_vector_type(8)));
typedef uchar_t  uc8  __attribute__((ext_vector_type(8)));
typedef short    s16x8 __attribute__((ext_vector_type(8)));
typedef float    f32x4 __attribute__((ext_vector_type(4)));
typedef unsigned int uint2v __attribute__((ext_vector_type(2)));

__device__ inline ushort_t f2bf(float f) {          // round-to-nearest-even
    unsigned u = __float_as_uint(f);
    u = u + 0x7fffu + ((u >> 16) & 1u);
    return (ushort_t)(u >> 16);
}
__device__ inline float bf2f(ushort_t b) {
    return __uint_as_float((unsigned)b << 16);
}
__device__ inline uchar_t f2fp8(float v) {          // OCP e4m3
    __hip_fp8_e4m3 q(v);
    return (uchar_t)q.__x;
}
__device__ inline void fp8x4_to_f32(unsigned int dw, float* o) {
#if __has_builtin(__builtin_amdgcn_cvt_pk_f32_fp8)
    auto lo = __builtin_amdgcn_cvt_pk_f32_fp8(dw, false);
    auto hi = __builtin_amdgcn_cvt_pk_f32_fp8(dw, true);
    o[0] = lo[0]; o[1] = lo[1]; o[2] = hi[0]; o[3] = hi[1];
#else
#pragma unroll
    for (int i = 0; i < 4; ++i) {
        __hip_fp8_e4m3 h; h.__x = (dw >> (8 * i)) & 0xff;
        o[i] = (float)h;
    }
#endif
}

// ---------------------------------------------------------------------------
// fused prep:
//   [0,BA)   feat fp32 -> bf16 + fp8
//   [BA,BB)  weights -> bf16 transposed
//   [BB,BC)  pass A: per-block bucket histogram (LDS atomics only)
// ---------------------------------------------------------------------------
__global__ __launch_bounds__(256)
void prep_kernel(const float* __restrict__ feat, ushort_t* __restrict__ featb,
                 uchar_t* __restrict__ featq, int n8,
                 const float* __restrict__ Ws1, const float* __restrict__ Wn1,
                 const float* __restrict__ Ws2, const float* __restrict__ Wn2,
                 const float* __restrict__ Wm1, const float* __restrict__ Wm2,
                 ushort_t* __restrict__ wsT1, ushort_t* __restrict__ wnT1,
                 ushort_t* __restrict__ wsT2, ushort_t* __restrict__ wnT2,
                 ushort_t* __restrict__ wmT1, ushort_t* __restrict__ wmT2,
                 const int* __restrict__ dst, int* __restrict__ histT,
                 int E, int nbuk, int nba, int BA, int BB) {
    __shared__ int hist[256];
    int b = blockIdx.x;
    int tid = threadIdx.x;
    if (b < BA) {
        int i = b * 256 + tid;
        if (i >= n8) return;
        f32x4 a = ((const f32x4*)feat)[2 * i];
        f32x4 c = ((const f32x4*)feat)[2 * i + 1];
        us8 v; uc8 q;
#pragma unroll
        for (int t = 0; t < 4; ++t) {
            v[t] = f2bf(a[t]); v[4 + t] = f2bf(c[t]);
            q[t] = f2fp8(a[t]); q[4 + t] = f2fp8(c[t]);
        }
        ((us8*)featb)[i] = v;
        ((uc8*)featq)[i] = q;
    } else if (b < BB) {
        int i = (b - BA) * 256 + tid;
        const float* W; ushort_t* WT; int K, H, l;
        if      (i < 8192)  { W = Ws1; WT = wsT1; K = 64;  H = 128; l = i; }
        else if (i < 16384) { W = Wn1; WT = wnT1; K = 64;  H = 128; l = i - 8192; }
        else if (i < 32768) { W = Ws2; WT = wsT2; K = 128; H = 128; l = i - 16384; }
        else if (i < 49152) { W = Wn2; WT = wnT2; K = 128; H = 128; l = i - 32768; }
        else if (i < 65536) { W = Wm1; WT = wmT1; K = 128; H = 128; l = i - 49152; }
        else if (i < 73728) { W = Wm2; WT = wmT2; K = 128; H = 64;  l = i - 65536; }
        else return;
        int h = l / K, k = l % K;
        WT[l] = f2bf(W[(size_t)k * H + h]);
    } else {
        const int blk  = b - BB;
        const int base = blk * EPB;
        if (tid < nbuk) hist[tid] = 0;
        __syncthreads();
#pragma unroll
        for (int it = 0; it < EPB / 256; ++it) {
            int e = base + it * 256 + tid;
            if (e < E) atomicAdd(&hist[(unsigned)dst[e] >> 9], 1);
        }
        __syncthreads();
        for (int k = tid; k < nbuk; k += 256)
            histT[(size_t)k * nba + blk] = hist[k];
    }
}

// ---------------------------------------------------------------------------
// generic scan (3 kernels): per-256 block scan, partials scan, add-back
// ---------------------------------------------------------------------------
__global__ __launch_bounds__(256)
void scan_block(const int* __restrict__ in, int* __restrict__ out,
                int* __restrict__ partials, int n) {
    __shared__ int sm[256];
    int i = blockIdx.x * 256 + threadIdx.x;
    int v = (i < n) ? in[i] : 0;
    sm[threadIdx.x] = v;
    __syncthreads();
    for (int d = 1; d < 256; d <<= 1) {
        int t = (threadIdx.x >= d) ? sm[threadIdx.x - d] : 0;
        __syncthreads();
        sm[threadIdx.x] += t;
        __syncthreads();
    }
    if (i < n) out[i] = sm[threadIdx.x] - v;
    if (threadIdx.x == 255) partials[blockIdx.x] = sm[255];
}

__global__ __launch_bounds__(1024)
void scan_partials(int* __restrict__ partials, int nparts) {
    __shared__ int sm[1024];
    int i = threadIdx.x;
    int v = (i < nparts) ? partials[i] : 0;
    sm[i] = v;
    __syncthreads();
    for (int d = 1; d < 1024; d <<= 1) {
        int t = (i >= d) ? sm[i - d] : 0;
        __syncthreads();
        sm[i] += t;
        __syncthreads();
    }
    if (i < nparts) partials[i] = sm[i] - v;
}

__global__ __launch_bounds__(256)
void scan_add(int* __restrict__ arr, const int* __restrict__ partials, int n) {
    int i = blockIdx.x * 256 + threadIdx.x;
    if (i < n) arr[i] += partials[i >> 8];
}

// ---------------------------------------------------------------------------
// pass C: bucket-partition edges; LDS cursors (no global atomics)
//   ebsd[pos] = (dst<<32) | src, pos within bucket segment
// ---------------------------------------------------------------------------
__global__ __launch_bounds__(256)
void part_edges(const int* __restrict__ src, const int* __restrict__ dst,
                const int* __restrict__ histT, ull_t* __restrict__ ebsd,
                int E, int nbuk, int nba) {
    __shared__ int cur[256];
    const int blk  = blockIdx.x;
    const int base = blk * EPB;
    const int tid  = threadIdx.x;
    for (int k = tid; k < nbuk; k += 256)
        cur[k] = histT[(size_t)k * nba + blk];
    __syncthreads();
#pragma unroll
    for (int it = 0; it < EPB / 256; ++it) {
        int e = base + it * 256 + tid;
        if (e < E) {
            int d = dst[e], s = src[e];
            int pos = atomicAdd(&cur[(unsigned)d >> 9], 1);
            ull_t pack = (ull_t)(unsigned)s | ((ull_t)(unsigned)d << 32);
            __builtin_nontemporal_store(pack, &ebsd[pos]);
        }
    }
}

// ---------------------------------------------------------------------------
// pass D: per-bucket CSR finalize (512 nodes, 512 threads):
//   LDS degree hist -> LDS scan -> offs/invd (coalesced) -> place csr_src
// ---------------------------------------------------------------------------
__global__ __launch_bounds__(512)
void build_bucket(const ull_t* __restrict__ ebsd, const int* __restrict__ histT,
                  int* __restrict__ offs, float* __restrict__ invd,
                  int* __restrict__ csr_src, int nn, int E, int nbuk, int nba) {
    __shared__ int sm[512];
    __shared__ int cur[512];
    const int b   = blockIdx.x;
    const int b0  = b << 9;
    const int tid = threadIdx.x;
    const int ebase = histT[(size_t)b * nba];
    const int eend  = (b == nbuk - 1) ? E : histT[(size_t)(b + 1) * nba];

    sm[tid] = 0;
    __syncthreads();
    for (int j = ebase + tid; j < eend; j += 512) {
        int d = (int)(ebsd[j] >> 32);
        atomicAdd(&sm[d - b0], 1);
    }
    __syncthreads();
    const int deg = sm[tid];
    // inclusive scan over 512
    for (int d = 1; d < 512; d <<= 1) {
        int t = (tid >= d) ? sm[tid - d] : 0;
        __syncthreads();
        sm[tid] += t;
        __syncthreads();
    }
    const int excl = sm[tid] - deg;
    const int n = b0 + tid;
    if (n < nn) {
        offs[n] = ebase + excl;
        invd[n] = 1.0f / fmaxf((float)deg, 1.0f);
    }
    if (b == nbuk - 1 && tid == 0) offs[nn] = E;
    cur[tid] = ebase + excl;
    __syncthreads();
    for (int j = ebase + tid; j < eend; j += 512) {
        ull_t p = ebsd[j];
        int s = (int)(unsigned)p;
        int d = (int)(p >> 32);
        int pos = atomicAdd(&cur[d - b0], 1);
        __builtin_nontemporal_store(s, &csr_src[pos]);
    }
}

// ---------------------------------------------------------------------------
// fp8 edge-parallel gather, wave = node, 8B per lane
// ---------------------------------------------------------------------------
template<int D>
__global__ __launch_bounds__(256)
void gather_fp8(const uchar_t* __restrict__ xq, const int* __restrict__ csr_src,
                const int* __restrict__ offs, const float* __restrict__ invd,
                ushort_t* __restrict__ aggb, int nn) {
    constexpr int C  = D / 8;
    constexpr int NE = 64 / C;
    const int n = (blockIdx.x * 256 + threadIdx.x) >> 6;
    if (n >= nn) return;
    const int lane = threadIdx.x & 63;
    const int c  = lane % C;
    const int eg = lane / C;
    const uchar_t* tab = xq + (size_t)c * 8;

    const int beg = offs[n], end = offs[n + 1];
    float acc[8] = {0.f, 0.f, 0.f, 0.f, 0.f, 0.f, 0.f, 0.f};

    int j = beg + eg;
    for (; j + NE < end; j += 2 * NE) {
        int s0 = csr_src[j], s1 = csr_src[j + NE];
        uint2v q0 = *(const uint2v*)(tab + (size_t)s0 * D);
        uint2v q1 = *(const uint2v*)(tab + (size_t)s1 * D);
        float f0[8], f1[8];
        fp8x4_to_f32(q0[0], f0); fp8x4_to_f32(q0[1], f0 + 4);
        fp8x4_to_f32(q1[0], f1); fp8x4_to_f32(q1[1], f1 + 4);
#pragma unroll
        for (int t = 0; t < 8; ++t) acc[t] += f0[t] + f1[t];
    }
    if (j < end) {
        int s = csr_src[j];
        uint2v q = *(const uint2v*)(tab + (size_t)s * D);
        float f[8];
        fp8x4_to_f32(q[0], f); fp8x4_to_f32(q[1], f + 4);
#pragma unroll
        for (int t = 0; t < 8; ++t) acc[t] += f[t];
    }

#pragma unroll
    for (int m = C; m < 64; m <<= 1) {
#pragma unroll
        for (int t = 0; t < 8; ++t) acc[t] += __shfl_xor(acc[t], m, 64);
    }

    if (eg == 0) {
        float iv = invd[n];
        us8 ov;
#pragma unroll
        for (int t = 0; t < 8; ++t) ov[t] = f2bf(acc[t] * iv);
        *(us8*)(aggb + (size_t)n * D + c * 8) = ov;
    }
}

// ---------------------------------------------------------------------------
// Weight-stationary MFMA layer (grid-stride over 64-node tiles)
// ---------------------------------------------------------------------------
template<int K, int H, bool NEIGH, bool RELU, bool OBF, bool OFP8>
__global__ __launch_bounds__(256)
void mfma_layer(const ushort_t* __restrict__ xb, const ushort_t* __restrict__ gb,
                const ushort_t* __restrict__ wsT, const ushort_t* __restrict__ wnT,
                const float* __restrict__ bias, void* __restrict__ out,
                uchar_t* __restrict__ outq, int nn) {
    constexpr int CH   = K / 8;
    constexpr int KS   = K / 32;
    constexpr int WTPW = H / 64;
    constexpr int PF   = CH / 4;

    __shared__ us8 xs[64][CH];
    __shared__ us8 gs[NEIGH ? 64 : 1][NEIGH ? CH : 1];

    const int tid  = threadIdx.x;
    const int lane = tid & 63;
    const int w    = tid >> 6;
    const int lr   = lane & 15;
    const int lk   = lane >> 4;

    s16x8 bws[WTPW][KS];
    s16x8 bwn[NEIGH ? WTPW : 1][NEIGH ? KS : 1];
#pragma unroll
    for (int t = 0; t < WTPW; ++t) {
        const size_t hrow = (size_t)((w * WTPW + t) * 16 + lr) * K;
#pragma unroll
        for (int ks = 0; ks < KS; ++ks) {
            bws[t][ks] = *(const s16x8*)(wsT + hrow + ks * 32 + lk * 8);
            if constexpr (NEIGH)
                bwn[t][ks] = *(const s16x8*)(wnT + hrow + ks * 32 + lk * 8);
        }
    }
    float bv[WTPW];
#pragma unroll
    for (int t = 0; t < WTPW; ++t) bv[t] = bias[(w * WTPW + t) * 16 + lr];

    const int ntiles = (nn + 63) >> 6;
    us8 pfx[PF], pfg[NEIGH ? PF : 1];
    const us8 z8 = {0, 0, 0, 0, 0, 0, 0, 0};

    auto loadpf = [&](int T) {
        const int base = T * 64;
#pragma unroll
        for (int q = 0; q < PF; ++q) {
            int idx = tid + q * 256, r = idx / CH, c = idx % CH, n = base + r;
            pfx[q] = (n < nn) ? *(const us8*)(xb + (size_t)n * K + c * 8) : z8;
            if constexpr (NEIGH)
                pfg[q] = (n < nn) ? *(const us8*)(gb + (size_t)n * K + c * 8) : z8;
        }
    };

    int tile = blockIdx.x;
    if (tile >= ntiles) return;
    loadpf(tile);

    while (true) {
        __syncthreads();
#pragma unroll
        for (int q = 0; q < PF; ++q) {
            int idx = tid + q * 256, r = idx / CH, c = idx % CH;
            int cs = c ^ (r & 7);
            xs[r][cs] = pfx[q];
            if constexpr (NEIGH) gs[r][cs] = pfg[q];
        }
        __syncthreads();

        const int row0 = tile * 64;
        tile += gridDim.x;
        if (tile < ntiles) loadpf(tile);

        f32x4 acc[4][WTPW];
#pragma unroll
        for (int rg = 0; rg < 4; ++rg)
#pragma unroll
            for (int t = 0; t < WTPW; ++t) acc[rg][t] = {0.f, 0.f, 0.f, 0.f};

#pragma unroll
        for (int rg = 0; rg < 4; ++rg) {
            const int R = rg * 16 + lr;
#pragma unroll
            for (int ks = 0; ks < KS; ++ks) {
                const int cs = (ks * 4 + lk) ^ (R & 7);
                s16x8 ax = (s16x8)xs[R][cs];
                s16x8 ag;
                if constexpr (NEIGH) ag = (s16x8)gs[R][cs];
#pragma unroll
                for (int t = 0; t < WTPW; ++t) {
                    acc[rg][t] = __builtin_amdgcn_mfma_f32_16x16x32_bf16(ax, bws[t][ks], acc[rg][t], 0, 0, 0);
                    if constexpr (NEIGH)
                        acc[rg][t] = __builtin_amdgcn_mfma_f32_16x16x32_bf16(ag, bwn[t][ks], acc[rg][t], 0, 0, 0);
                }
            }
        }

#pragma unroll
        for (int rg = 0; rg < 4; ++rg) {
#pragma unroll
            for (int t = 0; t < WTPW; ++t) {
                const int h = (w * WTPW + t) * 16 + lr;
#pragma unroll
                for (int j = 0; j < 4; ++j) {
                    int n = row0 + rg * 16 + lk * 4 + j;
                    if (n < nn) {
                        float v = acc[rg][t][j] + bv[t];
                        if constexpr (RELU) v = fmaxf(v, 0.f);
                        if constexpr (OBF)
                            ((ushort_t*)out)[(size_t)n * H + h] = f2bf(v);
                        else
                            ((float*)out)[(size_t)n * H + h] = v;
                        if constexpr (OFP8)
                            outq[(size_t)n * H + h] = f2fp8(v);
                    }
                }
            }
        }

        if (tile >= ntiles) break;
    }
}

// ---------------------------------------------------------------------------
extern "C" void kernel_launch(void* const* d_in, const int* in_sizes, int n_in,
                              void* d_out, int out_size, void* d_ws, size_t ws_size,
                              hipStream_t stream) {
    const float* feat = (const float*)d_in[0];
    const float* Wn1  = (const float*)d_in[1];
    const float* Ws1  = (const float*)d_in[2];
    const float* b1   = (const float*)d_in[3];
    const float* Wn2  = (const float*)d_in[4];
    const float* Ws2  = (const float*)d_in[5];
    const float* b2   = (const float*)d_in[6];
    const float* Wm1  = (const float*)d_in[7];
    const float* bm1  = (const float*)d_in[8];
    const float* Wm2  = (const float*)d_in[9];
    const float* bm2  = (const float*)d_in[10];
    const int*   src  = (const int*)d_in[11];
    const int*   dst  = (const int*)d_in[12];

    const int nn = in_sizes[0] / N_IN;    // 100000
    const int E  = in_sizes[11];          // 1600000

    const int nbuk  = (nn + 511) >> 9;    // buckets of 512 nodes (196)
    const int nba   = (E + EPB - 1) / EPB;// partition blocks (782)
    const int nhist = nbuk * nba;

    // ---- workspace carve-up (64B-aligned) ----
    char* p = (char*)d_ws;
    auto alloc = [&](size_t bytes) { void* q = p; p += (bytes + 63) & ~(size_t)63; return q; };
    int*      offs     = (int*)alloc((size_t)(nn + 1) * 4);
    int*      partials = (int*)alloc(1024 * 4);
    float*    invd     = (float*)alloc((size_t)nn * 4);
    int*      histT    = (int*)alloc((size_t)nhist * 4);
    ull_t*    ebsd     = (ull_t*)alloc((size_t)E * 8);
    int*      csr_src  = (int*)alloc((size_t)E * 4);
    ushort_t* wsT1     = (ushort_t*)alloc((size_t)N_IN * HID * 2);
    ushort_t* wnT1     = (ushort_t*)alloc((size_t)N_IN * HID * 2);
    ushort_t* wsT2     = (ushort_t*)alloc((size_t)HID * HID * 2);
    ushort_t* wnT2     = (ushort_t*)alloc((size_t)HID * HID * 2);
    ushort_t* wmT1     = (ushort_t*)alloc((size_t)HID * HID * 2);
    ushort_t* wmT2     = (ushort_t*)alloc((size_t)HID * OUT_F * 2);
    ushort_t* featb    = (ushort_t*)alloc((size_t)nn * N_IN * 2);
    uchar_t*  x1q      = (uchar_t*)alloc((size_t)nn * HID);
    ushort_t* x2b      = featb;                       // featb+x1q dead by then
    ushort_t* x1b      = (ushort_t*)alloc((size_t)nn * HID * 2);
    ushort_t* x3b      = x1b;                         // x1b dead after mfma2
    ushort_t* agg2b    = (ushort_t*)alloc((size_t)nn * HID * 2);
    ushort_t* agg1b    = (ushort_t*)d_out;            // dead before final GEMM
    uchar_t*  featq    = (uchar_t*)d_out + (size_t)nn * N_IN * 2;

    const int ntiles = (nn + 63) / 64;
    const int NB     = ntiles < 768 ? ntiles : 768;
    const int n8     = nn * (N_IN / 8);
    const int BA     = (n8 + 255) / 256;              // feat-cvt blocks
    const int BB     = BA + (73728 + 255) / 256;      // + weight-cvt blocks
    const int BC     = BB + nba;                      // + pass-A blocks

    // ---- fused prep: conversions + bucket histograms ----
    prep_kernel<<<BC, 256, 0, stream>>>(
        feat, featb, featq, n8,
        Ws1, Wn1, Ws2, Wn2, Wm1, Wm2,
        wsT1, wnT1, wsT2, wnT2, wmT1, wmT2,
        dst, histT, E, nbuk, nba, BA, BB);

    // ---- scan histT (atomic-free CSR offsets) ----
    const int nparts = (nhist + 255) / 256;
    scan_block<<<nparts, 256, 0, stream>>>(histT, histT, partials, nhist);
    scan_partials<<<1, 1024, 0, stream>>>(partials, nparts);
    scan_add<<<nparts, 256, 0, stream>>>(histT, partials, nhist);

    // ---- partition + per-bucket CSR build ----
    part_edges<<<nba, 256, 0, stream>>>(src, dst, histT, ebsd, E, nbuk, nba);
    build_bucket<<<nbuk, 512, 0, stream>>>(ebsd, histT, offs, invd, csr_src, nn, E, nbuk, nba);

    // ---- layer 1 ----
    gather_fp8<N_IN><<<(nn + 3) / 4, 256, 0, stream>>>(
        featq, csr_src, offs, invd, agg1b, nn);
    mfma_layer<N_IN, HID, true, true, true, true><<<NB, 256, 0, stream>>>(
        featb, agg1b, wsT1, wnT1, b1, x1b, x1q, nn);

    // ---- layer 2 ----
    gather_fp8<HID><<<(nn + 3) / 4, 256, 0, stream>>>(
        x1q, csr_src, offs, invd, agg2b, nn);
    mfma_layer<HID, HID, true, true, true, false><<<NB, 256, 0, stream>>>(
        x1b, agg2b, wsT2, wnT2, b2, x2b, nullptr, nn);

    // ---- MLP ----
    mfma_layer<HID, HID, false, true, true, false><<<NB, 256, 0, stream>>>(
        x2b, nullptr, wmT1, nullptr, bm1, x3b, nullptr, nn);
    mfma_layer<HID, OUT_F, false, false, false, false><<<NB, 256, 0, stream>>>(
        x3b, nullptr, wmT2, nullptr, bm2, (float*)d_out, nullptr, nn);
}

// Round 11
// 208.905 us; speedup vs baseline: 2.5736x; 1.3488x over previous
//
#include <hip/hip_runtime.h>
#include <hip/hip_fp8.h>

#define N_IN 64
#define HID 128
#define OUT_F 64
#define EPB 6144          // edges per partition block (24 iters x 256)
#define BKT 128           // nodes per bucket

typedef unsigned short ushort_t;
typedef unsigned char  uchar_t;
typedef unsigned long long ull_t;
typedef ushort_t us8  __attribute__((ext_vector_type(8)));
typedef uchar_t  uc8  __attribute__((ext_vector_type(8)));
typedef short    s16x8 __attribute__((ext_vector_type(8)));
typedef float    f32x4 __attribute__((ext_vector_type(4)));
typedef unsigned int uint2v __attribute__((ext_vector_type(2)));

__device__ inline ushort_t f2bf(float f) {          // round-to-nearest-even
    unsigned u = __float_as_uint(f);
    u = u + 0x7fffu + ((u >> 16) & 1u);
    return (ushort_t)(u >> 16);
}
__device__ inline float bf2f(ushort_t b) {
    return __uint_as_float((unsigned)b << 16);
}
__device__ inline uchar_t f2fp8(float v) {          // OCP e4m3
    __hip_fp8_e4m3 q(v);
    return (uchar_t)q.__x;
}
__device__ inline void fp8x4_to_f32(unsigned int dw, float* o) {
#if __has_builtin(__builtin_amdgcn_cvt_pk_f32_fp8)
    auto lo = __builtin_amdgcn_cvt_pk_f32_fp8(dw, false);
    auto hi = __builtin_amdgcn_cvt_pk_f32_fp8(dw, true);
    o[0] = lo[0]; o[1] = lo[1]; o[2] = hi[0]; o[3] = hi[1];
#else
#pragma unroll
    for (int i = 0; i < 4; ++i) {
        __hip_fp8_e4m3 h; h.__x = (dw >> (8 * i)) & 0xff;
        o[i] = (float)h;
    }
#endif
}

// ---------------------------------------------------------------------------
// fused prep:
//   [0,BA)   feat fp32 -> bf16 + fp8
//   [BA,BB)  weights -> bf16 transposed
//   [BB,BC)  pass A: per-block bucket histogram (LDS atomics only)
// ---------------------------------------------------------------------------
__global__ __launch_bounds__(256)
void prep_kernel(const float* __restrict__ feat, ushort_t* __restrict__ featb,
                 uchar_t* __restrict__ featq, int n8,
                 const float* __restrict__ Ws1, const float* __restrict__ Wn1,
                 const float* __restrict__ Ws2, const float* __restrict__ Wn2,
                 const float* __restrict__ Wm1, const float* __restrict__ Wm2,
                 ushort_t* __restrict__ wsT1, ushort_t* __restrict__ wnT1,
                 ushort_t* __restrict__ wsT2, ushort_t* __restrict__ wnT2,
                 ushort_t* __restrict__ wmT1, ushort_t* __restrict__ wmT2,
                 const int* __restrict__ dst, int* __restrict__ histT,
                 int E, int nbuk, int nba, int BA, int BB) {
    __shared__ int hist[800];
    int b = blockIdx.x;
    int tid = threadIdx.x;
    if (b < BA) {
        int i = b * 256 + tid;
        if (i >= n8) return;
        f32x4 a = ((const f32x4*)feat)[2 * i];
        f32x4 c = ((const f32x4*)feat)[2 * i + 1];
        us8 v; uc8 q;
#pragma unroll
        for (int t = 0; t < 4; ++t) {
            v[t] = f2bf(a[t]); v[4 + t] = f2bf(c[t]);
            q[t] = f2fp8(a[t]); q[4 + t] = f2fp8(c[t]);
        }
        ((us8*)featb)[i] = v;
        ((uc8*)featq)[i] = q;
    } else if (b < BB) {
        int i = (b - BA) * 256 + tid;
        const float* W; ushort_t* WT; int K, H, l;
        if      (i < 8192)  { W = Ws1; WT = wsT1; K = 64;  H = 128; l = i; }
        else if (i < 16384) { W = Wn1; WT = wnT1; K = 64;  H = 128; l = i - 8192; }
        else if (i < 32768) { W = Ws2; WT = wsT2; K = 128; H = 128; l = i - 16384; }
        else if (i < 49152) { W = Wn2; WT = wnT2; K = 128; H = 128; l = i - 32768; }
        else if (i < 65536) { W = Wm1; WT = wmT1; K = 128; H = 128; l = i - 49152; }
        else if (i < 73728) { W = Wm2; WT = wmT2; K = 128; H = 64;  l = i - 65536; }
        else return;
        int h = l / K, k = l % K;
        WT[l] = f2bf(W[(size_t)k * H + h]);
    } else {
        const int blk  = b - BB;
        const int base = blk * EPB;
        for (int k = tid; k < nbuk; k += 256) hist[k] = 0;
        __syncthreads();
#pragma unroll
        for (int it = 0; it < EPB / 256; ++it) {
            int e = base + it * 256 + tid;
            if (e < E) atomicAdd(&hist[(unsigned)dst[e] / BKT], 1);
        }
        __syncthreads();
        for (int k = tid; k < nbuk; k += 256)
            histT[(size_t)k * nba + blk] = hist[k];
    }
}

// ---------------------------------------------------------------------------
// generic scan (3 kernels)
// ---------------------------------------------------------------------------
__global__ __launch_bounds__(256)
void scan_block(const int* __restrict__ in, int* __restrict__ out,
                int* __restrict__ partials, int n) {
    __shared__ int sm[256];
    int i = blockIdx.x * 256 + threadIdx.x;
    int v = (i < n) ? in[i] : 0;
    sm[threadIdx.x] = v;
    __syncthreads();
    for (int d = 1; d < 256; d <<= 1) {
        int t = (threadIdx.x >= d) ? sm[threadIdx.x - d] : 0;
        __syncthreads();
        sm[threadIdx.x] += t;
        __syncthreads();
    }
    if (i < n) out[i] = sm[threadIdx.x] - v;
    if (threadIdx.x == 255) partials[blockIdx.x] = sm[255];
}

__global__ __launch_bounds__(1024)
void scan_partials(int* __restrict__ partials, int nparts) {
    __shared__ int sm[1024];
    int i = threadIdx.x;
    int v = (i < nparts) ? partials[i] : 0;
    sm[i] = v;
    __syncthreads();
    for (int d = 1; d < 1024; d <<= 1) {
        int t = (i >= d) ? sm[i - d] : 0;
        __syncthreads();
        sm[i] += t;
        __syncthreads();
    }
    if (i < nparts) partials[i] = sm[i] - v;
}

__global__ __launch_bounds__(256)
void scan_add(int* __restrict__ arr, const int* __restrict__ partials, int n) {
    int i = blockIdx.x * 256 + threadIdx.x;
    if (i < n) arr[i] += partials[i >> 8];
}

// ---------------------------------------------------------------------------
// pass C: bucket-partition edges; LDS cursors; CACHED stores (L2 re-read soon)
// ---------------------------------------------------------------------------
__global__ __launch_bounds__(256)
void part_edges(const int* __restrict__ src, const int* __restrict__ dst,
                const int* __restrict__ histT, ull_t* __restrict__ ebsd,
                int E, int nbuk, int nba) {
    __shared__ int cur[800];
    const int blk  = blockIdx.x;
    const int base = blk * EPB;
    const int tid  = threadIdx.x;
    for (int k = tid; k < nbuk; k += 256)
        cur[k] = histT[(size_t)k * nba + blk];
    __syncthreads();
#pragma unroll
    for (int it = 0; it < EPB / 256; ++it) {
        int e = base + it * 256 + tid;
        if (e < E) {
            int d = dst[e], s = src[e];
            int pos = atomicAdd(&cur[(unsigned)d / BKT], 1);
            ebsd[pos] = (ull_t)(unsigned)s | ((ull_t)(unsigned)d << 32);
        }
    }
}

// ---------------------------------------------------------------------------
// pass D: per-bucket CSR finalize (BKT=128 nodes, 256 threads, 782 blocks)
// ---------------------------------------------------------------------------
__global__ __launch_bounds__(256)
void build_bucket(const ull_t* __restrict__ ebsd, const int* __restrict__ histT,
                  int* __restrict__ offs, float* __restrict__ invd,
                  int* __restrict__ csr_src, int nn, int E, int nbuk, int nba) {
    __shared__ int sm[BKT];
    __shared__ int cur[BKT];
    const int b   = blockIdx.x;
    const int b0  = b * BKT;
    const int tid = threadIdx.x;
    const int ebase = histT[(size_t)b * nba];
    const int eend  = (b == nbuk - 1) ? E : histT[(size_t)(b + 1) * nba];

    if (tid < BKT) sm[tid] = 0;
    __syncthreads();
    for (int j = ebase + tid; j < eend; j += 256) {
        int d = (int)(ebsd[j] >> 32);
        atomicAdd(&sm[d - b0], 1);
    }
    __syncthreads();
    const int deg = (tid < BKT) ? sm[tid] : 0;
    // inclusive scan over BKT (all threads hit barriers)
    for (int d = 1; d < BKT; d <<= 1) {
        int t = (tid >= d && tid < BKT) ? sm[tid - d] : 0;
        __syncthreads();
        if (tid < BKT) sm[tid] += t;
        __syncthreads();
    }
    if (tid < BKT) {
        const int excl = sm[tid] - deg;
        const int n = b0 + tid;
        if (n < nn) {
            offs[n] = ebase + excl;
            invd[n] = 1.0f / fmaxf((float)deg, 1.0f);
        }
        if (b == nbuk - 1 && tid == 0) offs[nn] = E;
        cur[tid] = ebase + excl;
    }
    __syncthreads();
    for (int j = ebase + tid; j < eend; j += 256) {
        ull_t p = ebsd[j];
        int s = (int)(unsigned)p;
        int d = (int)(p >> 32);
        int pos = atomicAdd(&cur[d - b0], 1);
        csr_src[pos] = s;
    }
}

// ---------------------------------------------------------------------------
// fp8 edge-parallel gather, wave = node, 8B per lane
// ---------------------------------------------------------------------------
template<int D>
__global__ __launch_bounds__(256)
void gather_fp8(const uchar_t* __restrict__ xq, const int* __restrict__ csr_src,
                const int* __restrict__ offs, const float* __restrict__ invd,
                ushort_t* __restrict__ aggb, int nn) {
    constexpr int C  = D / 8;
    constexpr int NE = 64 / C;
    const int n = (blockIdx.x * 256 + threadIdx.x) >> 6;
    if (n >= nn) return;
    const int lane = threadIdx.x & 63;
    const int c  = lane % C;
    const int eg = lane / C;
    const uchar_t* tab = xq + (size_t)c * 8;

    const int beg = offs[n], end = offs[n + 1];
    float acc[8] = {0.f, 0.f, 0.f, 0.f, 0.f, 0.f, 0.f, 0.f};

    int j = beg + eg;
    for (; j + NE < end; j += 2 * NE) {
        int s0 = csr_src[j], s1 = csr_src[j + NE];
        uint2v q0 = *(const uint2v*)(tab + (size_t)s0 * D);
        uint2v q1 = *(const uint2v*)(tab + (size_t)s1 * D);
        float f0[8], f1[8];
        fp8x4_to_f32(q0[0], f0); fp8x4_to_f32(q0[1], f0 + 4);
        fp8x4_to_f32(q1[0], f1); fp8x4_to_f32(q1[1], f1 + 4);
#pragma unroll
        for (int t = 0; t < 8; ++t) acc[t] += f0[t] + f1[t];
    }
    if (j < end) {
        int s = csr_src[j];
        uint2v q = *(const uint2v*)(tab + (size_t)s * D);
        float f[8];
        fp8x4_to_f32(q[0], f); fp8x4_to_f32(q[1], f + 4);
#pragma unroll
        for (int t = 0; t < 8; ++t) acc[t] += f[t];
    }

#pragma unroll
    for (int m = C; m < 64; m <<= 1) {
#pragma unroll
        for (int t = 0; t < 8; ++t) acc[t] += __shfl_xor(acc[t], m, 64);
    }

    if (eg == 0) {
        float iv = invd[n];
        us8 ov;
#pragma unroll
        for (int t = 0; t < 8; ++t) ov[t] = f2bf(acc[t] * iv);
        *(us8*)(aggb + (size_t)n * D + c * 8) = ov;
    }
}

// ---------------------------------------------------------------------------
// Weight-stationary MFMA layer (grid-stride over 64-node tiles)
// ---------------------------------------------------------------------------
template<int K, int H, bool NEIGH, bool RELU, bool OBF, bool OFP8>
__global__ __launch_bounds__(256)
void mfma_layer(const ushort_t* __restrict__ xb, const ushort_t* __restrict__ gb,
                const ushort_t* __restrict__ wsT, const ushort_t* __restrict__ wnT,
                const float* __restrict__ bias, void* __restrict__ out,
                uchar_t* __restrict__ outq, int nn) {
    constexpr int CH   = K / 8;
    constexpr int KS   = K / 32;
    constexpr int WTPW = H / 64;
    constexpr int PF   = CH / 4;

    __shared__ us8 xs[64][CH];
    __shared__ us8 gs[NEIGH ? 64 : 1][NEIGH ? CH : 1];

    const int tid  = threadIdx.x;
    const int lane = tid & 63;
    const int w    = tid >> 6;
    const int lr   = lane & 15;
    const int lk   = lane >> 4;

    s16x8 bws[WTPW][KS];
    s16x8 bwn[NEIGH ? WTPW : 1][NEIGH ? KS : 1];
#pragma unroll
    for (int t = 0; t < WTPW; ++t) {
        const size_t hrow = (size_t)((w * WTPW + t) * 16 + lr) * K;
#pragma unroll
        for (int ks = 0; ks < KS; ++ks) {
            bws[t][ks] = *(const s16x8*)(wsT + hrow + ks * 32 + lk * 8);
            if constexpr (NEIGH)
                bwn[t][ks] = *(const s16x8*)(wnT + hrow + ks * 32 + lk * 8);
        }
    }
    float bv[WTPW];
#pragma unroll
    for (int t = 0; t < WTPW; ++t) bv[t] = bias[(w * WTPW + t) * 16 + lr];

    const int ntiles = (nn + 63) >> 6;
    us8 pfx[PF], pfg[NEIGH ? PF : 1];
    const us8 z8 = {0, 0, 0, 0, 0, 0, 0, 0};

    auto loadpf = [&](int T) {
        const int base = T * 64;
#pragma unroll
        for (int q = 0; q < PF; ++q) {
            int idx = tid + q * 256, r = idx / CH, c = idx % CH, n = base + r;
            pfx[q] = (n < nn) ? *(const us8*)(xb + (size_t)n * K + c * 8) : z8;
            if constexpr (NEIGH)
                pfg[q] = (n < nn) ? *(const us8*)(gb + (size_t)n * K + c * 8) : z8;
        }
    };

    int tile = blockIdx.x;
    if (tile >= ntiles) return;
    loadpf(tile);

    while (true) {
        __syncthreads();
#pragma unroll
        for (int q = 0; q < PF; ++q) {
            int idx = tid + q * 256, r = idx / CH, c = idx % CH;
            int cs = c ^ (r & 7);
            xs[r][cs] = pfx[q];
            if constexpr (NEIGH) gs[r][cs] = pfg[q];
        }
        __syncthreads();

        const int row0 = tile * 64;
        tile += gridDim.x;
        if (tile < ntiles) loadpf(tile);

        f32x4 acc[4][WTPW];
#pragma unroll
        for (int rg = 0; rg < 4; ++rg)
#pragma unroll
            for (int t = 0; t < WTPW; ++t) acc[rg][t] = {0.f, 0.f, 0.f, 0.f};

#pragma unroll
        for (int rg = 0; rg < 4; ++rg) {
            const int R = rg * 16 + lr;
#pragma unroll
            for (int ks = 0; ks < KS; ++ks) {
                const int cs = (ks * 4 + lk) ^ (R & 7);
                s16x8 ax = (s16x8)xs[R][cs];
                s16x8 ag;
                if constexpr (NEIGH) ag = (s16x8)gs[R][cs];
#pragma unroll
                for (int t = 0; t < WTPW; ++t) {
                    acc[rg][t] = __builtin_amdgcn_mfma_f32_16x16x32_bf16(ax, bws[t][ks], acc[rg][t], 0, 0, 0);
                    if constexpr (NEIGH)
                        acc[rg][t] = __builtin_amdgcn_mfma_f32_16x16x32_bf16(ag, bwn[t][ks], acc[rg][t], 0, 0, 0);
                }
            }
        }

#pragma unroll
        for (int rg = 0; rg < 4; ++rg) {
#pragma unroll
            for (int t = 0; t < WTPW; ++t) {
                const int h = (w * WTPW + t) * 16 + lr;
#pragma unroll
                for (int j = 0; j < 4; ++j) {
                    int n = row0 + rg * 16 + lk * 4 + j;
                    if (n < nn) {
                        float v = acc[rg][t][j] + bv[t];
                        if constexpr (RELU) v = fmaxf(v, 0.f);
                        if constexpr (OBF)
                            ((ushort_t*)out)[(size_t)n * H + h] = f2bf(v);
                        else
                            ((float*)out)[(size_t)n * H + h] = v;
                        if constexpr (OFP8)
                            outq[(size_t)n * H + h] = f2fp8(v);
                    }
                }
            }
        }

        if (tile >= ntiles) break;
    }
}

// ---------------------------------------------------------------------------
extern "C" void kernel_launch(void* const* d_in, const int* in_sizes, int n_in,
                              void* d_out, int out_size, void* d_ws, size_t ws_size,
                              hipStream_t stream) {
    const float* feat = (const float*)d_in[0];
    const float* Wn1  = (const float*)d_in[1];
    const float* Ws1  = (const float*)d_in[2];
    const float* b1   = (const float*)d_in[3];
    const float* Wn2  = (const float*)d_in[4];
    const float* Ws2  = (const float*)d_in[5];
    const float* b2   = (const float*)d_in[6];
    const float* Wm1  = (const float*)d_in[7];
    const float* bm1  = (const float*)d_in[8];
    const float* Wm2  = (const float*)d_in[9];
    const float* bm2  = (const float*)d_in[10];
    const int*   src  = (const int*)d_in[11];
    const int*   dst  = (const int*)d_in[12];

    const int nn = in_sizes[0] / N_IN;    // 100000
    const int E  = in_sizes[11];          // 1600000

    const int nbuk  = (nn + BKT - 1) / BKT;   // 782 buckets of 128 nodes
    const int nba   = (E + EPB - 1) / EPB;    // 261 partition blocks
    const int nhist = nbuk * nba;             // ~204K

    // ---- workspace carve-up (64B-aligned) ----
    char* p = (char*)d_ws;
    auto alloc = [&](size_t bytes) { void* q = p; p += (bytes + 63) & ~(size_t)63; return q; };
    int*      offs     = (int*)alloc((size_t)(nn + 1) * 4);
    int*      partials = (int*)alloc(1024 * 4);
    float*    invd     = (float*)alloc((size_t)nn * 4);
    int*      histT    = (int*)alloc((size_t)nhist * 4);
    ull_t*    ebsd     = (ull_t*)alloc((size_t)E * 8);
    int*      csr_src  = (int*)alloc((size_t)E * 4);
    ushort_t* wsT1     = (ushort_t*)alloc((size_t)N_IN * HID * 2);
    ushort_t* wnT1     = (ushort_t*)alloc((size_t)N_IN * HID * 2);
    ushort_t* wsT2     = (ushort_t*)alloc((size_t)HID * HID * 2);
    ushort_t* wnT2     = (ushort_t*)alloc((size_t)HID * HID * 2);
    ushort_t* wmT1     = (ushort_t*)alloc((size_t)HID * HID * 2);
    ushort_t* wmT2     = (ushort_t*)alloc((size_t)HID * OUT_F * 2);
    ushort_t* featb    = (ushort_t*)alloc((size_t)nn * N_IN * 2);
    uchar_t*  x1q      = (uchar_t*)alloc((size_t)nn * HID);
    ushort_t* x2b      = featb;                       // featb+x1q dead by then
    ushort_t* x1b      = (ushort_t*)alloc((size_t)nn * HID * 2);
    ushort_t* x3b      = x1b;                         // x1b dead after mfma2
    ushort_t* agg2b    = (ushort_t*)alloc((size_t)nn * HID * 2);
    ushort_t* agg1b    = (ushort_t*)d_out;            // dead before final GEMM
    uchar_t*  featq    = (uchar_t*)d_out + (size_t)nn * N_IN * 2;

    const int ntiles = (nn + 63) / 64;
    const int NB     = ntiles < 768 ? ntiles : 768;
    const int n8     = nn * (N_IN / 8);
    const int BA     = (n8 + 255) / 256;              // feat-cvt blocks
    const int BB     = BA + (73728 + 255) / 256;      // + weight-cvt blocks
    const int BC     = BB + nba;                      // + pass-A blocks

    // ---- fused prep: conversions + bucket histograms ----
    prep_kernel<<<BC, 256, 0, stream>>>(
        feat, featb, featq, n8,
        Ws1, Wn1, Ws2, Wn2, Wm1, Wm2,
        wsT1, wnT1, wsT2, wnT2, wmT1, wmT2,
        dst, histT, E, nbuk, nba, BA, BB);

    // ---- scan histT ----
    const int nparts = (nhist + 255) / 256;           // 798 <= 1024
    scan_block<<<nparts, 256, 0, stream>>>(histT, histT, partials, nhist);
    scan_partials<<<1, 1024, 0, stream>>>(partials, nparts);
    scan_add<<<nparts, 256, 0, stream>>>(histT, partials, nhist);

    // ---- partition + per-bucket CSR build ----
    part_edges<<<nba, 256, 0, stream>>>(src, dst, histT, ebsd, E, nbuk, nba);
    build_bucket<<<nbuk, 256, 0, stream>>>(ebsd, histT, offs, invd, csr_src, nn, E, nbuk, nba);

    // ---- layer 1 ----
    gather_fp8<N_IN><<<(nn + 3) / 4, 256, 0, stream>>>(
        featq, csr_src, offs, invd, agg1b, nn);
    mfma_layer<N_IN, HID, true, true, true, true><<<NB, 256, 0, stream>>>(
        featb, agg1b, wsT1, wnT1, b1, x1b, x1q, nn);

    // ---- layer 2 ----
    gather_fp8<HID><<<(nn + 3) / 4, 256, 0, stream>>>(
        x1q, csr_src, offs, invd, agg2b, nn);
    mfma_layer<HID, HID, true, true, true, false><<<NB, 256, 0, stream>>>(
        x1b, agg2b, wsT2, wnT2, b2, x2b, nullptr, nn);

    // ---- MLP ----
    mfma_layer<HID, HID, false, true, true, false><<<NB, 256, 0, stream>>>(
        x2b, nullptr, wmT1, nullptr, bm1, x3b, nullptr, nn);
    mfma_layer<HID, OUT_F, false, false, false, false><<<NB, 256, 0, stream>>>(
        x3b, nullptr, wmT2, nullptr, bm2, (float*)d_out, nullptr, nn);
}

// Round 13
// 208.279 us; speedup vs baseline: 2.5813x; 1.0030x over previous
//
#include <hip/hip_runtime.h>
#include <hip/hip_fp8.h>

#define N_IN 64
#define HID 128
#define OUT_F 64
#define EPB 6144          // edges per partition block (24 iters x 256)
#define BKT 128           // nodes per bucket

typedef unsigned short ushort_t;
typedef unsigned char  uchar_t;
typedef unsigned long long ull_t;
typedef ushort_t us8  __attribute__((ext_vector_type(8)));
typedef uchar_t  uc8  __attribute__((ext_vector_type(8)));
typedef short    s16x8 __attribute__((ext_vector_type(8)));
typedef float    f32x4 __attribute__((ext_vector_type(4)));
typedef float    f32x2 __attribute__((ext_vector_type(2)));
typedef unsigned int uint2v __attribute__((ext_vector_type(2)));

__device__ inline ushort_t f2bf(float f) {          // round-to-nearest-even
    unsigned u = __float_as_uint(f);
    u = u + 0x7fffu + ((u >> 16) & 1u);
    return (ushort_t)(u >> 16);
}
__device__ inline float bf2f(ushort_t b) {
    return __uint_as_float((unsigned)b << 16);
}
__device__ inline uchar_t f2fp8(float v) {          // OCP e4m3
    __hip_fp8_e4m3 q(v);
    return (uchar_t)q.__x;
}
template<bool HI>
__device__ inline f32x2 fp8pair(unsigned int dw) {
#if __has_builtin(__builtin_amdgcn_cvt_pk_f32_fp8)
    auto r = __builtin_amdgcn_cvt_pk_f32_fp8(dw, HI);   // HI is a literal
    f32x2 o; o[0] = r[0]; o[1] = r[1];
    return o;
#else
    f32x2 o;
#pragma unroll
    for (int i = 0; i < 2; ++i) {
        __hip_fp8_e4m3 h; h.__x = (dw >> (8 * (2 * (int)HI + i))) & 0xff;
        o[i] = (float)h;
    }
    return o;
#endif
}

// ---------------------------------------------------------------------------
// fused prep:
//   [0,BA)   feat fp32 -> bf16 + fp8
//   [BA,BB)  weights -> bf16 transposed
//   [BB,BC)  pass A: per-block bucket histogram (LDS atomics only)
// ---------------------------------------------------------------------------
__global__ __launch_bounds__(256)
void prep_kernel(const float* __restrict__ feat, ushort_t* __restrict__ featb,
                 uchar_t* __restrict__ featq, int n8,
                 const float* __restrict__ Ws1, const float* __restrict__ Wn1,
                 const float* __restrict__ Ws2, const float* __restrict__ Wn2,
                 const float* __restrict__ Wm1, const float* __restrict__ Wm2,
                 ushort_t* __restrict__ wsT1, ushort_t* __restrict__ wnT1,
                 ushort_t* __restrict__ wsT2, ushort_t* __restrict__ wnT2,
                 ushort_t* __restrict__ wmT1, ushort_t* __restrict__ wmT2,
                 const int* __restrict__ dst, int* __restrict__ histT,
                 int E, int nbuk, int nba, int BA, int BB) {
    __shared__ int hist[800];
    int b = blockIdx.x;
    int tid = threadIdx.x;
    if (b < BA) {
        int i = b * 256 + tid;
        if (i >= n8) return;
        f32x4 a = ((const f32x4*)feat)[2 * i];
        f32x4 c = ((const f32x4*)feat)[2 * i + 1];
        us8 v; uc8 q;
#pragma unroll
        for (int t = 0; t < 4; ++t) {
            v[t] = f2bf(a[t]); v[4 + t] = f2bf(c[t]);
            q[t] = f2fp8(a[t]); q[4 + t] = f2fp8(c[t]);
        }
        ((us8*)featb)[i] = v;
        ((uc8*)featq)[i] = q;
    } else if (b < BB) {
        int i = (b - BA) * 256 + tid;
        const float* W; ushort_t* WT; int K, H, l;
        if      (i < 8192)  { W = Ws1; WT = wsT1; K = 64;  H = 128; l = i; }
        else if (i < 16384) { W = Wn1; WT = wnT1; K = 64;  H = 128; l = i - 8192; }
        else if (i < 32768) { W = Ws2; WT = wsT2; K = 128; H = 128; l = i - 16384; }
        else if (i < 49152) { W = Wn2; WT = wnT2; K = 128; H = 128; l = i - 32768; }
        else if (i < 65536) { W = Wm1; WT = wmT1; K = 128; H = 128; l = i - 49152; }
        else if (i < 73728) { W = Wm2; WT = wmT2; K = 128; H = 64;  l = i - 65536; }
        else return;
        int h = l / K, k = l % K;
        WT[l] = f2bf(W[(size_t)k * H + h]);
    } else {
        const int blk  = b - BB;
        const int base = blk * EPB;
        for (int k = tid; k < nbuk; k += 256) hist[k] = 0;
        __syncthreads();
#pragma unroll
        for (int it = 0; it < EPB / 256; ++it) {
            int e = base + it * 256 + tid;
            if (e < E) atomicAdd(&hist[(unsigned)dst[e] / BKT], 1);
        }
        __syncthreads();
        for (int k = tid; k < nbuk; k += 256)
            histT[(size_t)k * nba + blk] = hist[k];
    }
}

// ---------------------------------------------------------------------------
// generic scan (3 kernels)
// ---------------------------------------------------------------------------
__global__ __launch_bounds__(256)
void scan_block(const int* __restrict__ in, int* __restrict__ out,
                int* __restrict__ partials, int n) {
    __shared__ int sm[256];
    int i = blockIdx.x * 256 + threadIdx.x;
    int v = (i < n) ? in[i] : 0;
    sm[threadIdx.x] = v;
    __syncthreads();
    for (int d = 1; d < 256; d <<= 1) {
        int t = (threadIdx.x >= d) ? sm[threadIdx.x - d] : 0;
        __syncthreads();
        sm[threadIdx.x] += t;
        __syncthreads();
    }
    if (i < n) out[i] = sm[threadIdx.x] - v;
    if (threadIdx.x == 255) partials[blockIdx.x] = sm[255];
}

__global__ __launch_bounds__(1024)
void scan_partials(int* __restrict__ partials, int nparts) {
    __shared__ int sm[1024];
    int i = threadIdx.x;
    int v = (i < nparts) ? partials[i] : 0;
    sm[i] = v;
    __syncthreads();
    for (int d = 1; d < 1024; d <<= 1) {
        int t = (i >= d) ? sm[i - d] : 0;
        __syncthreads();
        sm[i] += t;
        __syncthreads();
    }
    if (i < nparts) partials[i] = sm[i] - v;
}

__global__ __launch_bounds__(256)
void scan_add(int* __restrict__ arr, const int* __restrict__ partials, int n) {
    int i = blockIdx.x * 256 + threadIdx.x;
    if (i < n) arr[i] += partials[i >> 8];
}

// ---------------------------------------------------------------------------
// pass C: bucket-partition edges; LDS cursors; cached stores
// ---------------------------------------------------------------------------
__global__ __launch_bounds__(256)
void part_edges(const int* __restrict__ src, const int* __restrict__ dst,
                const int* __restrict__ histT, ull_t* __restrict__ ebsd,
                int E, int nbuk, int nba) {
    __shared__ int cur[800];
    const int blk  = blockIdx.x;
    const int base = blk * EPB;
    const int tid  = threadIdx.x;
    for (int k = tid; k < nbuk; k += 256)
        cur[k] = histT[(size_t)k * nba + blk];
    __syncthreads();
#pragma unroll
    for (int it = 0; it < EPB / 256; ++it) {
        int e = base + it * 256 + tid;
        if (e < E) {
            int d = dst[e], s = src[e];
            int pos = atomicAdd(&cur[(unsigned)d / BKT], 1);
            ebsd[pos] = (ull_t)(unsigned)s | ((ull_t)(unsigned)d << 32);
        }
    }
}

// ---------------------------------------------------------------------------
// pass D: per-bucket CSR finalize (BKT=128 nodes, 256 threads)
// ---------------------------------------------------------------------------
__global__ __launch_bounds__(256)
void build_bucket(const ull_t* __restrict__ ebsd, const int* __restrict__ histT,
                  int* __restrict__ offs, float* __restrict__ invd,
                  int* __restrict__ csr_src, int nn, int E, int nbuk, int nba) {
    __shared__ int sm[BKT];
    __shared__ int cur[BKT];
    const int b   = blockIdx.x;
    const int b0  = b * BKT;
    const int tid = threadIdx.x;
    const int ebase = histT[(size_t)b * nba];
    const int eend  = (b == nbuk - 1) ? E : histT[(size_t)(b + 1) * nba];

    if (tid < BKT) sm[tid] = 0;
    __syncthreads();
    for (int j = ebase + tid; j < eend; j += 256) {
        int d = (int)(ebsd[j] >> 32);
        atomicAdd(&sm[d - b0], 1);
    }
    __syncthreads();
    const int deg = (tid < BKT) ? sm[tid] : 0;
    for (int d = 1; d < BKT; d <<= 1) {
        int t = (tid >= d && tid < BKT) ? sm[tid - d] : 0;
        __syncthreads();
        if (tid < BKT) sm[tid] += t;
        __syncthreads();
    }
    if (tid < BKT) {
        const int excl = sm[tid] - deg;
        const int n = b0 + tid;
        if (n < nn) {
            offs[n] = ebase + excl;
            invd[n] = 1.0f / fmaxf((float)deg, 1.0f);
        }
        if (b == nbuk - 1 && tid == 0) offs[nn] = E;
        cur[tid] = ebase + excl;
    }
    __syncthreads();
    for (int j = ebase + tid; j < eend; j += 256) {
        ull_t p = ebsd[j];
        int s = (int)(unsigned)p;
        int d = (int)(p >> 32);
        int pos = atomicAdd(&cur[d - b0], 1);
        csr_src[pos] = s;
    }
}

// ---------------------------------------------------------------------------
// fp8 edge-parallel gather, wave = node, 8B/lane, 4-edge unroll, pk-f32 accum
// ---------------------------------------------------------------------------
template<int D>
__global__ __launch_bounds__(256)
void gather_fp8(const uchar_t* __restrict__ xq, const int* __restrict__ csr_src,
                const int* __restrict__ offs, const float* __restrict__ invd,
                ushort_t* __restrict__ aggb, int nn) {
    constexpr int C  = D / 8;
    constexpr int NE = 64 / C;
    const int n = (blockIdx.x * 256 + threadIdx.x) >> 6;
    if (n >= nn) return;
    const int lane = threadIdx.x & 63;
    const int c  = lane % C;
    const int eg = lane / C;
    const uchar_t* tab = xq + (size_t)c * 8;

    const int beg = offs[n], end = offs[n + 1];
    f32x2 acc[4];
#pragma unroll
    for (int t = 0; t < 4; ++t) acc[t] = (f32x2){0.f, 0.f};

    int j = beg + eg;
    for (; j + 3 * NE < end; j += 4 * NE) {
        int s0 = csr_src[j],          s1 = csr_src[j + NE];
        int s2 = csr_src[j + 2 * NE], s3 = csr_src[j + 3 * NE];
        uint2v q0 = *(const uint2v*)(tab + (size_t)s0 * D);
        uint2v q1 = *(const uint2v*)(tab + (size_t)s1 * D);
        uint2v q2 = *(const uint2v*)(tab + (size_t)s2 * D);
        uint2v q3 = *(const uint2v*)(tab + (size_t)s3 * D);
#pragma unroll
        for (int d = 0; d < 2; ++d) {
            f32x2 l01 = fp8pair<false>(q0[d]) + fp8pair<false>(q1[d]);
            f32x2 l23 = fp8pair<false>(q2[d]) + fp8pair<false>(q3[d]);
            acc[2 * d] += l01 + l23;
            f32x2 h01 = fp8pair<true>(q0[d]) + fp8pair<true>(q1[d]);
            f32x2 h23 = fp8pair<true>(q2[d]) + fp8pair<true>(q3[d]);
            acc[2 * d + 1] += h01 + h23;
        }
    }
    for (; j < end; j += NE) {
        int s = csr_src[j];
        uint2v q = *(const uint2v*)(tab + (size_t)s * D);
#pragma unroll
        for (int d = 0; d < 2; ++d) {
            acc[2 * d]     += fp8pair<false>(q[d]);
            acc[2 * d + 1] += fp8pair<true>(q[d]);
        }
    }

    // reduce across edge groups (stride C within the wave)
#pragma unroll
    for (int m = C; m < 64; m <<= 1) {
#pragma unroll
        for (int t = 0; t < 4; ++t) {
            acc[t][0] += __shfl_xor(acc[t][0], m, 64);
            acc[t][1] += __shfl_xor(acc[t][1], m, 64);
        }
    }

    if (eg == 0) {
        float iv = invd[n];
        us8 ov;
#pragma unroll
        for (int t = 0; t < 4; ++t) {
            ov[2 * t]     = f2bf(acc[t][0] * iv);
            ov[2 * t + 1] = f2bf(acc[t][1] * iv);
        }
        *(us8*)(aggb + (size_t)n * D + c * 8) = ov;
    }
}

// ---------------------------------------------------------------------------
// Weight-stationary MFMA layer (layer 1): grid-stride over 64-node tiles
// ---------------------------------------------------------------------------
template<int K, int H, bool NEIGH, bool RELU, bool OBF, bool OFP8>
__global__ __launch_bounds__(256)
void mfma_layer(const ushort_t* __restrict__ xb, const ushort_t* __restrict__ gb,
                const ushort_t* __restrict__ wsT, const ushort_t* __restrict__ wnT,
                const float* __restrict__ bias, void* __restrict__ out,
                uchar_t* __restrict__ outq, int nn) {
    constexpr int CH   = K / 8;
    constexpr int KS   = K / 32;
    constexpr int WTPW = H / 64;
    constexpr int PF   = CH / 4;

    __shared__ us8 xs[64][CH];
    __shared__ us8 gs[NEIGH ? 64 : 1][NEIGH ? CH : 1];

    const int tid  = threadIdx.x;
    const int lane = tid & 63;
    const int w    = tid >> 6;
    const int lr   = lane & 15;
    const int lk   = lane >> 4;

    s16x8 bws[WTPW][KS];
    s16x8 bwn[NEIGH ? WTPW : 1][NEIGH ? KS : 1];
#pragma unroll
    for (int t = 0; t < WTPW; ++t) {
        const size_t hrow = (size_t)((w * WTPW + t) * 16 + lr) * K;
#pragma unroll
        for (int ks = 0; ks < KS; ++ks) {
            bws[t][ks] = *(const s16x8*)(wsT + hrow + ks * 32 + lk * 8);
            if constexpr (NEIGH)
                bwn[t][ks] = *(const s16x8*)(wnT + hrow + ks * 32 + lk * 8);
        }
    }
    float bv[WTPW];
#pragma unroll
    for (int t = 0; t < WTPW; ++t) bv[t] = bias[(w * WTPW + t) * 16 + lr];

    const int ntiles = (nn + 63) >> 6;
    us8 pfx[PF], pfg[NEIGH ? PF : 1];
    const us8 z8 = {0, 0, 0, 0, 0, 0, 0, 0};

    auto loadpf = [&](int T) {
        const int base = T * 64;
#pragma unroll
        for (int q = 0; q < PF; ++q) {
            int idx = tid + q * 256, r = idx / CH, c = idx % CH, n = base + r;
            pfx[q] = (n < nn) ? *(const us8*)(xb + (size_t)n * K + c * 8) : z8;
            if constexpr (NEIGH)
                pfg[q] = (n < nn) ? *(const us8*)(gb + (size_t)n * K + c * 8) : z8;
        }
    };

    int tile = blockIdx.x;
    if (tile >= ntiles) return;
    loadpf(tile);

    while (true) {
        __syncthreads();
#pragma unroll
        for (int q = 0; q < PF; ++q) {
            int idx = tid + q * 256, r = idx / CH, c = idx % CH;
            int cs = c ^ (r & 7);
            xs[r][cs] = pfx[q];
            if constexpr (NEIGH) gs[r][cs] = pfg[q];
        }
        __syncthreads();

        const int row0 = tile * 64;
        tile += gridDim.x;
        if (tile < ntiles) loadpf(tile);

        f32x4 acc[4][WTPW];
#pragma unroll
        for (int rg = 0; rg < 4; ++rg)
#pragma unroll
            for (int t = 0; t < WTPW; ++t) acc[rg][t] = {0.f, 0.f, 0.f, 0.f};

#pragma unroll
        for (int rg = 0; rg < 4; ++rg) {
            const int R = rg * 16 + lr;
#pragma unroll
            for (int ks = 0; ks < KS; ++ks) {
                const int cs = (ks * 4 + lk) ^ (R & 7);
                s16x8 ax = (s16x8)xs[R][cs];
                s16x8 ag;
                if constexpr (NEIGH) ag = (s16x8)gs[R][cs];
#pragma unroll
                for (int t = 0; t < WTPW; ++t) {
                    acc[rg][t] = __builtin_amdgcn_mfma_f32_16x16x32_bf16(ax, bws[t][ks], acc[rg][t], 0, 0, 0);
                    if constexpr (NEIGH)
                        acc[rg][t] = __builtin_amdgcn_mfma_f32_16x16x32_bf16(ag, bwn[t][ks], acc[rg][t], 0, 0, 0);
                }
            }
        }

#pragma unroll
        for (int rg = 0; rg < 4; ++rg) {
#pragma unroll
            for (int t = 0; t < WTPW; ++t) {
                const int h = (w * WTPW + t) * 16 + lr;
#pragma unroll
                for (int j = 0; j < 4; ++j) {
                    int n = row0 + rg * 16 + lk * 4 + j;
                    if (n < nn) {
                        float v = acc[rg][t][j] + bv[t];
                        if constexpr (RELU) v = fmaxf(v, 0.f);
                        if constexpr (OBF)
                            ((ushort_t*)out)[(size_t)n * H + h] = f2bf(v);
                        else
                            ((float*)out)[(size_t)n * H + h] = v;
                        if constexpr (OFP8)
                            outq[(size_t)n * H + h] = f2fp8(v);
                    }
                }
            }
        }

        if (tile >= ntiles) break;
    }
}

// ---------------------------------------------------------------------------
// Fused tail: x2 = relu(x1@Ws2 + agg2@Wn2 + b2); x3 = relu(x2@Wm1 + bm1);
//             out = x3@Wm2 + bm2     (all weights register-resident,
//             x2/x3 round-trip through LDS as swizzled bf16)
// ---------------------------------------------------------------------------
__global__ __launch_bounds__(256)
void mfma_tail(const ushort_t* __restrict__ xb, const ushort_t* __restrict__ gb,
               const ushort_t* __restrict__ wsT2, const ushort_t* __restrict__ wnT2,
               const ushort_t* __restrict__ wmT1, const ushort_t* __restrict__ wmT2,
               const float* __restrict__ b2, const float* __restrict__ bm1,
               const float* __restrict__ bm2, float* __restrict__ out, int nn) {
    constexpr int CH = 16, KS = 4, PF = 4;
    __shared__ us8 xs[64][CH];
    __shared__ us8 gs[64][CH];
    ushort_t* xs16 = (ushort_t*)xs;
    ushort_t* gs16 = (ushort_t*)gs;

    const int tid  = threadIdx.x;
    const int lane = tid & 63;
    const int w    = tid >> 6;
    const int lr   = lane & 15;
    const int lk   = lane >> 4;

    // ---- register-resident weights ----
    s16x8 bws2[2][KS], bwn2[2][KS], bwm1[2][KS], bwm2[KS];
#pragma unroll
    for (int t = 0; t < 2; ++t) {
        const size_t hrow = (size_t)((w * 2 + t) * 16 + lr) * HID;
#pragma unroll
        for (int ks = 0; ks < KS; ++ks) {
            bws2[t][ks] = *(const s16x8*)(wsT2 + hrow + ks * 32 + lk * 8);
            bwn2[t][ks] = *(const s16x8*)(wnT2 + hrow + ks * 32 + lk * 8);
            bwm1[t][ks] = *(const s16x8*)(wmT1 + hrow + ks * 32 + lk * 8);
        }
    }
    {
        const size_t hrow = (size_t)(w * 16 + lr) * HID;
#pragma unroll
        for (int ks = 0; ks < KS; ++ks)
            bwm2[ks] = *(const s16x8*)(wmT2 + hrow + ks * 32 + lk * 8);
    }
    float bv2[2]  = {b2[(w * 2) * 16 + lr],  b2[(w * 2 + 1) * 16 + lr]};
    float bvm1[2] = {bm1[(w * 2) * 16 + lr], bm1[(w * 2 + 1) * 16 + lr]};
    float bvm2    = bm2[w * 16 + lr];

    const int ntiles = (nn + 63) >> 6;
    us8 pfx[PF], pfg[PF];
    const us8 z8 = {0, 0, 0, 0, 0, 0, 0, 0};

    auto loadpf = [&](int T) {
        const int base = T * 64;
#pragma unroll
        for (int q = 0; q < PF; ++q) {
            int idx = tid + q * 256, r = idx / CH, c = idx % CH, n = base + r;
            pfx[q] = (n < nn) ? *(const us8*)(xb + (size_t)n * HID + c * 8) : z8;
            pfg[q] = (n < nn) ? *(const us8*)(gb + (size_t)n * HID + c * 8) : z8;
        }
    };

    // swizzled bf16 scalar store into a [64][128]-ushort LDS tile
    auto st_bf = [&](ushort_t* base, int r, int h, float v) {
        int c8 = h >> 3, e = h & 7;
        int cs = c8 ^ (r & 7);
        base[r * 128 + cs * 8 + e] = f2bf(v);
    };

    int tile = blockIdx.x;
    if (tile >= ntiles) return;
    loadpf(tile);

    while (true) {
        __syncthreads();
#pragma unroll
        for (int q = 0; q < PF; ++q) {
            int idx = tid + q * 256, r = idx / CH, c = idx % CH;
            int cs = c ^ (r & 7);
            xs[r][cs] = pfx[q];
            gs[r][cs] = pfg[q];
        }
        __syncthreads();

        const int row0 = tile * 64;
        tile += gridDim.x;
        if (tile < ntiles) loadpf(tile);

        // ---- stage 1: x2 = relu(x1@Ws2 + agg2@Wn2 + b2) ----
        f32x4 a1[4][2];
#pragma unroll
        for (int rg = 0; rg < 4; ++rg)
#pragma unroll
            for (int t = 0; t < 2; ++t) a1[rg][t] = {0.f, 0.f, 0.f, 0.f};
#pragma unroll
        for (int rg = 0; rg < 4; ++rg) {
            const int R = rg * 16 + lr;
#pragma unroll
            for (int ks = 0; ks < KS; ++ks) {
                const int cs = (ks * 4 + lk) ^ (R & 7);
                s16x8 ax = (s16x8)xs[R][cs];
                s16x8 ag = (s16x8)gs[R][cs];
#pragma unroll
                for (int t = 0; t < 2; ++t) {
                    a1[rg][t] = __builtin_amdgcn_mfma_f32_16x16x32_bf16(ax, bws2[t][ks], a1[rg][t], 0, 0, 0);
                    a1[rg][t] = __builtin_amdgcn_mfma_f32_16x16x32_bf16(ag, bwn2[t][ks], a1[rg][t], 0, 0, 0);
                }
            }
        }
        __syncthreads();                       // all xs/gs reads done
        // write x2 (bf16, swizzled) into gs
#pragma unroll
        for (int rg = 0; rg < 4; ++rg)
#pragma unroll
            for (int t = 0; t < 2; ++t) {
                const int h = (w * 2 + t) * 16 + lr;
#pragma unroll
                for (int j = 0; j < 4; ++j) {
                    int r = rg * 16 + lk * 4 + j;
                    st_bf(gs16, r, h, fmaxf(a1[rg][t][j] + bv2[t], 0.f));
                }
            }
        __syncthreads();

        // ---- stage 2: x3 = relu(x2@Wm1 + bm1) ----
        f32x4 a2[4][2];
#pragma unroll
        for (int rg = 0; rg < 4; ++rg)
#pragma unroll
            for (int t = 0; t < 2; ++t) a2[rg][t] = {0.f, 0.f, 0.f, 0.f};
#pragma unroll
        for (int rg = 0; rg < 4; ++rg) {
            const int R = rg * 16 + lr;
#pragma unroll
            for (int ks = 0; ks < KS; ++ks) {
                const int cs = (ks * 4 + lk) ^ (R & 7);
                s16x8 ax = (s16x8)gs[R][cs];
#pragma unroll
                for (int t = 0; t < 2; ++t)
                    a2[rg][t] = __builtin_amdgcn_mfma_f32_16x16x32_bf16(ax, bwm1[t][ks], a2[rg][t], 0, 0, 0);
            }
        }
        __syncthreads();                       // gs reads done; xs free since stage1
        // write x3 (bf16, swizzled) into xs
#pragma unroll
        for (int rg = 0; rg < 4; ++rg)
#pragma unroll
            for (int t = 0; t < 2; ++t) {
                const int h = (w * 2 + t) * 16 + lr;
#pragma unroll
                for (int j = 0; j < 4; ++j) {
                    int r = rg * 16 + lk * 4 + j;
                    st_bf(xs16, r, h, fmaxf(a2[rg][t][j] + bvm1[t], 0.f));
                }
            }
        __syncthreads();

        // ---- stage 3: out = x3@Wm2 + bm2 (fp32, H=64) ----
        f32x4 a3[4];
#pragma unroll
        for (int rg = 0; rg < 4; ++rg) a3[rg] = {0.f, 0.f, 0.f, 0.f};
#pragma unroll
        for (int rg = 0; rg < 4; ++rg) {
            const int R = rg * 16 + lr;
#pragma unroll
            for (int ks = 0; ks < KS; ++ks) {
                const int cs = (ks * 4 + lk) ^ (R & 7);
                s16x8 ax = (s16x8)xs[R][cs];
                a3[rg] = __builtin_amdgcn_mfma_f32_16x16x32_bf16(ax, bwm2[ks], a3[rg], 0, 0, 0);
            }
        }
        const int h3 = w * 16 + lr;
#pragma unroll
        for (int rg = 0; rg < 4; ++rg)
#pragma unroll
            for (int j = 0; j < 4; ++j) {
                int n = row0 + rg * 16 + lk * 4 + j;
                if (n < nn) out[(size_t)n * OUT_F + h3] = a3[rg][j] + bvm2;
            }

        if (tile >= ntiles) break;
    }
}

// ---------------------------------------------------------------------------
extern "C" void kernel_launch(void* const* d_in, const int* in_sizes, int n_in,
                              void* d_out, int out_size, void* d_ws, size_t ws_size,
                              hipStream_t stream) {
    const float* feat = (const float*)d_in[0];
    const float* Wn1  = (const float*)d_in[1];
    const float* Ws1  = (const float*)d_in[2];
    const float* b1   = (const float*)d_in[3];
    const float* Wn2  = (const float*)d_in[4];
    const float* Ws2  = (const float*)d_in[5];
    const float* b2   = (const float*)d_in[6];
    const float* Wm1  = (const float*)d_in[7];
    const float* bm1  = (const float*)d_in[8];
    const float* Wm2  = (const float*)d_in[9];
    const float* bm2  = (const float*)d_in[10];
    const int*   src  = (const int*)d_in[11];
    const int*   dst  = (const int*)d_in[12];

    const int nn = in_sizes[0] / N_IN;    // 100000
    const int E  = in_sizes[11];          // 1600000

    const int nbuk  = (nn + BKT - 1) / BKT;   // 782 buckets of 128 nodes
    const int nba   = (E + EPB - 1) / EPB;    // 261 partition blocks
    const int nhist = nbuk * nba;

    // ---- workspace carve-up (64B-aligned) ----
    char* p = (char*)d_ws;
    auto alloc = [&](size_t bytes) { void* q = p; p += (bytes + 63) & ~(size_t)63; return q; };
    int*      offs     = (int*)alloc((size_t)(nn + 1) * 4);
    int*      partials = (int*)alloc(1024 * 4);
    float*    invd     = (float*)alloc((size_t)nn * 4);
    int*      histT    = (int*)alloc((size_t)nhist * 4);
    ull_t*    ebsd     = (ull_t*)alloc((size_t)E * 8);
    int*      csr_src  = (int*)alloc((size_t)E * 4);
    ushort_t* wsT1     = (ushort_t*)alloc((size_t)N_IN * HID * 2);
    ushort_t* wnT1     = (ushort_t*)alloc((size_t)N_IN * HID * 2);
    ushort_t* wsT2     = (ushort_t*)alloc((size_t)HID * HID * 2);
    ushort_t* wnT2     = (ushort_t*)alloc((size_t)HID * HID * 2);
    ushort_t* wmT1     = (ushort_t*)alloc((size_t)HID * HID * 2);
    ushort_t* wmT2     = (ushort_t*)alloc((size_t)HID * OUT_F * 2);
    ushort_t* featb    = (ushort_t*)alloc((size_t)nn * N_IN * 2);
    uchar_t*  x1q      = (uchar_t*)alloc((size_t)nn * HID);
    ushort_t* x1b      = (ushort_t*)alloc((size_t)nn * HID * 2);
    ushort_t* agg2b    = (ushort_t*)alloc((size_t)nn * HID * 2);
    ushort_t* agg1b    = (ushort_t*)d_out;            // dead after mfma_layer1
    uchar_t*  featq    = (uchar_t*)d_out + (size_t)nn * N_IN * 2;
    // agg1b/featq occupy d_out only until mfma_layer1 completes; the tail
    // kernel writes d_out afterwards (same stream, ordered).

    const int ntiles = (nn + 63) / 64;
    const int NB     = ntiles < 768 ? ntiles : 768;
    const int NBT    = ntiles < 512 ? ntiles : 512;   // tail: high VGPR
    const int n8     = nn * (N_IN / 8);
    const int BA     = (n8 + 255) / 256;
    const int BB     = BA + (73728 + 255) / 256;
    const int BC     = BB + nba;

    // ---- fused prep: conversions + bucket histograms ----
    prep_kernel<<<BC, 256, 0, stream>>>(
        feat, featb, featq, n8,
        Ws1, Wn1, Ws2, Wn2, Wm1, Wm2,
        wsT1, wnT1, wsT2, wnT2, wmT1, wmT2,
        dst, histT, E, nbuk, nba, BA, BB);

    // ---- scan histT ----
    const int nparts = (nhist + 255) / 256;
    scan_block<<<nparts, 256, 0, stream>>>(histT, histT, partials, nhist);
    scan_partials<<<1, 1024, 0, stream>>>(partials, nparts);
    scan_add<<<nparts, 256, 0, stream>>>(histT, partials, nhist);

    // ---- partition + per-bucket CSR build ----
    part_edges<<<nba, 256, 0, stream>>>(src, dst, histT, ebsd, E, nbuk, nba);
    build_bucket<<<nbuk, 256, 0, stream>>>(ebsd, histT, offs, invd, csr_src, nn, E, nbuk, nba);

    // ---- layer 1 ----
    gather_fp8<N_IN><<<(nn + 3) / 4, 256, 0, stream>>>(
        featq, csr_src, offs, invd, agg1b, nn);
    mfma_layer<N_IN, HID, true, true, true, true><<<NB, 256, 0, stream>>>(
        featb, agg1b, wsT1, wnT1, b1, x1b, x1q, nn);

    // ---- layer 2 gather ----
    gather_fp8<HID><<<(nn + 3) / 4, 256, 0, stream>>>(
        x1q, csr_src, offs, invd, agg2b, nn);

    // ---- fused tail: SAGE-2 + MLP1 + MLP2 -> d_out ----
    mfma_tail<<<NBT, 256, 0, stream>>>(
        x1b, agg2b, wsT2, wnT2, wmT1, wmT2, b2, bm1, bm2, (float*)d_out, nn);
}

// Round 14
// 200.621 us; speedup vs baseline: 2.6798x; 1.0382x over previous
//
#include <hip/hip_runtime.h>
#include <hip/hip_fp8.h>

#define N_IN 64
#define HID 128
#define OUT_F 64
#define EPB 6144          // edges per partition block (24 iters x 256)
#define BKT 128           // nodes per bucket (pow2; dlocal fits 7 bits)

typedef unsigned short ushort_t;
typedef unsigned char  uchar_t;
typedef ushort_t us8  __attribute__((ext_vector_type(8)));
typedef uchar_t  uc8  __attribute__((ext_vector_type(8)));
typedef short    s16x8 __attribute__((ext_vector_type(8)));
typedef float    f32x4 __attribute__((ext_vector_type(4)));
typedef float    f32x2 __attribute__((ext_vector_type(2)));
typedef unsigned int uint2v __attribute__((ext_vector_type(2)));

__device__ inline ushort_t f2bf(float f) {          // round-to-nearest-even
    unsigned u = __float_as_uint(f);
    u = u + 0x7fffu + ((u >> 16) & 1u);
    return (ushort_t)(u >> 16);
}
__device__ inline float bf2f(ushort_t b) {
    return __uint_as_float((unsigned)b << 16);
}
__device__ inline uchar_t f2fp8(float v) {          // OCP e4m3
    __hip_fp8_e4m3 q(v);
    return (uchar_t)q.__x;
}
template<bool HI>
__device__ inline f32x2 fp8pair(unsigned int dw) {
#if __has_builtin(__builtin_amdgcn_cvt_pk_f32_fp8)
    auto r = __builtin_amdgcn_cvt_pk_f32_fp8(dw, HI);   // HI is a literal
    f32x2 o; o[0] = r[0]; o[1] = r[1];
    return o;
#else
    f32x2 o;
#pragma unroll
    for (int i = 0; i < 2; ++i) {
        __hip_fp8_e4m3 h; h.__x = (dw >> (8 * (2 * (int)HI + i))) & 0xff;
        o[i] = (float)h;
    }
    return o;
#endif
}

// ---------------------------------------------------------------------------
// fused prep:
//   [0,BA)   feat fp32 -> bf16 + fp8
//   [BA,BB)  weights -> bf16 transposed
//   [BB,BC)  pass A: per-block bucket histogram (LDS atomics only)
// ---------------------------------------------------------------------------
__global__ __launch_bounds__(256)
void prep_kernel(const float* __restrict__ feat, ushort_t* __restrict__ featb,
                 uchar_t* __restrict__ featq, int n8,
                 const float* __restrict__ Ws1, const float* __restrict__ Wn1,
                 const float* __restrict__ Ws2, const float* __restrict__ Wn2,
                 const float* __restrict__ Wm1, const float* __restrict__ Wm2,
                 ushort_t* __restrict__ wsT1, ushort_t* __restrict__ wnT1,
                 ushort_t* __restrict__ wsT2, ushort_t* __restrict__ wnT2,
                 ushort_t* __restrict__ wmT1, ushort_t* __restrict__ wmT2,
                 const int* __restrict__ dst, int* __restrict__ histT,
                 int E, int nbuk, int nba, int BA, int BB) {
    __shared__ int hist[800];
    int b = blockIdx.x;
    int tid = threadIdx.x;
    if (b < BA) {
        int i = b * 256 + tid;
        if (i >= n8) return;
        f32x4 a = ((const f32x4*)feat)[2 * i];
        f32x4 c = ((const f32x4*)feat)[2 * i + 1];
        us8 v; uc8 q;
#pragma unroll
        for (int t = 0; t < 4; ++t) {
            v[t] = f2bf(a[t]); v[4 + t] = f2bf(c[t]);
            q[t] = f2fp8(a[t]); q[4 + t] = f2fp8(c[t]);
        }
        ((us8*)featb)[i] = v;
        ((uc8*)featq)[i] = q;
    } else if (b < BB) {
        int i = (b - BA) * 256 + tid;
        const float* W; ushort_t* WT; int K, H, l;
        if      (i < 8192)  { W = Ws1; WT = wsT1; K = 64;  H = 128; l = i; }
        else if (i < 16384) { W = Wn1; WT = wnT1; K = 64;  H = 128; l = i - 8192; }
        else if (i < 32768) { W = Ws2; WT = wsT2; K = 128; H = 128; l = i - 16384; }
        else if (i < 49152) { W = Wn2; WT = wnT2; K = 128; H = 128; l = i - 32768; }
        else if (i < 65536) { W = Wm1; WT = wmT1; K = 128; H = 128; l = i - 49152; }
        else if (i < 73728) { W = Wm2; WT = wmT2; K = 128; H = 64;  l = i - 65536; }
        else return;
        int h = l / K, k = l % K;
        WT[l] = f2bf(W[(size_t)k * H + h]);
    } else {
        const int blk  = b - BB;
        const int base = blk * EPB;
        for (int k = tid; k < nbuk; k += 256) hist[k] = 0;
        __syncthreads();
#pragma unroll
        for (int it = 0; it < EPB / 256; ++it) {
            int e = base + it * 256 + tid;
            if (e < E) atomicAdd(&hist[(unsigned)dst[e] / BKT], 1);
        }
        __syncthreads();
        for (int k = tid; k < nbuk; k += 256)
            histT[(size_t)k * nba + blk] = hist[k];
    }
}

// ---------------------------------------------------------------------------
// generic scan (3 kernels)
// ---------------------------------------------------------------------------
__global__ __launch_bounds__(256)
void scan_block(const int* __restrict__ in, int* __restrict__ out,
                int* __restrict__ partials, int n) {
    __shared__ int sm[256];
    int i = blockIdx.x * 256 + threadIdx.x;
    int v = (i < n) ? in[i] : 0;
    sm[threadIdx.x] = v;
    __syncthreads();
    for (int d = 1; d < 256; d <<= 1) {
        int t = (threadIdx.x >= d) ? sm[threadIdx.x - d] : 0;
        __syncthreads();
        sm[threadIdx.x] += t;
        __syncthreads();
    }
    if (i < n) out[i] = sm[threadIdx.x] - v;
    if (threadIdx.x == 255) partials[blockIdx.x] = sm[255];
}

__global__ __launch_bounds__(1024)
void scan_partials(int* __restrict__ partials, int nparts) {
    __shared__ int sm[1024];
    int i = threadIdx.x;
    int v = (i < nparts) ? partials[i] : 0;
    sm[i] = v;
    __syncthreads();
    for (int d = 1; d < 1024; d <<= 1) {
        int t = (i >= d) ? sm[i - d] : 0;
        __syncthreads();
        sm[i] += t;
        __syncthreads();
    }
    if (i < nparts) partials[i] = sm[i] - v;
}

__global__ __launch_bounds__(256)
void scan_add(int* __restrict__ arr, const int* __restrict__ partials, int n) {
    int i = blockIdx.x * 256 + threadIdx.x;
    if (i < n) arr[i] += partials[i >> 8];
}

// ---------------------------------------------------------------------------
// pass C: bucket-partition edges; u32-packed (dlocal<<17 | src); LDS cursors
// ---------------------------------------------------------------------------
__global__ __launch_bounds__(256)
void part_edges(const int* __restrict__ src, const int* __restrict__ dst,
                const int* __restrict__ histT, unsigned* __restrict__ epk,
                int E, int nbuk, int nba) {
    __shared__ int cur[800];
    const int blk  = blockIdx.x;
    const int base = blk * EPB;
    const int tid  = threadIdx.x;
    for (int k = tid; k < nbuk; k += 256)
        cur[k] = histT[(size_t)k * nba + blk];
    __syncthreads();
#pragma unroll
    for (int it = 0; it < EPB / 256; ++it) {
        int e = base + it * 256 + tid;
        if (e < E) {
            unsigned d = (unsigned)dst[e], s = (unsigned)src[e];
            int pos = atomicAdd(&cur[d / BKT], 1);
            epk[pos] = ((d & (BKT - 1)) << 17) | s;     // nn < 2^17
        }
    }
}

// ---------------------------------------------------------------------------
// pass D: per-bucket CSR finalize (BKT=128 nodes, 256 threads)
// ---------------------------------------------------------------------------
__global__ __launch_bounds__(256)
void build_bucket(const unsigned* __restrict__ epk, const int* __restrict__ histT,
                  int* __restrict__ offs, float* __restrict__ invd,
                  int* __restrict__ csr_src, int nn, int E, int nbuk, int nba) {
    __shared__ int sm[BKT];
    __shared__ int cur[BKT];
    const int b   = blockIdx.x;
    const int b0  = b * BKT;
    const int tid = threadIdx.x;
    const int ebase = histT[(size_t)b * nba];
    const int eend  = (b == nbuk - 1) ? E : histT[(size_t)(b + 1) * nba];

    if (tid < BKT) sm[tid] = 0;
    __syncthreads();
    for (int j = ebase + tid; j < eend; j += 256)
        atomicAdd(&sm[epk[j] >> 17], 1);
    __syncthreads();
    const int deg = (tid < BKT) ? sm[tid] : 0;
    for (int d = 1; d < BKT; d <<= 1) {
        int t = (tid >= d && tid < BKT) ? sm[tid - d] : 0;
        __syncthreads();
        if (tid < BKT) sm[tid] += t;
        __syncthreads();
    }
    if (tid < BKT) {
        const int excl = sm[tid] - deg;
        const int n = b0 + tid;
        if (n < nn) {
            offs[n] = ebase + excl;
            invd[n] = 1.0f / fmaxf((float)deg, 1.0f);
        }
        if (b == nbuk - 1 && tid == 0) offs[nn] = E;
        cur[tid] = ebase + excl;
    }
    __syncthreads();
    for (int j = ebase + tid; j < eend; j += 256) {
        unsigned p = epk[j];
        int pos = atomicAdd(&cur[p >> 17], 1);
        csr_src[pos] = (int)(p & 0x1FFFFu);
    }
}

// ---------------------------------------------------------------------------
// fp8 edge-parallel gather, wave = node, 8B/lane, 4/2/1 unroll ladder
// ---------------------------------------------------------------------------
template<int D>
__global__ __launch_bounds__(256)
void gather_fp8(const uchar_t* __restrict__ xq, const int* __restrict__ csr_src,
                const int* __restrict__ offs, const float* __restrict__ invd,
                ushort_t* __restrict__ aggb, int nn) {
    constexpr int C  = D / 8;
    constexpr int NE = 64 / C;
    const int n = (blockIdx.x * 256 + threadIdx.x) >> 6;
    if (n >= nn) return;
    const int lane = threadIdx.x & 63;
    const int c  = lane % C;
    const int eg = lane / C;
    const uchar_t* tab = xq + (size_t)c * 8;

    const int beg = offs[n], end = offs[n + 1];
    f32x2 acc[4];
#pragma unroll
    for (int t = 0; t < 4; ++t) acc[t] = (f32x2){0.f, 0.f};

    int j = beg + eg;
    for (; j + 3 * NE < end; j += 4 * NE) {
        int s0 = csr_src[j],          s1 = csr_src[j + NE];
        int s2 = csr_src[j + 2 * NE], s3 = csr_src[j + 3 * NE];
        uint2v q0 = *(const uint2v*)(tab + (size_t)s0 * D);
        uint2v q1 = *(const uint2v*)(tab + (size_t)s1 * D);
        uint2v q2 = *(const uint2v*)(tab + (size_t)s2 * D);
        uint2v q3 = *(const uint2v*)(tab + (size_t)s3 * D);
#pragma unroll
        for (int d = 0; d < 2; ++d) {
            f32x2 l01 = fp8pair<false>(q0[d]) + fp8pair<false>(q1[d]);
            f32x2 l23 = fp8pair<false>(q2[d]) + fp8pair<false>(q3[d]);
            acc[2 * d] += l01 + l23;
            f32x2 h01 = fp8pair<true>(q0[d]) + fp8pair<true>(q1[d]);
            f32x2 h23 = fp8pair<true>(q2[d]) + fp8pair<true>(q3[d]);
            acc[2 * d + 1] += h01 + h23;
        }
    }
    if (j + NE < end) {                       // 2-deep step
        int s0 = csr_src[j], s1 = csr_src[j + NE];
        uint2v q0 = *(const uint2v*)(tab + (size_t)s0 * D);
        uint2v q1 = *(const uint2v*)(tab + (size_t)s1 * D);
#pragma unroll
        for (int d = 0; d < 2; ++d) {
            acc[2 * d]     += fp8pair<false>(q0[d]) + fp8pair<false>(q1[d]);
            acc[2 * d + 1] += fp8pair<true>(q0[d]) + fp8pair<true>(q1[d]);
        }
        j += 2 * NE;
    }
    if (j < end) {                            // final single
        int s = csr_src[j];
        uint2v q = *(const uint2v*)(tab + (size_t)s * D);
#pragma unroll
        for (int d = 0; d < 2; ++d) {
            acc[2 * d]     += fp8pair<false>(q[d]);
            acc[2 * d + 1] += fp8pair<true>(q[d]);
        }
    }

    // reduce across edge groups (stride C within the wave)
#pragma unroll
    for (int m = C; m < 64; m <<= 1) {
#pragma unroll
        for (int t = 0; t < 4; ++t) {
            acc[t][0] += __shfl_xor(acc[t][0], m, 64);
            acc[t][1] += __shfl_xor(acc[t][1], m, 64);
        }
    }

    if (eg == 0) {
        float iv = invd[n];
        us8 ov;
#pragma unroll
        for (int t = 0; t < 4; ++t) {
            ov[2 * t]     = f2bf(acc[t][0] * iv);
            ov[2 * t + 1] = f2bf(acc[t][1] * iv);
        }
        *(us8*)(aggb + (size_t)n * D + c * 8) = ov;
    }
}

// ---------------------------------------------------------------------------
// Weight-stationary MFMA layer (layer 1): grid-stride over 64-node tiles
// ---------------------------------------------------------------------------
template<int K, int H, bool NEIGH, bool RELU, bool OBF, bool OFP8>
__global__ __launch_bounds__(256)
void mfma_layer(const ushort_t* __restrict__ xb, const ushort_t* __restrict__ gb,
                const ushort_t* __restrict__ wsT, const ushort_t* __restrict__ wnT,
                const float* __restrict__ bias, void* __restrict__ out,
                uchar_t* __restrict__ outq, int nn) {
    constexpr int CH   = K / 8;
    constexpr int KS   = K / 32;
    constexpr int WTPW = H / 64;
    constexpr int PF   = CH / 4;

    __shared__ us8 xs[64][CH];
    __shared__ us8 gs[NEIGH ? 64 : 1][NEIGH ? CH : 1];

    const int tid  = threadIdx.x;
    const int lane = tid & 63;
    const int w    = tid >> 6;
    const int lr   = lane & 15;
    const int lk   = lane >> 4;

    s16x8 bws[WTPW][KS];
    s16x8 bwn[NEIGH ? WTPW : 1][NEIGH ? KS : 1];
#pragma unroll
    for (int t = 0; t < WTPW; ++t) {
        const size_t hrow = (size_t)((w * WTPW + t) * 16 + lr) * K;
#pragma unroll
        for (int ks = 0; ks < KS; ++ks) {
            bws[t][ks] = *(const s16x8*)(wsT + hrow + ks * 32 + lk * 8);
            if constexpr (NEIGH)
                bwn[t][ks] = *(const s16x8*)(wnT + hrow + ks * 32 + lk * 8);
        }
    }
    float bv[WTPW];
#pragma unroll
    for (int t = 0; t < WTPW; ++t) bv[t] = bias[(w * WTPW + t) * 16 + lr];

    const int ntiles = (nn + 63) >> 6;
    us8 pfx[PF], pfg[NEIGH ? PF : 1];
    const us8 z8 = {0, 0, 0, 0, 0, 0, 0, 0};

    auto loadpf = [&](int T) {
        const int base = T * 64;
#pragma unroll
        for (int q = 0; q < PF; ++q) {
            int idx = tid + q * 256, r = idx / CH, c = idx % CH, n = base + r;
            pfx[q] = (n < nn) ? *(const us8*)(xb + (size_t)n * K + c * 8) : z8;
            if constexpr (NEIGH)
                pfg[q] = (n < nn) ? *(const us8*)(gb + (size_t)n * K + c * 8) : z8;
        }
    };

    int tile = blockIdx.x;
    if (tile >= ntiles) return;
    loadpf(tile);

    while (true) {
        __syncthreads();
#pragma unroll
        for (int q = 0; q < PF; ++q) {
            int idx = tid + q * 256, r = idx / CH, c = idx % CH;
            int cs = c ^ (r & 7);
            xs[r][cs] = pfx[q];
            if constexpr (NEIGH) gs[r][cs] = pfg[q];
        }
        __syncthreads();

        const int row0 = tile * 64;
        tile += gridDim.x;
        if (tile < ntiles) loadpf(tile);

        f32x4 acc[4][WTPW];
#pragma unroll
        for (int rg = 0; rg < 4; ++rg)
#pragma unroll
            for (int t = 0; t < WTPW; ++t) acc[rg][t] = {0.f, 0.f, 0.f, 0.f};

#pragma unroll
        for (int rg = 0; rg < 4; ++rg) {
            const int R = rg * 16 + lr;
#pragma unroll
            for (int ks = 0; ks < KS; ++ks) {
                const int cs = (ks * 4 + lk) ^ (R & 7);
                s16x8 ax = (s16x8)xs[R][cs];
                s16x8 ag;
                if constexpr (NEIGH) ag = (s16x8)gs[R][cs];
#pragma unroll
                for (int t = 0; t < WTPW; ++t) {
                    acc[rg][t] = __builtin_amdgcn_mfma_f32_16x16x32_bf16(ax, bws[t][ks], acc[rg][t], 0, 0, 0);
                    if constexpr (NEIGH)
                        acc[rg][t] = __builtin_amdgcn_mfma_f32_16x16x32_bf16(ag, bwn[t][ks], acc[rg][t], 0, 0, 0);
                }
            }
        }

#pragma unroll
        for (int rg = 0; rg < 4; ++rg) {
#pragma unroll
            for (int t = 0; t < WTPW; ++t) {
                const int h = (w * WTPW + t) * 16 + lr;
#pragma unroll
                for (int j = 0; j < 4; ++j) {
                    int n = row0 + rg * 16 + lk * 4 + j;
                    if (n < nn) {
                        float v = acc[rg][t][j] + bv[t];
                        if constexpr (RELU) v = fmaxf(v, 0.f);
                        if constexpr (OBF)
                            ((ushort_t*)out)[(size_t)n * H + h] = f2bf(v);
                        else
                            ((float*)out)[(size_t)n * H + h] = v;
                        if constexpr (OFP8)
                            outq[(size_t)n * H + h] = f2fp8(v);
                    }
                }
            }
        }

        if (tile >= ntiles) break;
    }
}

// ---------------------------------------------------------------------------
// Fused tail: x2 = relu(x1@Ws2 + agg2@Wn2 + b2); x3 = relu(x2@Wm1 + bm1);
//             out = x3@Wm2 + bm2
// ---------------------------------------------------------------------------
__global__ __launch_bounds__(256)
void mfma_tail(const ushort_t* __restrict__ xb, const ushort_t* __restrict__ gb,
               const ushort_t* __restrict__ wsT2, const ushort_t* __restrict__ wnT2,
               const ushort_t* __restrict__ wmT1, const ushort_t* __restrict__ wmT2,
               const float* __restrict__ b2, const float* __restrict__ bm1,
               const float* __restrict__ bm2, float* __restrict__ out, int nn) {
    constexpr int CH = 16, KS = 4, PF = 4;
    __shared__ us8 xs[64][CH];
    __shared__ us8 gs[64][CH];
    ushort_t* xs16 = (ushort_t*)xs;
    ushort_t* gs16 = (ushort_t*)gs;

    const int tid  = threadIdx.x;
    const int lane = tid & 63;
    const int w    = tid >> 6;
    const int lr   = lane & 15;
    const int lk   = lane >> 4;

    s16x8 bws2[2][KS], bwn2[2][KS], bwm1[2][KS], bwm2[KS];
#pragma unroll
    for (int t = 0; t < 2; ++t) {
        const size_t hrow = (size_t)((w * 2 + t) * 16 + lr) * HID;
#pragma unroll
        for (int ks = 0; ks < KS; ++ks) {
            bws2[t][ks] = *(const s16x8*)(wsT2 + hrow + ks * 32 + lk * 8);
            bwn2[t][ks] = *(const s16x8*)(wnT2 + hrow + ks * 32 + lk * 8);
            bwm1[t][ks] = *(const s16x8*)(wmT1 + hrow + ks * 32 + lk * 8);
        }
    }
    {
        const size_t hrow = (size_t)(w * 16 + lr) * HID;
#pragma unroll
        for (int ks = 0; ks < KS; ++ks)
            bwm2[ks] = *(const s16x8*)(wmT2 + hrow + ks * 32 + lk * 8);
    }
    float bv2[2]  = {b2[(w * 2) * 16 + lr],  b2[(w * 2 + 1) * 16 + lr]};
    float bvm1[2] = {bm1[(w * 2) * 16 + lr], bm1[(w * 2 + 1) * 16 + lr]};
    float bvm2    = bm2[w * 16 + lr];

    const int ntiles = (nn + 63) >> 6;
    us8 pfx[PF], pfg[PF];
    const us8 z8 = {0, 0, 0, 0, 0, 0, 0, 0};

    auto loadpf = [&](int T) {
        const int base = T * 64;
#pragma unroll
        for (int q = 0; q < PF; ++q) {
            int idx = tid + q * 256, r = idx / CH, c = idx % CH, n = base + r;
            pfx[q] = (n < nn) ? *(const us8*)(xb + (size_t)n * HID + c * 8) : z8;
            pfg[q] = (n < nn) ? *(const us8*)(gb + (size_t)n * HID + c * 8) : z8;
        }
    };

    auto st_bf = [&](ushort_t* base, int r, int h, float v) {
        int c8 = h >> 3, e = h & 7;
        int cs = c8 ^ (r & 7);
        base[r * 128 + cs * 8 + e] = f2bf(v);
    };

    int tile = blockIdx.x;
    if (tile >= ntiles) return;
    loadpf(tile);

    while (true) {
        __syncthreads();
#pragma unroll
        for (int q = 0; q < PF; ++q) {
            int idx = tid + q * 256, r = idx / CH, c = idx % CH;
            int cs = c ^ (r & 7);
            xs[r][cs] = pfx[q];
            gs[r][cs] = pfg[q];
        }
        __syncthreads();

        const int row0 = tile * 64;
        tile += gridDim.x;
        if (tile < ntiles) loadpf(tile);

        // ---- stage 1: x2 = relu(x1@Ws2 + agg2@Wn2 + b2) ----
        f32x4 a1[4][2];
#pragma unroll
        for (int rg = 0; rg < 4; ++rg)
#pragma unroll
            for (int t = 0; t < 2; ++t) a1[rg][t] = {0.f, 0.f, 0.f, 0.f};
#pragma unroll
        for (int rg = 0; rg < 4; ++rg) {
            const int R = rg * 16 + lr;
#pragma unroll
            for (int ks = 0; ks < KS; ++ks) {
                const int cs = (ks * 4 + lk) ^ (R & 7);
                s16x8 ax = (s16x8)xs[R][cs];
                s16x8 ag = (s16x8)gs[R][cs];
#pragma unroll
                for (int t = 0; t < 2; ++t) {
                    a1[rg][t] = __builtin_amdgcn_mfma_f32_16x16x32_bf16(ax, bws2[t][ks], a1[rg][t], 0, 0, 0);
                    a1[rg][t] = __builtin_amdgcn_mfma_f32_16x16x32_bf16(ag, bwn2[t][ks], a1[rg][t], 0, 0, 0);
                }
            }
        }
        __syncthreads();
#pragma unroll
        for (int rg = 0; rg < 4; ++rg)
#pragma unroll
            for (int t = 0; t < 2; ++t) {
                const int h = (w * 2 + t) * 16 + lr;
#pragma unroll
                for (int j = 0; j < 4; ++j) {
                    int r = rg * 16 + lk * 4 + j;
                    st_bf(gs16, r, h, fmaxf(a1[rg][t][j] + bv2[t], 0.f));
                }
            }
        __syncthreads();

        // ---- stage 2: x3 = relu(x2@Wm1 + bm1) ----
        f32x4 a2[4][2];
#pragma unroll
        for (int rg = 0; rg < 4; ++rg)
#pragma unroll
            for (int t = 0; t < 2; ++t) a2[rg][t] = {0.f, 0.f, 0.f, 0.f};
#pragma unroll
        for (int rg = 0; rg < 4; ++rg) {
            const int R = rg * 16 + lr;
#pragma unroll
            for (int ks = 0; ks < KS; ++ks) {
                const int cs = (ks * 4 + lk) ^ (R & 7);
                s16x8 ax = (s16x8)gs[R][cs];
#pragma unroll
                for (int t = 0; t < 2; ++t)
                    a2[rg][t] = __builtin_amdgcn_mfma_f32_16x16x32_bf16(ax, bwm1[t][ks], a2[rg][t], 0, 0, 0);
            }
        }
        __syncthreads();
#pragma unroll
        for (int rg = 0; rg < 4; ++rg)
#pragma unroll
            for (int t = 0; t < 2; ++t) {
                const int h = (w * 2 + t) * 16 + lr;
#pragma unroll
                for (int j = 0; j < 4; ++j) {
                    int r = rg * 16 + lk * 4 + j;
                    st_bf(xs16, r, h, fmaxf(a2[rg][t][j] + bvm1[t], 0.f));
                }
            }
        __syncthreads();

        // ---- stage 3: out = x3@Wm2 + bm2 (fp32, H=64) ----
        f32x4 a3[4];
#pragma unroll
        for (int rg = 0; rg < 4; ++rg) a3[rg] = {0.f, 0.f, 0.f, 0.f};
#pragma unroll
        for (int rg = 0; rg < 4; ++rg) {
            const int R = rg * 16 + lr;
#pragma unroll
            for (int ks = 0; ks < KS; ++ks) {
                const int cs = (ks * 4 + lk) ^ (R & 7);
                s16x8 ax = (s16x8)xs[R][cs];
                a3[rg] = __builtin_amdgcn_mfma_f32_16x16x32_bf16(ax, bwm2[ks], a3[rg], 0, 0, 0);
            }
        }
        const int h3 = w * 16 + lr;
#pragma unroll
        for (int rg = 0; rg < 4; ++rg)
#pragma unroll
            for (int j = 0; j < 4; ++j) {
                int n = row0 + rg * 16 + lk * 4 + j;
                if (n < nn) out[(size_t)n * OUT_F + h3] = a3[rg][j] + bvm2;
            }

        if (tile >= ntiles) break;
    }
}

// ---------------------------------------------------------------------------
extern "C" void kernel_launch(void* const* d_in, const int* in_sizes, int n_in,
                              void* d_out, int out_size, void* d_ws, size_t ws_size,
                              hipStream_t stream) {
    const float* feat = (const float*)d_in[0];
    const float* Wn1  = (const float*)d_in[1];
    const float* Ws1  = (const float*)d_in[2];
    const float* b1   = (const float*)d_in[3];
    const float* Wn2  = (const float*)d_in[4];
    const float* Ws2  = (const float*)d_in[5];
    const float* b2   = (const float*)d_in[6];
    const float* Wm1  = (const float*)d_in[7];
    const float* bm1  = (const float*)d_in[8];
    const float* Wm2  = (const float*)d_in[9];
    const float* bm2  = (const float*)d_in[10];
    const int*   src  = (const int*)d_in[11];
    const int*   dst  = (const int*)d_in[12];

    const int nn = in_sizes[0] / N_IN;    // 100000 (< 2^17, required by pack)
    const int E  = in_sizes[11];          // 1600000

    const int nbuk  = (nn + BKT - 1) / BKT;   // 782 buckets
    const int nba   = (E + EPB - 1) / EPB;    // 261 partition blocks
    const int nhist = nbuk * nba;

    // ---- workspace carve-up (64B-aligned) ----
    char* p = (char*)d_ws;
    auto alloc = [&](size_t bytes) { void* q = p; p += (bytes + 63) & ~(size_t)63; return q; };
    int*      offs     = (int*)alloc((size_t)(nn + 1) * 4);
    int*      partials = (int*)alloc(1024 * 4);
    float*    invd     = (float*)alloc((size_t)nn * 4);
    int*      histT    = (int*)alloc((size_t)nhist * 4);
    unsigned* epk      = (unsigned*)alloc((size_t)E * 4);
    int*      csr_src  = (int*)alloc((size_t)E * 4);
    ushort_t* wsT1     = (ushort_t*)alloc((size_t)N_IN * HID * 2);
    ushort_t* wnT1     = (ushort_t*)alloc((size_t)N_IN * HID * 2);
    ushort_t* wsT2     = (ushort_t*)alloc((size_t)HID * HID * 2);
    ushort_t* wnT2     = (ushort_t*)alloc((size_t)HID * HID * 2);
    ushort_t* wmT1     = (ushort_t*)alloc((size_t)HID * HID * 2);
    ushort_t* wmT2     = (ushort_t*)alloc((size_t)HID * OUT_F * 2);
    ushort_t* featb    = (ushort_t*)alloc((size_t)nn * N_IN * 2);
    uchar_t*  x1q      = (uchar_t*)alloc((size_t)nn * HID);
    ushort_t* x1b      = (ushort_t*)alloc((size_t)nn * HID * 2);
    ushort_t* agg2b    = (ushort_t*)alloc((size_t)nn * HID * 2);
    ushort_t* agg1b    = (ushort_t*)d_out;            // dead after mfma_layer1
    uchar_t*  featq    = (uchar_t*)d_out + (size_t)nn * N_IN * 2;
    // agg1b/featq occupy d_out only until mfma_layer1 completes; tail writes
    // d_out afterwards (same stream, ordered).

    const int ntiles = (nn + 63) / 64;
    const int NB     = ntiles < 768 ? ntiles : 768;
    const int NBT    = ntiles < 512 ? ntiles : 512;
    const int n8     = nn * (N_IN / 8);
    const int BA     = (n8 + 255) / 256;
    const int BB     = BA + (73728 + 255) / 256;
    const int BC     = BB + nba;

    // ---- fused prep: conversions + bucket histograms ----
    prep_kernel<<<BC, 256, 0, stream>>>(
        feat, featb, featq, n8,
        Ws1, Wn1, Ws2, Wn2, Wm1, Wm2,
        wsT1, wnT1, wsT2, wnT2, wmT1, wmT2,
        dst, histT, E, nbuk, nba, BA, BB);

    // ---- scan histT ----
    const int nparts = (nhist + 255) / 256;
    scan_block<<<nparts, 256, 0, stream>>>(histT, histT, partials, nhist);
    scan_partials<<<1, 1024, 0, stream>>>(partials, nparts);
    scan_add<<<nparts, 256, 0, stream>>>(histT, partials, nhist);

    // ---- partition + per-bucket CSR build ----
    part_edges<<<nba, 256, 0, stream>>>(src, dst, histT, epk, E, nbuk, nba);
    build_bucket<<<nbuk, 256, 0, stream>>>(epk, histT, offs, invd, csr_src, nn, E, nbuk, nba);

    // ---- layer 1 ----
    gather_fp8<N_IN><<<(nn + 3) / 4, 256, 0, stream>>>(
        featq, csr_src, offs, invd, agg1b, nn);
    mfma_layer<N_IN, HID, true, true, true, true><<<NB, 256, 0, stream>>>(
        featb, agg1b, wsT1, wnT1, b1, x1b, x1q, nn);

    // ---- layer 2 gather ----
    gather_fp8<HID><<<(nn + 3) / 4, 256, 0, stream>>>(
        x1q, csr_src, offs, invd, agg2b, nn);

    // ---- fused tail: SAGE-2 + MLP1 + MLP2 -> d_out ----
    mfma_tail<<<NBT, 256, 0, stream>>>(
        x1b, agg2b, wsT2, wnT2, wmT1, wmT2, b2, bm1, bm2, (float*)d_out, nn);
}